// Round 1
// baseline (1477.994 us; speedup 1.0000x reference)
//
#include <hip/hip_runtime.h>
#include <hip/hip_bf16.h>
#include <math.h>

// ---------------- constants (match reference) ----------------
#define NN 20000
#define EE 400000
#define GG 64
#define VIN 128
#define CONVD 128
#define H1 4
#define NETD 256
#define NXD 9
#define EPS_BN 1e-5f
#define NEG_SLOPE 0.2f

// ---------------- init ----------------
__global__ void init_minf2(float* m1, int n1, float* m2, int n2) {
    int i = blockIdx.x * blockDim.x + threadIdx.x;
    if (i < n1) m1[i] = -INFINITY;
    else if (i < n1 + n2) m2[i - n1] = -INFINITY;
}

// ---------------- f32 tiled GEMM: C[M,Nn] = A[M,K] @ B[K,Nn] ----------------
__global__ __launch_bounds__(256) void gemm_f32(const float* __restrict__ A,
                                                const float* __restrict__ B,
                                                float* __restrict__ C,
                                                int M, int Nn, int K) {
    __shared__ float As[16][64];
    __shared__ float Bs[16][64];
    int tid = threadIdx.x;
    int bm = blockIdx.y * 64, bn = blockIdx.x * 64;
    int tx = tid & 15, ty = tid >> 4;
    float acc[4][4] = {};
    int ar = tid >> 2;          // 0..63
    int ac = (tid & 3) << 2;    // 0,4,8,12
    int br = tid >> 4;          // 0..15
    int bc = (tid & 15) << 2;   // 0..60
    for (int k0 = 0; k0 < K; k0 += 16) {
        float4 av = make_float4(0.f, 0.f, 0.f, 0.f);
        if (bm + ar < M) av = *(const float4*)(A + (size_t)(bm + ar) * K + k0 + ac);
        float4 bv = *(const float4*)(B + (size_t)(k0 + br) * Nn + bn + bc);
        As[ac + 0][ar] = av.x; As[ac + 1][ar] = av.y;
        As[ac + 2][ar] = av.z; As[ac + 3][ar] = av.w;
        *(float4*)&Bs[br][bc] = bv;
        __syncthreads();
#pragma unroll
        for (int kk = 0; kk < 16; kk++) {
            float4 a = *(const float4*)&As[kk][ty << 2];
            float4 b = *(const float4*)&Bs[kk][tx << 2];
            float avr[4] = {a.x, a.y, a.z, a.w};
            float bvr[4] = {b.x, b.y, b.z, b.w};
#pragma unroll
            for (int i = 0; i < 4; i++)
#pragma unroll
                for (int j = 0; j < 4; j++)
                    acc[i][j] = fmaf(avr[i], bvr[j], acc[i][j]);
        }
        __syncthreads();
    }
#pragma unroll
    for (int i = 0; i < 4; i++) {
        int row = bm + (ty << 2) + i;
        if (row < M) {
            float4 o = make_float4(acc[i][0], acc[i][1], acc[i][2], acc[i][3]);
            *(float4*)(C + (size_t)row * Nn + bn + (tx << 2)) = o;
        }
    }
}

// ---------------- attention logits: per (node, head) wave dot ----------------
__global__ void alpha_kernel(const float* __restrict__ h,
                             const float* __restrict__ a_s,
                             const float* __restrict__ a_d,
                             float* __restrict__ as_out, float* __restrict__ ad_out,
                             int H, int C) {
    int n = blockIdx.x;
    int wv = threadIdx.x >> 6, ln = threadIdx.x & 63;
    const float* hr = h + ((size_t)n * H + wv) * C;
    float ss = 0.f, sd = 0.f;
    for (int c = ln; c < C; c += 64) {
        float v = hr[c];
        ss = fmaf(v, a_s[wv * C + c], ss);
        sd = fmaf(v, a_d[wv * C + c], sd);
    }
    for (int o = 32; o > 0; o >>= 1) {
        ss += __shfl_down(ss, o);
        sd += __shfl_down(sd, o);
    }
    if (ln == 0) { as_out[n * H + wv] = ss; ad_out[n * H + wv] = sd; }
}

__device__ __forceinline__ float leaky(float v) {
    return v >= 0.f ? v : NEG_SLOPE * v;
}

__device__ __forceinline__ void atomicMaxFloat(float* addr, float v) {
    if (v >= 0.f) atomicMax((int*)addr, __float_as_int(v));
    else atomicMin((unsigned int*)addr, __float_as_uint(v));
}

// ---------------- edge pass A: segment max ----------------
__global__ void edge_max(const int* __restrict__ ei, int E, int Np,
                         const float* __restrict__ as, const float* __restrict__ ad,
                         float* __restrict__ m, int H) {
    int e = blockIdx.x * blockDim.x + threadIdx.x;
    if (e >= E + Np) return;
    int s = (e < E) ? ei[e] : e - E;
    int d = (e < E) ? ei[E + e] : e - E;
    for (int h = 0; h < H; h++) {
        float v = leaky(as[s * H + h] + ad[d * H + h]);
        atomicMaxFloat(&m[d * H + h], v);
    }
}

// ---------------- edge pass B: p = exp(e - m[dst]); denom += p ----------------
__global__ void edge_p(const int* __restrict__ ei, int E, int Np,
                       const float* __restrict__ as, const float* __restrict__ ad,
                       const float* __restrict__ m,
                       float* __restrict__ p, float* __restrict__ denom, int H) {
    int e = blockIdx.x * blockDim.x + threadIdx.x;
    if (e >= E + Np) return;
    int s = (e < E) ? ei[e] : e - E;
    int d = (e < E) ? ei[E + e] : e - E;
    for (int h = 0; h < H; h++) {
        float v = leaky(as[s * H + h] + ad[d * H + h]);
        float pv = __expf(v - m[d * H + h]);
        p[e * H + h] = pv;
        atomicAdd(&denom[d * H + h], pv);
    }
}

// ---------------- edge pass C: out[dst,h,:] += (p/denom)*h[src,h,:] ----------------
__global__ __launch_bounds__(256) void edge_aggr(const int* __restrict__ ei, int E, int Np,
                          const float* __restrict__ p, const float* __restrict__ denom,
                          const float* __restrict__ h, float* __restrict__ out, int H) {
    const int C = 128;
    int pair = blockIdx.x * 2 + (threadIdx.x >> 7);
    int c = threadIdx.x & 127;
    int tot = (E + Np) * H;
    if (pair >= tot) return;
    int e = pair / H, hh = pair - e * H;
    int s = (e < E) ? ei[e] : e - E;
    int d = (e < E) ? ei[E + e] : e - E;
    float w = p[e * H + hh] / (denom[d * H + hh] + 1e-16f);
    float val = w * h[((size_t)s * H + hh) * C + c];
    atomicAdd(&out[((size_t)d * H + hh) * C + c], val);
}

// ---------------- BN stats: per-column sum / sumsq of (x + bias) ----------------
__global__ void bn_stats(const float* __restrict__ x, const float* __restrict__ bias,
                         float* __restrict__ stats, int Nn, int C) {
    const int ROWS = 64;
    int r0 = blockIdx.x * ROWS;
    int rend = min(r0 + ROWS, Nn);
    for (int c = threadIdx.x; c < C; c += blockDim.x) {
        float b = bias[c];
        float s1 = 0.f, s2 = 0.f;
        for (int r = r0; r < rend; r++) {
            float v = x[(size_t)r * C + c] + b;
            s1 += v;
            s2 = fmaf(v, v, s2);
        }
        atomicAdd(&stats[c], s1);
        atomicAdd(&stats[C + c], s2);
    }
}

// ---------------- BN apply + ReLU (in place ok) ----------------
__global__ void bn_apply(const float* __restrict__ x, const float* __restrict__ bias,
                         const float* __restrict__ stats,
                         const float* __restrict__ gamma, const float* __restrict__ beta,
                         float* __restrict__ y, int Nn, int C) {
    int idx = blockIdx.x * blockDim.x + threadIdx.x;
    if (idx >= Nn * C) return;
    int c = idx % C;
    float inv_n = 1.f / (float)Nn;
    float mu = stats[c] * inv_n;
    float var = stats[C + c] * inv_n - mu * mu;
    float v = (x[idx] + bias[c] - mu) * rsqrtf(var + EPS_BN);
    v = fmaf(gamma[c], v, beta[c]);
    y[idx] = v > 0.f ? v : 0.f;
}

// ---------------- global add pool ----------------
__global__ void pool_kernel(const float* __restrict__ h, const int* __restrict__ batch,
                            float* __restrict__ z) {
    int n = blockIdx.x, c = threadIdx.x;   // block = 128
    int b = batch[n];
    atomicAdd(&z[b * CONVD + c], h[(size_t)n * CONVD + c]);
}

// ---------------- fused MLP head: one block per graph ----------------
__global__ __launch_bounds__(320) void mlp_kernel(const float* __restrict__ g,
                           const float* __restrict__ extras,
                           const float* __restrict__ Wm1, const float* __restrict__ bm1,
                           const float* __restrict__ Wm2, const float* __restrict__ bm2,
                           const float* __restrict__ Wm3, const float* __restrict__ bm3,
                           float* __restrict__ out) {
    const int Z0 = CONVD + NXD;   // 137
    const int Z1 = NETD + NXD;    // 265
    const int Z2 = NETD;          // 256
    __shared__ float z[Z0];
    __shared__ float z1[Z1];
    __shared__ float z2[Z2];
    __shared__ float wred[5];
    int gi = blockIdx.x, t = threadIdx.x;
    if (t < CONVD) z[t] = g[gi * CONVD + t];
    else if (t < Z0) z[t] = extras[gi * NXD + (t - CONVD)];
    __syncthreads();
    if (t < Z1) {
        float acc = bm1[t];
        for (int k = 0; k < Z0; k++) acc = fmaf(z[k], Wm1[k * Z1 + t], acc);
        z1[t] = acc > 0.f ? acc : 0.f;
    }
    __syncthreads();
    if (t < Z2) {
        float acc = bm2[t];
        for (int k = 0; k < Z1; k++) acc = fmaf(z1[k], Wm2[k * Z2 + t], acc);
        z2[t] = acc > 0.f ? acc : 0.f;
    }
    __syncthreads();
    float partial = (t < Z2) ? z2[t] * Wm3[t] : 0.f;
    for (int o = 32; o > 0; o >>= 1) partial += __shfl_down(partial, o);
    int wv = t >> 6, ln = t & 63;
    if (ln == 0) wred[wv] = partial;
    __syncthreads();
    if (t == 0) {
        float s = bm3[0];
        for (int i = 0; i < 5; i++) s += wred[i];
        out[gi] = s;
    }
}

// ---------------- launch ----------------
extern "C" void kernel_launch(void* const* d_in, const int* in_sizes, int n_in,
                              void* d_out, int out_size, void* d_ws, size_t ws_size,
                              hipStream_t stream) {
    const float* x      = (const float*)d_in[0];
    const int*   ei     = (const int*)d_in[1];
    const int*   batch  = (const int*)d_in[2];
    const float* extras = (const float*)d_in[3];
    const float* W1     = (const float*)d_in[4];
    const float* a_s1   = (const float*)d_in[5];
    const float* a_d1   = (const float*)d_in[6];
    const float* b1     = (const float*)d_in[7];
    const float* W2     = (const float*)d_in[8];
    const float* a_s2   = (const float*)d_in[9];
    const float* a_d2   = (const float*)d_in[10];
    const float* b2     = (const float*)d_in[11];
    const float* gamma1 = (const float*)d_in[12];
    const float* beta1  = (const float*)d_in[13];
    const float* gamma2 = (const float*)d_in[14];
    const float* beta2  = (const float*)d_in[15];
    const float* Wm1    = (const float*)d_in[16];
    const float* bm1    = (const float*)d_in[17];
    const float* Wm2    = (const float*)d_in[18];
    const float* bm2    = (const float*)d_in[19];
    const float* Wm3    = (const float*)d_in[20];
    const float* bm3    = (const float*)d_in[21];
    float* out = (float*)d_out;

    const int N = NN, E = EE, EP = EE + NN;

    char* ws = (char*)d_ws;
    size_t off = 0;
    auto alloc = [&](size_t bytes) -> float* {
        float* pp = (float*)(ws + off);
        off += (bytes + 255) & ~(size_t)255;
        return pp;
    };
    // --- zero region (contiguous; one memset) ---
    float* out1   = alloc((size_t)N * 512 * 4);
    float* out2   = alloc((size_t)N * 128 * 4);
    float* denom1 = alloc((size_t)N * 4 * 4);
    float* denom2 = alloc((size_t)N * 4);
    float* stats1 = alloc(512 * 2 * 4);
    float* stats2 = alloc(128 * 2 * 4);
    float* zbuf   = alloc((size_t)GG * CONVD * 4);
    size_t zero_bytes = off;
    // --- -inf region ---
    float* m1 = alloc((size_t)N * 4 * 4);
    float* m2 = alloc((size_t)N * 4);
    // --- scratch ---
    float* h1  = alloc((size_t)N * 512 * 4);
    float* h2  = alloc((size_t)N * 128 * 4);
    float* as1 = alloc((size_t)N * 4 * 4);
    float* ad1 = alloc((size_t)N * 4 * 4);
    float* p1  = alloc((size_t)EP * 4 * 4);
    float* as2 = alloc((size_t)N * 4);
    float* ad2 = alloc((size_t)N * 4);
    float* p2  = alloc((size_t)EP * 4);

    hipMemsetAsync(d_ws, 0, zero_bytes, stream);
    init_minf2<<<(N * 5 + 255) / 256, 256, 0, stream>>>(m1, N * 4, m2, N);

    int eb = (EP + 255) / 256;
    int nrow = (N + 63) / 64;

    // ---- GAT layer 1 (H=4, concat) ----
    gemm_f32<<<dim3(512 / 64, nrow), 256, 0, stream>>>(x, W1, h1, N, 512, VIN);
    alpha_kernel<<<N, 4 * 64, 0, stream>>>(h1, a_s1, a_d1, as1, ad1, 4, CONVD);
    edge_max<<<eb, 256, 0, stream>>>(ei, E, N, as1, ad1, m1, 4);
    edge_p<<<eb, 256, 0, stream>>>(ei, E, N, as1, ad1, m1, p1, denom1, 4);
    edge_aggr<<<(EP * 4 + 1) / 2, 256, 0, stream>>>(ei, E, N, p1, denom1, h1, out1, 4);
    bn_stats<<<nrow, 256, 0, stream>>>(out1, b1, stats1, N, 512);
    bn_apply<<<(N * 512 + 255) / 256, 256, 0, stream>>>(out1, b1, stats1, gamma1, beta1, out1, N, 512);

    // ---- GAT layer 2 (H=1) ----
    gemm_f32<<<dim3(128 / 64, nrow), 256, 0, stream>>>(out1, W2, h2, N, 128, 512);
    alpha_kernel<<<N, 64, 0, stream>>>(h2, a_s2, a_d2, as2, ad2, 1, CONVD);
    edge_max<<<eb, 256, 0, stream>>>(ei, E, N, as2, ad2, m2, 1);
    edge_p<<<eb, 256, 0, stream>>>(ei, E, N, as2, ad2, m2, p2, denom2, 1);
    edge_aggr<<<(EP + 1) / 2, 256, 0, stream>>>(ei, E, N, p2, denom2, h2, out2, 1);
    bn_stats<<<nrow, 256, 0, stream>>>(out2, b2, stats2, N, 128);
    bn_apply<<<(N * 128 + 255) / 256, 256, 0, stream>>>(out2, b2, stats2, gamma2, beta2, out2, N, 128);

    // ---- pool + MLP head ----
    pool_kernel<<<N, 128, 0, stream>>>(out2, batch, zbuf);
    mlp_kernel<<<GG, 320, 0, stream>>>(zbuf, extras, Wm1, bm1, Wm2, bm2, Wm3, bm3, out);
}

// Round 2
// 660.998 us; speedup vs baseline: 2.2360x; 2.2360x over previous
//
#include <hip/hip_runtime.h>
#include <hip/hip_bf16.h>
#include <math.h>

// ---------------- constants (match reference) ----------------
#define NN 20000
#define EE 400000
#define GG 64
#define VIN 128
#define CONVD 128
#define NETD 256
#define NXD 9
#define EPS_BN 1e-5f
#define NEG_SLOPE 0.2f

__device__ __forceinline__ float leaky(float v) {
    return v >= 0.f ? v : NEG_SLOPE * v;
}

// ---------------- CSR build: histogram of dst (incl. self-loops) ----------------
__global__ void hist_kernel(const int* __restrict__ ei, int* __restrict__ deg,
                            int E, int Np) {
    int e = blockIdx.x * blockDim.x + threadIdx.x;
    if (e >= E + Np) return;
    int d = (e < E) ? ei[E + e] : e - E;
    atomicAdd(&deg[d], 1);
}

// single-block exclusive scan of deg[0..n) -> rowptr[0..n]
__global__ __launch_bounds__(1024) void scan_kernel(const int* __restrict__ deg,
                                                    int* __restrict__ rowptr,
                                                    int n, int total) {
    __shared__ int ssum[1024];
    const int CH = (NN + 1023) / 1024;   // 20
    int t = threadIdx.x;
    int base = t * CH;
    int s = 0;
    for (int i = 0; i < CH; i++) {
        int idx = base + i;
        if (idx < n) s += deg[idx];
    }
    ssum[t] = s;
    __syncthreads();
    for (int off = 1; off < 1024; off <<= 1) {
        int v = (t >= off) ? ssum[t - off] : 0;
        __syncthreads();
        ssum[t] += v;
        __syncthreads();
    }
    int pre = ssum[t] - s;   // exclusive prefix for this thread's chunk
    for (int i = 0; i < CH; i++) {
        int idx = base + i;
        if (idx < n) { rowptr[idx] = pre; pre += deg[idx]; }
    }
    if (t == 0) rowptr[n] = total;
}

__global__ void scatter_kernel(const int* __restrict__ ei, const int* __restrict__ rowptr,
                               int* __restrict__ cursor, int* __restrict__ esrc,
                               int E, int Np) {
    int e = blockIdx.x * blockDim.x + threadIdx.x;
    if (e >= E + Np) return;
    int s = (e < E) ? ei[e] : e - E;
    int d = (e < E) ? ei[E + e] : e - E;
    int slot = rowptr[d] + atomicAdd(&cursor[d], 1);
    esrc[slot] = s;
}

// ---------------- f32 tiled GEMM: C[M,Nn] = A[M,K] @ B[K,Nn] ----------------
__global__ __launch_bounds__(256) void gemm_f32(const float* __restrict__ A,
                                                const float* __restrict__ B,
                                                float* __restrict__ C,
                                                int M, int Nn, int K) {
    __shared__ float As[16][64];
    __shared__ float Bs[16][64];
    int tid = threadIdx.x;
    int bm = blockIdx.y * 64, bn = blockIdx.x * 64;
    int tx = tid & 15, ty = tid >> 4;
    float acc[4][4] = {};
    int ar = tid >> 2;          // 0..63
    int ac = (tid & 3) << 2;    // 0,4,8,12
    int br = tid >> 4;          // 0..15
    int bc = (tid & 15) << 2;   // 0..60
    for (int k0 = 0; k0 < K; k0 += 16) {
        float4 av = make_float4(0.f, 0.f, 0.f, 0.f);
        if (bm + ar < M) av = *(const float4*)(A + (size_t)(bm + ar) * K + k0 + ac);
        float4 bv = *(const float4*)(B + (size_t)(k0 + br) * Nn + bn + bc);
        As[ac + 0][ar] = av.x; As[ac + 1][ar] = av.y;
        As[ac + 2][ar] = av.z; As[ac + 3][ar] = av.w;
        *(float4*)&Bs[br][bc] = bv;
        __syncthreads();
#pragma unroll
        for (int kk = 0; kk < 16; kk++) {
            float4 a = *(const float4*)&As[kk][ty << 2];
            float4 b = *(const float4*)&Bs[kk][tx << 2];
            float avr[4] = {a.x, a.y, a.z, a.w};
            float bvr[4] = {b.x, b.y, b.z, b.w};
#pragma unroll
            for (int i = 0; i < 4; i++)
#pragma unroll
                for (int j = 0; j < 4; j++)
                    acc[i][j] = fmaf(avr[i], bvr[j], acc[i][j]);
        }
        __syncthreads();
    }
#pragma unroll
    for (int i = 0; i < 4; i++) {
        int row = bm + (ty << 2) + i;
        if (row < M) {
            float4 o = make_float4(acc[i][0], acc[i][1], acc[i][2], acc[i][3]);
            *(float4*)(C + (size_t)row * Nn + bn + (tx << 2)) = o;
        }
    }
}

// ---------------- attention logits: per (node, head) wave dot ----------------
__global__ void alpha_kernel(const float* __restrict__ h,
                             const float* __restrict__ a_s,
                             const float* __restrict__ a_d,
                             float* __restrict__ as_out, float* __restrict__ ad_out,
                             int H, int C) {
    int n = blockIdx.x;
    int wv = threadIdx.x >> 6, ln = threadIdx.x & 63;
    const float* hr = h + ((size_t)n * H + wv) * C;
    float ss = 0.f, sd = 0.f;
    for (int c = ln; c < C; c += 64) {
        float v = hr[c];
        ss = fmaf(v, a_s[wv * C + c], ss);
        sd = fmaf(v, a_d[wv * C + c], sd);
    }
    for (int o = 32; o > 0; o >>= 1) {
        ss += __shfl_down(ss, o);
        sd += __shfl_down(sd, o);
    }
    if (ln == 0) { as_out[n * H + wv] = ss; ad_out[n * H + wv] = sd; }
}

// ---------------- fused per-node softmax + aggregation (no atomics) ----------------
// one wave per (node, head); lane owns 2 channels (C=128)
template <int H>
__global__ __launch_bounds__(256) void node_attn(const int* __restrict__ rowptr,
                                                 const int* __restrict__ esrc,
                                                 const float* __restrict__ as,
                                                 const float* __restrict__ ad,
                                                 const float* __restrict__ h,
                                                 float* __restrict__ out) {
    int lane = threadIdx.x & 63;
    int wid = blockIdx.x * 4 + (threadIdx.x >> 6);
    if (wid >= NN * H) return;
    int n = wid / H, hh = wid % H;
    int beg = rowptr[n], end = rowptr[n + 1];
    float adn = ad[n * H + hh];
    // phase A: segment max (lane-strided)
    float m = -INFINITY;
    for (int j = beg + lane; j < end; j += 64) {
        float v = leaky(as[esrc[j] * H + hh] + adn);
        m = fmaxf(m, v);
    }
#pragma unroll
    for (int o = 32; o > 0; o >>= 1) m = fmaxf(m, __shfl_xor(m, o));
    // phase B: softmax denom
    float sum = 0.f;
    for (int j = beg + lane; j < end; j += 64) {
        sum += __expf(leaky(as[esrc[j] * H + hh] + adn) - m);
    }
#pragma unroll
    for (int o = 32; o > 0; o >>= 1) sum += __shfl_xor(sum, o);
    float inv = 1.f / (sum + 1e-16f);
    // phase C: weighted gather-accumulate; w recomputed wave-uniformly per edge
    float2 acc = make_float2(0.f, 0.f);
    const float* hbase = h + (size_t)hh * CONVD + lane * 2;
    for (int j = beg; j < end; j++) {
        int s = esrc[j];
        float w = __expf(leaky(as[s * H + hh] + adn) - m) * inv;
        float2 hv = *(const float2*)(hbase + (size_t)s * (CONVD * H));
        acc.x = fmaf(w, hv.x, acc.x);
        acc.y = fmaf(w, hv.y, acc.y);
    }
    *(float2*)(out + ((size_t)n * H + hh) * CONVD + lane * 2) = acc;
}

// ---------------- BN stats: per-column sum / sumsq of (x + bias) ----------------
__global__ void bn_stats(const float* __restrict__ x, const float* __restrict__ bias,
                         float* __restrict__ stats, int Nn, int C) {
    const int ROWS = 64;
    int r0 = blockIdx.x * ROWS;
    int rend = min(r0 + ROWS, Nn);
    for (int c = threadIdx.x; c < C; c += blockDim.x) {
        float b = bias[c];
        float s1 = 0.f, s2 = 0.f;
        for (int r = r0; r < rend; r++) {
            float v = x[(size_t)r * C + c] + b;
            s1 += v;
            s2 = fmaf(v, v, s2);
        }
        atomicAdd(&stats[c], s1);
        atomicAdd(&stats[C + c], s2);
    }
}

// ---------------- BN apply + ReLU (in place ok) ----------------
__global__ void bn_apply(const float* __restrict__ x, const float* __restrict__ bias,
                         const float* __restrict__ stats,
                         const float* __restrict__ gamma, const float* __restrict__ beta,
                         float* __restrict__ y, int Nn, int C) {
    int idx = blockIdx.x * blockDim.x + threadIdx.x;
    if (idx >= Nn * C) return;
    int c = idx % C;
    float inv_n = 1.f / (float)Nn;
    float mu = stats[c] * inv_n;
    float var = stats[C + c] * inv_n - mu * mu;
    float v = (x[idx] + bias[c] - mu) * rsqrtf(var + EPS_BN);
    v = fmaf(gamma[c], v, beta[c]);
    y[idx] = v > 0.f ? v : 0.f;
}

// ---------------- global add pool ----------------
__global__ void pool_kernel(const float* __restrict__ h, const int* __restrict__ batch,
                            float* __restrict__ z) {
    int n = blockIdx.x, c = threadIdx.x;   // block = 128
    int b = batch[n];
    atomicAdd(&z[b * CONVD + c], h[(size_t)n * CONVD + c]);
}

// ---------------- fused MLP head: one block per graph ----------------
__global__ __launch_bounds__(320) void mlp_kernel(const float* __restrict__ g,
                           const float* __restrict__ extras,
                           const float* __restrict__ Wm1, const float* __restrict__ bm1,
                           const float* __restrict__ Wm2, const float* __restrict__ bm2,
                           const float* __restrict__ Wm3, const float* __restrict__ bm3,
                           float* __restrict__ out) {
    const int Z0 = CONVD + NXD;   // 137
    const int Z1 = NETD + NXD;    // 265
    const int Z2 = NETD;          // 256
    __shared__ float z[Z0];
    __shared__ float z1[Z1];
    __shared__ float z2[Z2];
    __shared__ float wred[5];
    int gi = blockIdx.x, t = threadIdx.x;
    if (t < CONVD) z[t] = g[gi * CONVD + t];
    else if (t < Z0) z[t] = extras[gi * NXD + (t - CONVD)];
    __syncthreads();
    if (t < Z1) {
        float acc = bm1[t];
        for (int k = 0; k < Z0; k++) acc = fmaf(z[k], Wm1[k * Z1 + t], acc);
        z1[t] = acc > 0.f ? acc : 0.f;
    }
    __syncthreads();
    if (t < Z2) {
        float acc = bm2[t];
        for (int k = 0; k < Z1; k++) acc = fmaf(z1[k], Wm2[k * Z2 + t], acc);
        z2[t] = acc > 0.f ? acc : 0.f;
    }
    __syncthreads();
    float partial = (t < Z2) ? z2[t] * Wm3[t] : 0.f;
    for (int o = 32; o > 0; o >>= 1) partial += __shfl_down(partial, o);
    int wv = t >> 6, ln = t & 63;
    if (ln == 0) wred[wv] = partial;
    __syncthreads();
    if (t == 0) {
        float s = bm3[0];
        for (int i = 0; i < 5; i++) s += wred[i];
        out[gi] = s;
    }
}

// ---------------- launch ----------------
extern "C" void kernel_launch(void* const* d_in, const int* in_sizes, int n_in,
                              void* d_out, int out_size, void* d_ws, size_t ws_size,
                              hipStream_t stream) {
    const float* x      = (const float*)d_in[0];
    const int*   ei     = (const int*)d_in[1];
    const int*   batch  = (const int*)d_in[2];
    const float* extras = (const float*)d_in[3];
    const float* W1     = (const float*)d_in[4];
    const float* a_s1   = (const float*)d_in[5];
    const float* a_d1   = (const float*)d_in[6];
    const float* b1     = (const float*)d_in[7];
    const float* W2     = (const float*)d_in[8];
    const float* a_s2   = (const float*)d_in[9];
    const float* a_d2   = (const float*)d_in[10];
    const float* b2     = (const float*)d_in[11];
    const float* gamma1 = (const float*)d_in[12];
    const float* beta1  = (const float*)d_in[13];
    const float* gamma2 = (const float*)d_in[14];
    const float* beta2  = (const float*)d_in[15];
    const float* Wm1    = (const float*)d_in[16];
    const float* bm1    = (const float*)d_in[17];
    const float* Wm2    = (const float*)d_in[18];
    const float* bm2    = (const float*)d_in[19];
    const float* Wm3    = (const float*)d_in[20];
    const float* bm3    = (const float*)d_in[21];
    float* out = (float*)d_out;

    const int N = NN, E = EE, EP = EE + NN;

    char* ws = (char*)d_ws;
    size_t off = 0;
    auto alloc = [&](size_t bytes) -> void* {
        void* pp = (void*)(ws + off);
        off += (bytes + 255) & ~(size_t)255;
        return pp;
    };
    // --- zero region (contiguous; one small memset) ---
    int*   deg    = (int*)alloc((size_t)N * 4);
    int*   cursor = (int*)alloc((size_t)N * 4);
    float* stats1 = (float*)alloc(512 * 2 * 4);
    float* stats2 = (float*)alloc(128 * 2 * 4);
    float* zbuf   = (float*)alloc((size_t)GG * CONVD * 4);
    size_t zero_bytes = off;
    // --- scratch (fully overwritten each launch) ---
    int*   rowptr = (int*)alloc((size_t)(N + 1) * 4);
    int*   esrc   = (int*)alloc((size_t)EP * 4);
    float* h1     = (float*)alloc((size_t)N * 512 * 4);
    float* h2     = (float*)alloc((size_t)N * 128 * 4);
    float* out1   = (float*)alloc((size_t)N * 512 * 4);
    float* out2   = (float*)alloc((size_t)N * 128 * 4);
    float* as1    = (float*)alloc((size_t)N * 4 * 4);
    float* ad1    = (float*)alloc((size_t)N * 4 * 4);
    float* as2    = (float*)alloc((size_t)N * 4);
    float* ad2    = (float*)alloc((size_t)N * 4);

    hipMemsetAsync(d_ws, 0, zero_bytes, stream);

    int eb = (EP + 255) / 256;
    int nrow = (N + 63) / 64;

    // ---- CSR build (dst-sorted adjacency) ----
    hist_kernel<<<eb, 256, 0, stream>>>(ei, deg, E, N);
    scan_kernel<<<1, 1024, 0, stream>>>(deg, rowptr, N, EP);
    scatter_kernel<<<eb, 256, 0, stream>>>(ei, rowptr, cursor, esrc, E, N);

    // ---- GAT layer 1 (H=4, concat) ----
    gemm_f32<<<dim3(512 / 64, nrow), 256, 0, stream>>>(x, W1, h1, N, 512, VIN);
    alpha_kernel<<<N, 4 * 64, 0, stream>>>(h1, a_s1, a_d1, as1, ad1, 4, CONVD);
    node_attn<4><<<(N * 4 + 3) / 4, 256, 0, stream>>>(rowptr, esrc, as1, ad1, h1, out1);
    bn_stats<<<nrow, 256, 0, stream>>>(out1, b1, stats1, N, 512);
    bn_apply<<<(N * 512 + 255) / 256, 256, 0, stream>>>(out1, b1, stats1, gamma1, beta1, out1, N, 512);

    // ---- GAT layer 2 (H=1) ----
    gemm_f32<<<dim3(128 / 64, nrow), 256, 0, stream>>>(out1, W2, h2, N, 128, 512);
    alpha_kernel<<<N, 64, 0, stream>>>(h2, a_s2, a_d2, as2, ad2, 1, CONVD);
    node_attn<1><<<(N + 3) / 4, 256, 0, stream>>>(rowptr, esrc, as2, ad2, h2, out2);
    bn_stats<<<nrow, 256, 0, stream>>>(out2, b2, stats2, N, 128);
    bn_apply<<<(N * 128 + 255) / 256, 256, 0, stream>>>(out2, b2, stats2, gamma2, beta2, out2, N, 128);

    // ---- pool + MLP head ----
    pool_kernel<<<N, 128, 0, stream>>>(out2, batch, zbuf);
    mlp_kernel<<<GG, 320, 0, stream>>>(zbuf, extras, Wm1, bm1, Wm2, bm2, Wm3, bm3, out);
}

// Round 3
// 512.362 us; speedup vs baseline: 2.8847x; 1.2901x over previous
//
#include <hip/hip_runtime.h>
#include <hip/hip_bf16.h>
#include <math.h>

// ---------------- constants (match reference) ----------------
#define NN 20000
#define EE 400000
#define GG 64
#define VIN 128
#define CONVD 128
#define NETD 256
#define NXD 9
#define EPS_BN 1e-5f
#define NEG_SLOPE 0.2f

typedef short short8 __attribute__((ext_vector_type(8)));
typedef float floatx4 __attribute__((ext_vector_type(4)));

__device__ __forceinline__ float leaky(float v) {
    return v >= 0.f ? v : NEG_SLOPE * v;
}
__device__ __forceinline__ unsigned short f2bf(float f) {
    union { float f; unsigned u; } v; v.f = f;
    unsigned r = v.u + 0x7FFFu + ((v.u >> 16) & 1u);   // RNE
    return (unsigned short)(r >> 16);
}
__device__ __forceinline__ float bf2f(unsigned u) {
    union { unsigned u; float f; } v; v.u = u << 16;
    return v.f;
}

// ---------------- cast f32 -> bf16 ----------------
__global__ void cast_bf(const float* __restrict__ in, unsigned short* __restrict__ out, int n) {
    int i = blockIdx.x * blockDim.x + threadIdx.x;
    if (i < n) out[i] = f2bf(in[i]);
}

// ---------------- pack B (f32 [K,Nn]) into MFMA B-fragment layout (bf16) ----------
// Bp[((nt*(K/32)+kt)*64 + lane)*8 + j] = bf16(B[kt*32 + (lane>>4)*8 + j][nt*16 + (lane&15)])
__global__ void pack_b(const float* __restrict__ B, unsigned short* __restrict__ Bp,
                       int K, int Nn) {
    int idx = blockIdx.x * blockDim.x + threadIdx.x;
    if (idx >= K * Nn) return;
    int j = idx & 7, lane = (idx >> 3) & 63, t = idx >> 9;
    int KT = K >> 5;
    int kt = t % KT, nt = t / KT;
    int k = kt * 32 + (lane >> 4) * 8 + j;
    int n = nt * 16 + (lane & 15);
    Bp[idx] = f2bf(B[(size_t)k * Nn + n]);
}

// ---------------- MFMA bf16 GEMM: C_bf16[M,Nn] = A_bf16[M,K] @ B ----------------
// one wave = 16 rows; block = 4 waves; blockIdx.y selects a NCOLS-wide column chunk
template <int K, int Nn, int NCOLS>
__global__ __launch_bounds__(256) void gemm_bf16(const unsigned short* __restrict__ A,
                                                 const unsigned short* __restrict__ Bp,
                                                 unsigned short* __restrict__ C, int M) {
    constexpr int KT = K / 32;
    constexpr int NT = NCOLS / 16;
    int wave = threadIdx.x >> 6, lane = threadIdx.x & 63;
    int row0 = (blockIdx.x * 4 + wave) * 16;
    if (row0 >= M) return;
    int r = lane & 15, quad = lane >> 4;
    int nt0 = blockIdx.y * NT;
    short8 af[KT];
    const unsigned short* arow = A + (size_t)(row0 + r) * K + quad * 8;
#pragma unroll
    for (int kt = 0; kt < KT; kt++) af[kt] = *(const short8*)(arow + kt * 32);
#pragma unroll
    for (int nt = 0; nt < NT; nt++) {
        floatx4 acc = {0.f, 0.f, 0.f, 0.f};
        const unsigned short* bbase = Bp + (((size_t)(nt0 + nt) * KT) << 9) + lane * 8;
#pragma unroll
        for (int kt = 0; kt < KT; kt++) {
            short8 bf = *(const short8*)(bbase + ((size_t)kt << 9));
            acc = __builtin_amdgcn_mfma_f32_16x16x32_bf16(af[kt], bf, acc, 0, 0, 0);
        }
        int col = (nt0 + nt) * 16 + r;
        unsigned short* cbase = C + (size_t)(row0 + quad * 4) * Nn + col;
#pragma unroll
        for (int reg = 0; reg < 4; reg++)
            cbase[(size_t)reg * Nn] = f2bf(acc[reg]);
    }
}

// ---------------- CSR build ----------------
__global__ void hist_kernel(const int* __restrict__ ei, int* __restrict__ deg,
                            int E, int Np) {
    int e = blockIdx.x * blockDim.x + threadIdx.x;
    if (e >= E + Np) return;
    int d = (e < E) ? ei[E + e] : e - E;
    atomicAdd(&deg[d], 1);
}

__global__ __launch_bounds__(1024) void scan_kernel(const int* __restrict__ deg,
                                                    int* __restrict__ rowptr,
                                                    int n, int total) {
    __shared__ int ssum[1024];
    const int CH = (NN + 1023) / 1024;   // 20
    int t = threadIdx.x;
    int base = t * CH;
    int s = 0;
    for (int i = 0; i < CH; i++) {
        int idx = base + i;
        if (idx < n) s += deg[idx];
    }
    ssum[t] = s;
    __syncthreads();
    for (int off = 1; off < 1024; off <<= 1) {
        int v = (t >= off) ? ssum[t - off] : 0;
        __syncthreads();
        ssum[t] += v;
        __syncthreads();
    }
    int pre = ssum[t] - s;
    for (int i = 0; i < CH; i++) {
        int idx = base + i;
        if (idx < n) { rowptr[idx] = pre; pre += deg[idx]; }
    }
    if (t == 0) rowptr[n] = total;
}

__global__ void scatter_kernel(const int* __restrict__ ei, const int* __restrict__ rowptr,
                               int* __restrict__ cursor, int* __restrict__ esrc,
                               int E, int Np) {
    int e = blockIdx.x * blockDim.x + threadIdx.x;
    if (e >= E + Np) return;
    int s = (e < E) ? ei[e] : e - E;
    int d = (e < E) ? ei[E + e] : e - E;
    int slot = rowptr[d] + atomicAdd(&cursor[d], 1);
    esrc[slot] = s;
}

// ---------------- attention logits (bf16 h): per (node, head) wave dot -----------
__global__ void alpha_bf(const unsigned short* __restrict__ h,
                         const float* __restrict__ a_s, const float* __restrict__ a_d,
                         float* __restrict__ as_out, float* __restrict__ ad_out, int H) {
    int n = blockIdx.x;
    int wv = threadIdx.x >> 6, ln = threadIdx.x & 63;
    const unsigned short* hr = h + ((size_t)n * H + wv) * CONVD + ln * 2;
    unsigned hv = *(const unsigned*)hr;
    float v0 = bf2f(hv & 0xffffu), v1 = bf2f(hv >> 16);
    int ci = wv * CONVD + ln * 2;
    float ss = v0 * a_s[ci] + v1 * a_s[ci + 1];
    float sd = v0 * a_d[ci] + v1 * a_d[ci + 1];
    for (int o = 32; o > 0; o >>= 1) { ss += __shfl_down(ss, o); sd += __shfl_down(sd, o); }
    if (ln == 0) { as_out[n * H + wv] = ss; ad_out[n * H + wv] = sd; }
}

// ---------------- fused per-node softmax + aggregation (gather, bf16 h) ----------
// one wave per (node, head); lane owns 2 channels (C=128)
template <int H>
__global__ __launch_bounds__(256) void node_attn(const int* __restrict__ rowptr,
                                                 const int* __restrict__ esrc,
                                                 const float* __restrict__ as,
                                                 const float* __restrict__ ad,
                                                 const unsigned short* __restrict__ h,
                                                 float* __restrict__ out) {
    int lane = threadIdx.x & 63;
    int wid = blockIdx.x * 4 + (threadIdx.x >> 6);
    if (wid >= NN * H) return;
    int n = wid / H, hh = wid % H;
    int beg = rowptr[n], end = rowptr[n + 1];
    float adn = ad[n * H + hh];
    // phase A: segment max
    float m = -INFINITY;
    for (int j = beg + lane; j < end; j += 64) {
        float v = leaky(as[esrc[j] * H + hh] + adn);
        m = fmaxf(m, v);
    }
#pragma unroll
    for (int o = 32; o > 0; o >>= 1) m = fmaxf(m, __shfl_xor(m, o));
    // phase B: softmax denom
    float sum = 0.f;
    for (int j = beg + lane; j < end; j += 64) {
        sum += __expf(leaky(as[esrc[j] * H + hh] + adn) - m);
    }
#pragma unroll
    for (int o = 32; o > 0; o >>= 1) sum += __shfl_xor(sum, o);
    float inv = 1.f / (sum + 1e-16f);
    // phase C: weighted gather-accumulate (2-way unrolled)
    float2 acc0 = make_float2(0.f, 0.f), acc1 = make_float2(0.f, 0.f);
    const unsigned short* hbase = h + (size_t)hh * CONVD + lane * 2;
    int j = beg;
    for (; j + 1 < end; j += 2) {
        int s0 = esrc[j], s1 = esrc[j + 1];
        float w0 = __expf(leaky(as[s0 * H + hh] + adn) - m) * inv;
        float w1 = __expf(leaky(as[s1 * H + hh] + adn) - m) * inv;
        unsigned hv0 = *(const unsigned*)(hbase + (size_t)s0 * (CONVD * H));
        unsigned hv1 = *(const unsigned*)(hbase + (size_t)s1 * (CONVD * H));
        acc0.x = fmaf(w0, bf2f(hv0 & 0xffffu), acc0.x);
        acc0.y = fmaf(w0, bf2f(hv0 >> 16), acc0.y);
        acc1.x = fmaf(w1, bf2f(hv1 & 0xffffu), acc1.x);
        acc1.y = fmaf(w1, bf2f(hv1 >> 16), acc1.y);
    }
    if (j < end) {
        int s0 = esrc[j];
        float w0 = __expf(leaky(as[s0 * H + hh] + adn) - m) * inv;
        unsigned hv0 = *(const unsigned*)(hbase + (size_t)s0 * (CONVD * H));
        acc0.x = fmaf(w0, bf2f(hv0 & 0xffffu), acc0.x);
        acc0.y = fmaf(w0, bf2f(hv0 >> 16), acc0.y);
    }
    float2 acc = make_float2(acc0.x + acc1.x, acc0.y + acc1.y);
    *(float2*)(out + ((size_t)n * H + hh) * CONVD + lane * 2) = acc;
}

// ---------------- BN stats: per-column sum / sumsq of (x + bias) ----------------
__global__ void bn_stats(const float* __restrict__ x, const float* __restrict__ bias,
                         float* __restrict__ stats, int Nn, int C) {
    const int ROWS = 64;
    int r0 = blockIdx.x * ROWS;
    int rend = min(r0 + ROWS, Nn);
    for (int c = threadIdx.x; c < C; c += blockDim.x) {
        float b = bias[c];
        float s1 = 0.f, s2 = 0.f;
        for (int r = r0; r < rend; r++) {
            float v = x[(size_t)r * C + c] + b;
            s1 += v;
            s2 = fmaf(v, v, s2);
        }
        atomicAdd(&stats[c], s1);
        atomicAdd(&stats[C + c], s2);
    }
}

// ---------------- BN apply + ReLU -> bf16 (layer-1 output feeds MFMA GEMM) -------
__global__ void bn_apply_bf(const float* __restrict__ x, const float* __restrict__ bias,
                            const float* __restrict__ stats,
                            const float* __restrict__ gamma, const float* __restrict__ beta,
                            unsigned short* __restrict__ y, int Nn, int C) {
    int idx = blockIdx.x * blockDim.x + threadIdx.x;
    if (idx >= Nn * C) return;
    int c = idx % C;
    float inv_n = 1.f / (float)Nn;
    float mu = stats[c] * inv_n;
    float var = stats[C + c] * inv_n - mu * mu;
    float v = (x[idx] + bias[c] - mu) * rsqrtf(var + EPS_BN);
    v = fmaf(gamma[c], v, beta[c]);
    y[idx] = f2bf(v > 0.f ? v : 0.f);
}

// ---------------- BN apply + ReLU -> f32 (layer-2 output feeds pool) -------------
__global__ void bn_apply_f32(const float* __restrict__ x, const float* __restrict__ bias,
                             const float* __restrict__ stats,
                             const float* __restrict__ gamma, const float* __restrict__ beta,
                             float* __restrict__ y, int Nn, int C) {
    int idx = blockIdx.x * blockDim.x + threadIdx.x;
    if (idx >= Nn * C) return;
    int c = idx % C;
    float inv_n = 1.f / (float)Nn;
    float mu = stats[c] * inv_n;
    float var = stats[C + c] * inv_n - mu * mu;
    float v = (x[idx] + bias[c] - mu) * rsqrtf(var + EPS_BN);
    v = fmaf(gamma[c], v, beta[c]);
    y[idx] = v > 0.f ? v : 0.f;
}

// ---------------- global add pool ----------------
__global__ void pool_kernel(const float* __restrict__ h, const int* __restrict__ batch,
                            float* __restrict__ z) {
    int n = blockIdx.x, c = threadIdx.x;   // block = 128
    int b = batch[n];
    atomicAdd(&z[b * CONVD + c], h[(size_t)n * CONVD + c]);
}

// ---------------- fused MLP head: one block per graph ----------------
__global__ __launch_bounds__(320) void mlp_kernel(const float* __restrict__ g,
                           const float* __restrict__ extras,
                           const float* __restrict__ Wm1, const float* __restrict__ bm1,
                           const float* __restrict__ Wm2, const float* __restrict__ bm2,
                           const float* __restrict__ Wm3, const float* __restrict__ bm3,
                           float* __restrict__ out) {
    const int Z0 = CONVD + NXD;   // 137
    const int Z1 = NETD + NXD;    // 265
    const int Z2 = NETD;          // 256
    __shared__ float z[Z0];
    __shared__ float z1[Z1];
    __shared__ float z2[Z2];
    __shared__ float wred[5];
    int gi = blockIdx.x, t = threadIdx.x;
    if (t < CONVD) z[t] = g[gi * CONVD + t];
    else if (t < Z0) z[t] = extras[gi * NXD + (t - CONVD)];
    __syncthreads();
    if (t < Z1) {
        float acc = bm1[t];
        for (int k = 0; k < Z0; k++) acc = fmaf(z[k], Wm1[k * Z1 + t], acc);
        z1[t] = acc > 0.f ? acc : 0.f;
    }
    __syncthreads();
    if (t < Z2) {
        float acc = bm2[t];
        for (int k = 0; k < Z1; k++) acc = fmaf(z1[k], Wm2[k * Z2 + t], acc);
        z2[t] = acc > 0.f ? acc : 0.f;
    }
    __syncthreads();
    float partial = (t < Z2) ? z2[t] * Wm3[t] : 0.f;
    for (int o = 32; o > 0; o >>= 1) partial += __shfl_down(partial, o);
    int wv = t >> 6, ln = t & 63;
    if (ln == 0) wred[wv] = partial;
    __syncthreads();
    if (t == 0) {
        float s = bm3[0];
        for (int i = 0; i < 5; i++) s += wred[i];
        out[gi] = s;
    }
}

// ---------------- launch ----------------
extern "C" void kernel_launch(void* const* d_in, const int* in_sizes, int n_in,
                              void* d_out, int out_size, void* d_ws, size_t ws_size,
                              hipStream_t stream) {
    const float* x      = (const float*)d_in[0];
    const int*   ei     = (const int*)d_in[1];
    const int*   batch  = (const int*)d_in[2];
    const float* extras = (const float*)d_in[3];
    const float* W1     = (const float*)d_in[4];
    const float* a_s1   = (const float*)d_in[5];
    const float* a_d1   = (const float*)d_in[6];
    const float* b1     = (const float*)d_in[7];
    const float* W2     = (const float*)d_in[8];
    const float* a_s2   = (const float*)d_in[9];
    const float* a_d2   = (const float*)d_in[10];
    const float* b2     = (const float*)d_in[11];
    const float* gamma1 = (const float*)d_in[12];
    const float* beta1  = (const float*)d_in[13];
    const float* gamma2 = (const float*)d_in[14];
    const float* beta2  = (const float*)d_in[15];
    const float* Wm1    = (const float*)d_in[16];
    const float* bm1    = (const float*)d_in[17];
    const float* Wm2    = (const float*)d_in[18];
    const float* bm2    = (const float*)d_in[19];
    const float* Wm3    = (const float*)d_in[20];
    const float* bm3    = (const float*)d_in[21];
    float* out = (float*)d_out;

    const int N = NN, E = EE, EP = EE + NN;

    char* ws = (char*)d_ws;
    size_t off = 0;
    auto alloc = [&](size_t bytes) -> void* {
        void* pp = (void*)(ws + off);
        off += (bytes + 255) & ~(size_t)255;
        return pp;
    };
    // --- zero region (contiguous; one small memset) ---
    int*   deg    = (int*)alloc((size_t)N * 4);
    int*   cursor = (int*)alloc((size_t)N * 4);
    float* stats1 = (float*)alloc(512 * 2 * 4);
    float* stats2 = (float*)alloc(128 * 2 * 4);
    float* zbuf   = (float*)alloc((size_t)GG * CONVD * 4);
    size_t zero_bytes = off;
    // --- scratch (fully overwritten each launch) ---
    int*   rowptr = (int*)alloc((size_t)(N + 1) * 4);
    int*   esrc   = (int*)alloc((size_t)EP * 4);
    unsigned short* xb   = (unsigned short*)alloc((size_t)N * VIN * 2);
    unsigned short* W1p  = (unsigned short*)alloc((size_t)VIN * 512 * 2);
    unsigned short* W2p  = (unsigned short*)alloc((size_t)512 * 128 * 2);
    unsigned short* h1b  = (unsigned short*)alloc((size_t)N * 512 * 2);
    unsigned short* h2b  = (unsigned short*)alloc((size_t)N * 128 * 2);
    unsigned short* o1b  = (unsigned short*)alloc((size_t)N * 512 * 2);
    float* out1   = (float*)alloc((size_t)N * 512 * 4);
    float* out2   = (float*)alloc((size_t)N * 128 * 4);
    float* as1    = (float*)alloc((size_t)N * 4 * 4);
    float* ad1    = (float*)alloc((size_t)N * 4 * 4);
    float* as2    = (float*)alloc((size_t)N * 4);
    float* ad2    = (float*)alloc((size_t)N * 4);

    hipMemsetAsync(d_ws, 0, zero_bytes, stream);

    int eb = (EP + 255) / 256;
    int nrow = (N + 63) / 64;
    int mblk = (N + 63) / 64;   // gemm blocks along M (4 waves x 16 rows)

    // ---- casts / weight packing ----
    cast_bf<<<(N * VIN + 255) / 256, 256, 0, stream>>>(x, xb, N * VIN);
    pack_b<<<(VIN * 512 + 255) / 256, 256, 0, stream>>>(W1, W1p, VIN, 512);
    pack_b<<<(512 * 128 + 255) / 256, 256, 0, stream>>>(W2, W2p, 512, 128);

    // ---- CSR build (dst-sorted adjacency) ----
    hist_kernel<<<eb, 256, 0, stream>>>(ei, deg, E, N);
    scan_kernel<<<1, 1024, 0, stream>>>(deg, rowptr, N, EP);
    scatter_kernel<<<eb, 256, 0, stream>>>(ei, rowptr, cursor, esrc, E, N);

    // ---- GAT layer 1 (H=4, concat) ----
    gemm_bf16<VIN, 512, 128><<<dim3(mblk, 4), 256, 0, stream>>>(xb, W1p, h1b, N);
    alpha_bf<<<N, 4 * 64, 0, stream>>>(h1b, a_s1, a_d1, as1, ad1, 4);
    node_attn<4><<<(N * 4 + 3) / 4, 256, 0, stream>>>(rowptr, esrc, as1, ad1, h1b, out1);
    bn_stats<<<nrow, 256, 0, stream>>>(out1, b1, stats1, N, 512);
    bn_apply_bf<<<(N * 512 + 255) / 256, 256, 0, stream>>>(out1, b1, stats1, gamma1, beta1, o1b, N, 512);

    // ---- GAT layer 2 (H=1) ----
    gemm_bf16<512, 128, 64><<<dim3(mblk, 2), 256, 0, stream>>>(o1b, W2p, h2b, N);
    alpha_bf<<<N, 64, 0, stream>>>(h2b, a_s2, a_d2, as2, ad2, 1);
    node_attn<1><<<(N + 3) / 4, 256, 0, stream>>>(rowptr, esrc, as2, ad2, h2b, out2);
    bn_stats<<<nrow, 256, 0, stream>>>(out2, b2, stats2, N, 128);
    bn_apply_f32<<<(N * 128 + 255) / 256, 256, 0, stream>>>(out2, b2, stats2, gamma2, beta2, out2, N, 128);

    // ---- pool + MLP head ----
    pool_kernel<<<N, 128, 0, stream>>>(out2, batch, zbuf);
    mlp_kernel<<<GG, 320, 0, stream>>>(zbuf, extras, Wm1, bm1, Wm2, bm2, Wm3, bm3, out);
}

// Round 4
// 462.647 us; speedup vs baseline: 3.1946x; 1.1075x over previous
//
#include <hip/hip_runtime.h>
#include <hip/hip_bf16.h>
#include <math.h>

// ---------------- constants (match reference) ----------------
#define NN 20000
#define EE 400000
#define GG 64
#define VIN 128
#define CONVD 128
#define NETD 256
#define NXD 9
#define EPS_BN 1e-5f
#define NEG_SLOPE 0.2f

typedef short short8 __attribute__((ext_vector_type(8)));
typedef float floatx4 __attribute__((ext_vector_type(4)));

__device__ __forceinline__ float leaky(float v) {
    return v >= 0.f ? v : NEG_SLOPE * v;
}
__device__ __forceinline__ unsigned short f2bf(float f) {
    union { float f; unsigned u; } v; v.f = f;
    unsigned r = v.u + 0x7FFFu + ((v.u >> 16) & 1u);   // RNE
    return (unsigned short)(r >> 16);
}
__device__ __forceinline__ float bf2f(unsigned short u) {
    union { unsigned u; float f; } v; v.u = ((unsigned)u) << 16;
    return v.f;
}

// ---------------- cast f32 -> bf16 ----------------
__global__ void cast_bf(const float* __restrict__ in, unsigned short* __restrict__ out, int n) {
    int i = blockIdx.x * blockDim.x + threadIdx.x;
    if (i < n) out[i] = f2bf(in[i]);
}

// ---------------- pack B (f32 [K,Nn]) into MFMA B-fragment layout (bf16) ----------
__global__ void pack_b(const float* __restrict__ B, unsigned short* __restrict__ Bp,
                       int K, int Nn) {
    int idx = blockIdx.x * blockDim.x + threadIdx.x;
    if (idx >= K * Nn) return;
    int j = idx & 7, lane = (idx >> 3) & 63, t = idx >> 9;
    int KT = K >> 5;
    int kt = t % KT, nt = t / KT;
    int k = kt * 32 + (lane >> 4) * 8 + j;
    int n = nt * 16 + (lane & 15);
    Bp[idx] = f2bf(B[(size_t)k * Nn + n]);
}

// ---------------- MFMA bf16 GEMM: C_bf16[M,Nn] = A_bf16[M,K] @ B ----------------
template <int K, int Nn, int NCOLS>
__global__ __launch_bounds__(256) void gemm_bf16(const unsigned short* __restrict__ A,
                                                 const unsigned short* __restrict__ Bp,
                                                 unsigned short* __restrict__ C, int M) {
    constexpr int KT = K / 32;
    constexpr int NT = NCOLS / 16;
    int wave = threadIdx.x >> 6, lane = threadIdx.x & 63;
    int row0 = (blockIdx.x * 4 + wave) * 16;
    if (row0 >= M) return;
    int r = lane & 15, quad = lane >> 4;
    int nt0 = blockIdx.y * NT;
    short8 af[KT];
    const unsigned short* arow = A + (size_t)(row0 + r) * K + quad * 8;
#pragma unroll
    for (int kt = 0; kt < KT; kt++) af[kt] = *(const short8*)(arow + kt * 32);
#pragma unroll
    for (int nt = 0; nt < NT; nt++) {
        floatx4 acc = {0.f, 0.f, 0.f, 0.f};
        const unsigned short* bbase = Bp + (((size_t)(nt0 + nt) * KT) << 9) + lane * 8;
#pragma unroll
        for (int kt = 0; kt < KT; kt++) {
            short8 bf = *(const short8*)(bbase + ((size_t)kt << 9));
            acc = __builtin_amdgcn_mfma_f32_16x16x32_bf16(af[kt], bf, acc, 0, 0, 0);
        }
        int col = (nt0 + nt) * 16 + r;
        unsigned short* cbase = C + (size_t)(row0 + quad * 4) * Nn + col;
#pragma unroll
        for (int reg = 0; reg < 4; reg++)
            cbase[(size_t)reg * Nn] = f2bf(acc[reg]);
    }
}

// ---------------- CSR build ----------------
__global__ void hist_kernel(const int* __restrict__ ei, int* __restrict__ deg,
                            int E, int Np) {
    int e = blockIdx.x * blockDim.x + threadIdx.x;
    if (e >= E + Np) return;
    int d = (e < E) ? ei[E + e] : e - E;
    atomicAdd(&deg[d], 1);
}

__global__ __launch_bounds__(1024) void scan_kernel(const int* __restrict__ deg,
                                                    int* __restrict__ rowptr,
                                                    int n, int total) {
    __shared__ int ssum[1024];
    const int CH = (NN + 1023) / 1024;   // 20
    int t = threadIdx.x;
    int base = t * CH;
    int s = 0;
    for (int i = 0; i < CH; i++) {
        int idx = base + i;
        if (idx < n) s += deg[idx];
    }
    ssum[t] = s;
    __syncthreads();
    for (int off = 1; off < 1024; off <<= 1) {
        int v = (t >= off) ? ssum[t - off] : 0;
        __syncthreads();
        ssum[t] += v;
        __syncthreads();
    }
    int pre = ssum[t] - s;
    for (int i = 0; i < CH; i++) {
        int idx = base + i;
        if (idx < n) { rowptr[idx] = pre; pre += deg[idx]; }
    }
    if (t == 0) rowptr[n] = total;
}

__global__ void scatter_kernel(const int* __restrict__ ei, const int* __restrict__ rowptr,
                               int* __restrict__ cursor, int* __restrict__ esrc,
                               int E, int Np) {
    int e = blockIdx.x * blockDim.x + threadIdx.x;
    if (e >= E + Np) return;
    int s = (e < E) ? ei[e] : e - E;
    int d = (e < E) ? ei[E + e] : e - E;
    int slot = rowptr[d] + atomicAdd(&cursor[d], 1);
    esrc[slot] = s;
}

// ---------------- attention logits (bf16 h): per (node, head) wave dot -----------
__global__ void alpha_bf(const unsigned short* __restrict__ h,
                         const float* __restrict__ a_s, const float* __restrict__ a_d,
                         float* __restrict__ as_out, float* __restrict__ ad_out, int H) {
    int n = blockIdx.x;
    int wv = threadIdx.x >> 6, ln = threadIdx.x & 63;
    const unsigned short* hr = h + ((size_t)n * H + wv) * CONVD + ln * 2;
    unsigned hv = *(const unsigned*)hr;
    float v0 = bf2f((unsigned short)(hv & 0xffffu)), v1 = bf2f((unsigned short)(hv >> 16));
    int ci = wv * CONVD + ln * 2;
    float ss = v0 * a_s[ci] + v1 * a_s[ci + 1];
    float sd = v0 * a_d[ci] + v1 * a_d[ci + 1];
    for (int o = 32; o > 0; o >>= 1) { ss += __shfl_down(ss, o); sd += __shfl_down(sd, o); }
    if (ln == 0) { as_out[n * H + wv] = ss; ad_out[n * H + wv] = sd; }
}

// ---------------- per-node softmax, H=4: store unnormalized p + 1/sum ------------
__global__ __launch_bounds__(256) void node_softmax4(const int* __restrict__ rowptr,
                                                     const int* __restrict__ esrc,
                                                     const float* __restrict__ as4,
                                                     const float* __restrict__ ad4,
                                                     float* __restrict__ w,
                                                     float* __restrict__ winv) {
    int lane = threadIdx.x & 63;
    int n = blockIdx.x * 4 + (threadIdx.x >> 6);
    if (n >= NN) return;
    int beg = rowptr[n], end = rowptr[n + 1];
    float4 adn = *(const float4*)(ad4 + (size_t)n * 4);
    float m0 = -INFINITY, m1 = -INFINITY, m2 = -INFINITY, m3 = -INFINITY;
    for (int j = beg + lane; j < end; j += 64) {
        int s = esrc[j];
        float4 av = *(const float4*)(as4 + (size_t)s * 4);
        m0 = fmaxf(m0, leaky(av.x + adn.x));
        m1 = fmaxf(m1, leaky(av.y + adn.y));
        m2 = fmaxf(m2, leaky(av.z + adn.z));
        m3 = fmaxf(m3, leaky(av.w + adn.w));
    }
#pragma unroll
    for (int o = 32; o > 0; o >>= 1) {
        m0 = fmaxf(m0, __shfl_xor(m0, o));
        m1 = fmaxf(m1, __shfl_xor(m1, o));
        m2 = fmaxf(m2, __shfl_xor(m2, o));
        m3 = fmaxf(m3, __shfl_xor(m3, o));
    }
    float s0 = 0.f, s1 = 0.f, s2 = 0.f, s3 = 0.f;
    for (int j = beg + lane; j < end; j += 64) {
        int s = esrc[j];
        float4 av = *(const float4*)(as4 + (size_t)s * 4);
        float p0 = __expf(leaky(av.x + adn.x) - m0);
        float p1 = __expf(leaky(av.y + adn.y) - m1);
        float p2 = __expf(leaky(av.z + adn.z) - m2);
        float p3 = __expf(leaky(av.w + adn.w) - m3);
        *(float4*)(w + (size_t)j * 4) = make_float4(p0, p1, p2, p3);
        s0 += p0; s1 += p1; s2 += p2; s3 += p3;
    }
#pragma unroll
    for (int o = 32; o > 0; o >>= 1) {
        s0 += __shfl_xor(s0, o);
        s1 += __shfl_xor(s1, o);
        s2 += __shfl_xor(s2, o);
        s3 += __shfl_xor(s3, o);
    }
    if (lane == 0) {
        *(float4*)(winv + (size_t)n * 4) = make_float4(
            1.f / (s0 + 1e-16f), 1.f / (s1 + 1e-16f),
            1.f / (s2 + 1e-16f), 1.f / (s3 + 1e-16f));
    }
}

// ---------------- per-node softmax, H=1 ----------------
__global__ __launch_bounds__(256) void node_softmax1(const int* __restrict__ rowptr,
                                                     const int* __restrict__ esrc,
                                                     const float* __restrict__ as,
                                                     const float* __restrict__ ad,
                                                     float* __restrict__ w,
                                                     float* __restrict__ winv) {
    int lane = threadIdx.x & 63;
    int n = blockIdx.x * 4 + (threadIdx.x >> 6);
    if (n >= NN) return;
    int beg = rowptr[n], end = rowptr[n + 1];
    float adn = ad[n];
    float m = -INFINITY;
    for (int j = beg + lane; j < end; j += 64)
        m = fmaxf(m, leaky(as[esrc[j]] + adn));
#pragma unroll
    for (int o = 32; o > 0; o >>= 1) m = fmaxf(m, __shfl_xor(m, o));
    float sum = 0.f;
    for (int j = beg + lane; j < end; j += 64) {
        float p = __expf(leaky(as[esrc[j]] + adn) - m);
        w[j] = p;
        sum += p;
    }
#pragma unroll
    for (int o = 32; o > 0; o >>= 1) sum += __shfl_xor(sum, o);
    if (lane == 0) winv[n] = 1.f / (sum + 1e-16f);
}

// ---------------- aggregation H=4: one wave per node; lane owns 8 of 512 ch ------
__global__ __launch_bounds__(256) void node_aggr4(const int* __restrict__ rowptr,
                                                  const int* __restrict__ esrc,
                                                  const float* __restrict__ w,
                                                  const float* __restrict__ winv,
                                                  const unsigned short* __restrict__ h,
                                                  unsigned short* __restrict__ outb) {
    int lane = threadIdx.x & 63;
    int n = blockIdx.x * 4 + (threadIdx.x >> 6);
    if (n >= NN) return;
    int beg = rowptr[n], end = rowptr[n + 1];
    int hh = lane >> 4;                 // head owning this lane's 8 channels
    float inv = winv[(size_t)n * 4 + hh];
    float acc[8] = {};
    const unsigned short* hbase = h + lane * 8;
    int j = beg;
    for (; j + 1 < end; j += 2) {
        int sA = esrc[j], sB = esrc[j + 1];
        float pA = w[(size_t)j * 4 + hh];
        float pB = w[(size_t)(j + 1) * 4 + hh];
        short8 hvA = *(const short8*)(hbase + (size_t)sA * 512);
        short8 hvB = *(const short8*)(hbase + (size_t)sB * 512);
#pragma unroll
        for (int i = 0; i < 8; i++) acc[i] = fmaf(pA, bf2f((unsigned short)hvA[i]), acc[i]);
#pragma unroll
        for (int i = 0; i < 8; i++) acc[i] = fmaf(pB, bf2f((unsigned short)hvB[i]), acc[i]);
    }
    if (j < end) {
        int sA = esrc[j];
        float pA = w[(size_t)j * 4 + hh];
        short8 hvA = *(const short8*)(hbase + (size_t)sA * 512);
#pragma unroll
        for (int i = 0; i < 8; i++) acc[i] = fmaf(pA, bf2f((unsigned short)hvA[i]), acc[i]);
    }
    short8 o;
#pragma unroll
    for (int i = 0; i < 8; i++) o[i] = (short)f2bf(acc[i] * inv);
    *(short8*)(outb + (size_t)n * 512 + lane * 8) = o;
}

// ---------------- aggregation H=1: one wave per node; lane owns 2 of 128 ch ------
__global__ __launch_bounds__(256) void node_aggr1(const int* __restrict__ rowptr,
                                                  const int* __restrict__ esrc,
                                                  const float* __restrict__ w,
                                                  const float* __restrict__ winv,
                                                  const unsigned short* __restrict__ h,
                                                  float* __restrict__ out) {
    int lane = threadIdx.x & 63;
    int n = blockIdx.x * 4 + (threadIdx.x >> 6);
    if (n >= NN) return;
    int beg = rowptr[n], end = rowptr[n + 1];
    float inv = winv[n];
    float2 acc = make_float2(0.f, 0.f);
    const unsigned short* hbase = h + lane * 2;
    int j = beg;
    for (; j + 1 < end; j += 2) {
        int sA = esrc[j], sB = esrc[j + 1];
        float pA = w[j], pB = w[j + 1];
        unsigned hvA = *(const unsigned*)(hbase + (size_t)sA * CONVD);
        unsigned hvB = *(const unsigned*)(hbase + (size_t)sB * CONVD);
        acc.x = fmaf(pA, bf2f((unsigned short)(hvA & 0xffffu)), acc.x);
        acc.y = fmaf(pA, bf2f((unsigned short)(hvA >> 16)), acc.y);
        acc.x = fmaf(pB, bf2f((unsigned short)(hvB & 0xffffu)), acc.x);
        acc.y = fmaf(pB, bf2f((unsigned short)(hvB >> 16)), acc.y);
    }
    if (j < end) {
        int sA = esrc[j];
        float pA = w[j];
        unsigned hvA = *(const unsigned*)(hbase + (size_t)sA * CONVD);
        acc.x = fmaf(pA, bf2f((unsigned short)(hvA & 0xffffu)), acc.x);
        acc.y = fmaf(pA, bf2f((unsigned short)(hvA >> 16)), acc.y);
    }
    *(float2*)(out + (size_t)n * CONVD + lane * 2) = make_float2(acc.x * inv, acc.y * inv);
}

// ---------------- BN stats (bf16 input): per-column sum / sumsq of (x + bias) ----
__global__ void bn_stats_bf(const unsigned short* __restrict__ x, const float* __restrict__ bias,
                            float* __restrict__ stats, int Nn, int C) {
    const int ROWS = 64;
    int r0 = blockIdx.x * ROWS;
    int rend = min(r0 + ROWS, Nn);
    for (int c = threadIdx.x; c < C; c += blockDim.x) {
        float b = bias[c];
        float s1 = 0.f, s2 = 0.f;
        for (int r = r0; r < rend; r++) {
            float v = bf2f(x[(size_t)r * C + c]) + b;
            s1 += v;
            s2 = fmaf(v, v, s2);
        }
        atomicAdd(&stats[c], s1);
        atomicAdd(&stats[C + c], s2);
    }
}

// ---------------- BN stats (f32 input) ----------------
__global__ void bn_stats_f32(const float* __restrict__ x, const float* __restrict__ bias,
                             float* __restrict__ stats, int Nn, int C) {
    const int ROWS = 64;
    int r0 = blockIdx.x * ROWS;
    int rend = min(r0 + ROWS, Nn);
    for (int c = threadIdx.x; c < C; c += blockDim.x) {
        float b = bias[c];
        float s1 = 0.f, s2 = 0.f;
        for (int r = r0; r < rend; r++) {
            float v = x[(size_t)r * C + c] + b;
            s1 += v;
            s2 = fmaf(v, v, s2);
        }
        atomicAdd(&stats[c], s1);
        atomicAdd(&stats[C + c], s2);
    }
}

// ---------------- BN apply + ReLU, bf16 in -> bf16 out (feeds GEMM2) -------------
__global__ void bn_apply_bf(const unsigned short* __restrict__ x, const float* __restrict__ bias,
                            const float* __restrict__ stats,
                            const float* __restrict__ gamma, const float* __restrict__ beta,
                            unsigned short* __restrict__ y, int Nn, int C) {
    int idx = blockIdx.x * blockDim.x + threadIdx.x;
    if (idx >= Nn * C) return;
    int c = idx % C;
    float inv_n = 1.f / (float)Nn;
    float mu = stats[c] * inv_n;
    float var = stats[C + c] * inv_n - mu * mu;
    float v = (bf2f(x[idx]) + bias[c] - mu) * rsqrtf(var + EPS_BN);
    v = fmaf(gamma[c], v, beta[c]);
    y[idx] = f2bf(v > 0.f ? v : 0.f);
}

// ---------------- BN apply + ReLU + pool (layer 2, fused) ------------------------
__global__ void bn_apply_pool(const float* __restrict__ x, const float* __restrict__ bias,
                              const float* __restrict__ stats,
                              const float* __restrict__ gamma, const float* __restrict__ beta,
                              const int* __restrict__ batch, float* __restrict__ z,
                              int Nn, int C) {
    int idx = blockIdx.x * blockDim.x + threadIdx.x;
    if (idx >= Nn * C) return;
    int c = idx % C;
    int n = idx / C;
    float inv_n = 1.f / (float)Nn;
    float mu = stats[c] * inv_n;
    float var = stats[C + c] * inv_n - mu * mu;
    float v = (x[idx] + bias[c] - mu) * rsqrtf(var + EPS_BN);
    v = fmaf(gamma[c], v, beta[c]);
    v = v > 0.f ? v : 0.f;
    atomicAdd(&z[batch[n] * C + c], v);
}

// ---------------- fused MLP head: one block per graph ----------------
__global__ __launch_bounds__(320) void mlp_kernel(const float* __restrict__ g,
                           const float* __restrict__ extras,
                           const float* __restrict__ Wm1, const float* __restrict__ bm1,
                           const float* __restrict__ Wm2, const float* __restrict__ bm2,
                           const float* __restrict__ Wm3, const float* __restrict__ bm3,
                           float* __restrict__ out) {
    const int Z0 = CONVD + NXD;   // 137
    const int Z1 = NETD + NXD;    // 265
    const int Z2 = NETD;          // 256
    __shared__ float z[Z0];
    __shared__ float z1[Z1];
    __shared__ float z2[Z2];
    __shared__ float wred[5];
    int gi = blockIdx.x, t = threadIdx.x;
    if (t < CONVD) z[t] = g[gi * CONVD + t];
    else if (t < Z0) z[t] = extras[gi * NXD + (t - CONVD)];
    __syncthreads();
    if (t < Z1) {
        float acc = bm1[t];
        for (int k = 0; k < Z0; k++) acc = fmaf(z[k], Wm1[k * Z1 + t], acc);
        z1[t] = acc > 0.f ? acc : 0.f;
    }
    __syncthreads();
    if (t < Z2) {
        float acc = bm2[t];
        for (int k = 0; k < Z1; k++) acc = fmaf(z1[k], Wm2[k * Z2 + t], acc);
        z2[t] = acc > 0.f ? acc : 0.f;
    }
    __syncthreads();
    float partial = (t < Z2) ? z2[t] * Wm3[t] : 0.f;
    for (int o = 32; o > 0; o >>= 1) partial += __shfl_down(partial, o);
    int wv = t >> 6, ln = t & 63;
    if (ln == 0) wred[wv] = partial;
    __syncthreads();
    if (t == 0) {
        float s = bm3[0];
        for (int i = 0; i < 5; i++) s += wred[i];
        out[gi] = s;
    }
}

// ---------------- launch ----------------
extern "C" void kernel_launch(void* const* d_in, const int* in_sizes, int n_in,
                              void* d_out, int out_size, void* d_ws, size_t ws_size,
                              hipStream_t stream) {
    const float* x      = (const float*)d_in[0];
    const int*   ei     = (const int*)d_in[1];
    const int*   batch  = (const int*)d_in[2];
    const float* extras = (const float*)d_in[3];
    const float* W1     = (const float*)d_in[4];
    const float* a_s1   = (const float*)d_in[5];
    const float* a_d1   = (const float*)d_in[6];
    const float* b1     = (const float*)d_in[7];
    const float* W2     = (const float*)d_in[8];
    const float* a_s2   = (const float*)d_in[9];
    const float* a_d2   = (const float*)d_in[10];
    const float* b2     = (const float*)d_in[11];
    const float* gamma1 = (const float*)d_in[12];
    const float* beta1  = (const float*)d_in[13];
    const float* gamma2 = (const float*)d_in[14];
    const float* beta2  = (const float*)d_in[15];
    const float* Wm1    = (const float*)d_in[16];
    const float* bm1    = (const float*)d_in[17];
    const float* Wm2    = (const float*)d_in[18];
    const float* bm2    = (const float*)d_in[19];
    const float* Wm3    = (const float*)d_in[20];
    const float* bm3    = (const float*)d_in[21];
    float* out = (float*)d_out;

    const int N = NN, E = EE, EP = EE + NN;

    char* ws = (char*)d_ws;
    size_t off = 0;
    auto alloc = [&](size_t bytes) -> void* {
        void* pp = (void*)(ws + off);
        off += (bytes + 255) & ~(size_t)255;
        return pp;
    };
    // --- zero region (contiguous; one small memset) ---
    int*   deg    = (int*)alloc((size_t)N * 4);
    int*   cursor = (int*)alloc((size_t)N * 4);
    float* stats1 = (float*)alloc(512 * 2 * 4);
    float* stats2 = (float*)alloc(128 * 2 * 4);
    float* zbuf   = (float*)alloc((size_t)GG * CONVD * 4);
    size_t zero_bytes = off;
    // --- scratch (fully overwritten each launch) ---
    int*   rowptr = (int*)alloc((size_t)(N + 1) * 4);
    int*   esrc   = (int*)alloc((size_t)EP * 4);
    unsigned short* xb   = (unsigned short*)alloc((size_t)N * VIN * 2);
    unsigned short* W1p  = (unsigned short*)alloc((size_t)VIN * 512 * 2);
    unsigned short* W2p  = (unsigned short*)alloc((size_t)512 * 128 * 2);
    unsigned short* h1b  = (unsigned short*)alloc((size_t)N * 512 * 2);
    unsigned short* h2b  = (unsigned short*)alloc((size_t)N * 128 * 2);
    unsigned short* out1b = (unsigned short*)alloc((size_t)N * 512 * 2);
    unsigned short* o1b  = (unsigned short*)alloc((size_t)N * 512 * 2);
    float* out2   = (float*)alloc((size_t)N * 128 * 4);
    float* as1    = (float*)alloc((size_t)N * 4 * 4);
    float* ad1    = (float*)alloc((size_t)N * 4 * 4);
    float* as2    = (float*)alloc((size_t)N * 4);
    float* ad2    = (float*)alloc((size_t)N * 4);
    float* w4     = (float*)alloc((size_t)EP * 4 * 4);
    float* winv4  = (float*)alloc((size_t)N * 4 * 4);
    float* w1e    = (float*)alloc((size_t)EP * 4);
    float* winv1  = (float*)alloc((size_t)N * 4);

    hipMemsetAsync(d_ws, 0, zero_bytes, stream);

    int eb = (EP + 255) / 256;
    int nrow = (N + 63) / 64;
    int mblk = (N + 63) / 64;
    int nblk4 = (N + 3) / 4;

    // ---- casts / weight packing ----
    cast_bf<<<(N * VIN + 255) / 256, 256, 0, stream>>>(x, xb, N * VIN);
    pack_b<<<(VIN * 512 + 255) / 256, 256, 0, stream>>>(W1, W1p, VIN, 512);
    pack_b<<<(512 * 128 + 255) / 256, 256, 0, stream>>>(W2, W2p, 512, 128);

    // ---- CSR build (dst-sorted adjacency) ----
    hist_kernel<<<eb, 256, 0, stream>>>(ei, deg, E, N);
    scan_kernel<<<1, 1024, 0, stream>>>(deg, rowptr, N, EP);
    scatter_kernel<<<eb, 256, 0, stream>>>(ei, rowptr, cursor, esrc, E, N);

    // ---- GAT layer 1 (H=4, concat) ----
    gemm_bf16<VIN, 512, 128><<<dim3(mblk, 4), 256, 0, stream>>>(xb, W1p, h1b, N);
    alpha_bf<<<N, 4 * 64, 0, stream>>>(h1b, a_s1, a_d1, as1, ad1, 4);
    node_softmax4<<<nblk4, 256, 0, stream>>>(rowptr, esrc, as1, ad1, w4, winv4);
    node_aggr4<<<nblk4, 256, 0, stream>>>(rowptr, esrc, w4, winv4, h1b, out1b);
    bn_stats_bf<<<nrow, 256, 0, stream>>>(out1b, b1, stats1, N, 512);
    bn_apply_bf<<<(N * 512 + 255) / 256, 256, 0, stream>>>(out1b, b1, stats1, gamma1, beta1, o1b, N, 512);

    // ---- GAT layer 2 (H=1) ----
    gemm_bf16<512, 128, 64><<<dim3(mblk, 2), 256, 0, stream>>>(o1b, W2p, h2b, N);
    alpha_bf<<<N, 64, 0, stream>>>(h2b, a_s2, a_d2, as2, ad2, 1);
    node_softmax1<<<nblk4, 256, 0, stream>>>(rowptr, esrc, as2, ad2, w1e, winv1);
    node_aggr1<<<nblk4, 256, 0, stream>>>(rowptr, esrc, w1e, winv1, h2b, out2);
    bn_stats_f32<<<nrow, 256, 0, stream>>>(out2, b2, stats2, N, 128);
    bn_apply_pool<<<(N * 128 + 255) / 256, 256, 0, stream>>>(out2, b2, stats2, gamma2, beta2, batch, zbuf, N, 128);

    // ---- MLP head ----
    mlp_kernel<<<GG, 320, 0, stream>>>(zbuf, extras, Wm1, bm1, Wm2, bm2, Wm3, bm3, out);
}

// Round 5
// 427.611 us; speedup vs baseline: 3.4564x; 1.0819x over previous
//
#include <hip/hip_runtime.h>
#include <hip/hip_bf16.h>
#include <math.h>

// ---------------- constants (match reference) ----------------
#define NN 20000
#define EE 400000
#define GG 64
#define VIN 128
#define CONVD 128
#define NETD 256
#define NXD 9
#define EPS_BN 1e-5f
#define NEG_SLOPE 0.2f

typedef short short8 __attribute__((ext_vector_type(8)));
typedef float floatx4 __attribute__((ext_vector_type(4)));

__device__ __forceinline__ float leaky(float v) {
    return v >= 0.f ? v : NEG_SLOPE * v;
}
__device__ __forceinline__ unsigned short f2bf(float f) {
    union { float f; unsigned u; } v; v.f = f;
    unsigned r = v.u + 0x7FFFu + ((v.u >> 16) & 1u);   // RNE
    return (unsigned short)(r >> 16);
}
__device__ __forceinline__ float bf2f(unsigned short u) {
    union { unsigned u; float f; } v; v.u = ((unsigned)u) << 16;
    return v.f;
}

// ---------------- pack helper: B (f32 [K,Nn]) -> MFMA B-frag layout (bf16) -------
__device__ __forceinline__ void pack_one(const float* __restrict__ B,
                                         unsigned short* __restrict__ Bp,
                                         int K, int Nn, int idx) {
    int j = idx & 7, lane = (idx >> 3) & 63, t = idx >> 9;
    int KT = K >> 5;
    int kt = t % KT, nt = t / KT;
    int k = kt * 32 + (lane >> 4) * 8 + j;
    int n = nt * 16 + (lane & 15);
    Bp[idx] = f2bf(B[(size_t)k * Nn + n]);
}

// ---------------- prep: cast x->bf16, pack W1, pack W2, dst histogram ------------
__global__ void prep_kernel(const float* __restrict__ x, unsigned short* __restrict__ xb,
                            const float* __restrict__ W1, unsigned short* __restrict__ W1p,
                            const float* __restrict__ W2, unsigned short* __restrict__ W2p,
                            const int* __restrict__ ei, int* __restrict__ deg) {
    const int CB = (NN * VIN + 255) / 256;     // 10000
    const int PB = (VIN * 512) / 256;          // 256
    const int QB = (512 * 128) / 256;          // 256
    int b = blockIdx.x;
    if (b < CB) {
        int i = b * 256 + threadIdx.x;
        if (i < NN * VIN) xb[i] = f2bf(x[i]);
    } else if (b < CB + PB) {
        int i = (b - CB) * 256 + threadIdx.x;
        pack_one(W1, W1p, VIN, 512, i);
    } else if (b < CB + PB + QB) {
        int i = (b - CB - PB) * 256 + threadIdx.x;
        pack_one(W2, W2p, 512, 128, i);
    } else {
        int e = (b - CB - PB - QB) * 256 + threadIdx.x;
        if (e < EE + NN) {
            int d = (e < EE) ? ei[EE + e] : e - EE;
            atomicAdd(&deg[d], 1);
        }
    }
}

// ---------------- single-block exclusive scan (LDS-staged, u16 degrees) ----------
__global__ __launch_bounds__(1024) void scan_kernel(const int* __restrict__ deg,
                                                    int* __restrict__ rowptr,
                                                    int n, int total) {
    __shared__ unsigned short sdeg[NN];
    __shared__ int ssum[1024];
    int t = threadIdx.x;
    for (int i = t; i < n; i += 1024) sdeg[i] = (unsigned short)deg[i];
    __syncthreads();
    const int CH = (NN + 1023) / 1024;   // 20
    int base = t * CH;
    int s = 0;
    for (int i = 0; i < CH; i++) {
        int idx = base + i;
        if (idx < n) s += sdeg[idx];
    }
    ssum[t] = s;
    __syncthreads();
    for (int off = 1; off < 1024; off <<= 1) {
        int v = (t >= off) ? ssum[t - off] : 0;
        __syncthreads();
        ssum[t] += v;
        __syncthreads();
    }
    int pre = ssum[t] - s;
    for (int i = 0; i < CH; i++) {
        int idx = base + i;
        if (idx < n) { rowptr[idx] = pre; pre += sdeg[idx]; }
    }
    if (t == 0) rowptr[n] = total;
}

__global__ void scatter_kernel(const int* __restrict__ ei, const int* __restrict__ rowptr,
                               int* __restrict__ cursor, int* __restrict__ esrc,
                               int E, int Np) {
    int e = blockIdx.x * blockDim.x + threadIdx.x;
    if (e >= E + Np) return;
    int s = (e < E) ? ei[e] : e - E;
    int d = (e < E) ? ei[E + e] : e - E;
    int slot = rowptr[d] + atomicAdd(&cursor[d], 1);
    esrc[slot] = s;
}

// ---------------- GEMM1 + fused alpha: h1 = x@W1 ; as/ad = h1 . a_{s,d} ----------
// blockIdx.y = head (covers 128 cols); wave = 16 rows
__global__ __launch_bounds__(256) void gemm1_alpha(const unsigned short* __restrict__ A,
                                                   const unsigned short* __restrict__ Bp,
                                                   const float* __restrict__ a_s,
                                                   const float* __restrict__ a_d,
                                                   unsigned short* __restrict__ C,
                                                   float* __restrict__ as_out,
                                                   float* __restrict__ ad_out, int M) {
    constexpr int K = VIN;            // 128
    constexpr int Nn = 512;
    constexpr int KT = K / 32;        // 4
    int wave = threadIdx.x >> 6, lane = threadIdx.x & 63;
    int row0 = (blockIdx.x * 4 + wave) * 16;
    if (row0 >= M) return;
    int r = lane & 15, quad = lane >> 4;
    int hh = blockIdx.y;
    int nt0 = hh * 8;
    short8 af[KT];
    const unsigned short* arow = A + (size_t)(row0 + r) * K + quad * 8;
#pragma unroll
    for (int kt = 0; kt < KT; kt++) af[kt] = *(const short8*)(arow + kt * 32);
    float asp[4] = {}, adp[4] = {};
#pragma unroll
    for (int nt = 0; nt < 8; nt++) {
        floatx4 acc = {0.f, 0.f, 0.f, 0.f};
        const unsigned short* bbase = Bp + (((size_t)(nt0 + nt) * KT) << 9) + lane * 8;
#pragma unroll
        for (int kt = 0; kt < KT; kt++) {
            short8 bf = *(const short8*)(bbase + ((size_t)kt << 9));
            acc = __builtin_amdgcn_mfma_f32_16x16x32_bf16(af[kt], bf, acc, 0, 0, 0);
        }
        int col = (nt0 + nt) * 16 + r;
        unsigned short* cbase = C + (size_t)(row0 + quad * 4) * Nn + col;
        float sv = a_s[hh * CONVD + nt * 16 + r];
        float dv = a_d[hh * CONVD + nt * 16 + r];
#pragma unroll
        for (int reg = 0; reg < 4; reg++) {
            cbase[(size_t)reg * Nn] = f2bf(acc[reg]);
            asp[reg] = fmaf(acc[reg], sv, asp[reg]);
            adp[reg] = fmaf(acc[reg], dv, adp[reg]);
        }
    }
#pragma unroll
    for (int msk = 1; msk < 16; msk <<= 1) {
#pragma unroll
        for (int reg = 0; reg < 4; reg++) {
            asp[reg] += __shfl_xor(asp[reg], msk);
            adp[reg] += __shfl_xor(adp[reg], msk);
        }
    }
    if (r < 4) {
        int row = row0 + quad * 4 + r;
        as_out[row * 4 + hh] = asp[r];
        ad_out[row * 4 + hh] = adp[r];
    }
}

// ---- GEMM2 + fused layer-1 BN on A-load + fused alpha: h2 = bn(out1)@W2 ---------
__global__ __launch_bounds__(256) void gemm2_bn_alpha(const unsigned short* __restrict__ A,
                                                      const unsigned short* __restrict__ Bp,
                                                      const float* __restrict__ S,
                                                      const float* __restrict__ T,
                                                      const float* __restrict__ a_s,
                                                      const float* __restrict__ a_d,
                                                      unsigned short* __restrict__ C,
                                                      float* __restrict__ as_out,
                                                      float* __restrict__ ad_out, int M) {
    constexpr int K = 512;
    constexpr int Nn = CONVD;         // 128
    constexpr int KT = K / 32;        // 16
    int wave = threadIdx.x >> 6, lane = threadIdx.x & 63;
    int row0 = (blockIdx.x * 4 + wave) * 16;
    if (row0 >= M) return;
    int r = lane & 15, quad = lane >> 4;
    short8 af[KT];
    const unsigned short* arow = A + (size_t)(row0 + r) * K + quad * 8;
#pragma unroll
    for (int kt = 0; kt < KT; kt++) {
        short8 raw = *(const short8*)(arow + kt * 32);
        int k = kt * 32 + quad * 8;
        float4 s0 = *(const float4*)(S + k);
        float4 s1 = *(const float4*)(S + k + 4);
        float4 t0 = *(const float4*)(T + k);
        float4 t1 = *(const float4*)(T + k + 4);
        float sv[8] = {s0.x, s0.y, s0.z, s0.w, s1.x, s1.y, s1.z, s1.w};
        float tv[8] = {t0.x, t0.y, t0.z, t0.w, t1.x, t1.y, t1.z, t1.w};
        short8 o;
#pragma unroll
        for (int i = 0; i < 8; i++) {
            float v = fmaf(bf2f((unsigned short)raw[i]), sv[i], tv[i]);
            o[i] = (short)f2bf(v > 0.f ? v : 0.f);
        }
        af[kt] = o;
    }
    float asp[4] = {}, adp[4] = {};
#pragma unroll
    for (int nt = 0; nt < 8; nt++) {
        floatx4 acc = {0.f, 0.f, 0.f, 0.f};
        const unsigned short* bbase = Bp + (((size_t)nt * KT) << 9) + lane * 8;
#pragma unroll
        for (int kt = 0; kt < KT; kt++) {
            short8 bf = *(const short8*)(bbase + ((size_t)kt << 9));
            acc = __builtin_amdgcn_mfma_f32_16x16x32_bf16(af[kt], bf, acc, 0, 0, 0);
        }
        int col = nt * 16 + r;
        unsigned short* cbase = C + (size_t)(row0 + quad * 4) * Nn + col;
        float sv = a_s[col];
        float dv = a_d[col];
#pragma unroll
        for (int reg = 0; reg < 4; reg++) {
            cbase[(size_t)reg * Nn] = f2bf(acc[reg]);
            asp[reg] = fmaf(acc[reg], sv, asp[reg]);
            adp[reg] = fmaf(acc[reg], dv, adp[reg]);
        }
    }
#pragma unroll
    for (int msk = 1; msk < 16; msk <<= 1) {
#pragma unroll
        for (int reg = 0; reg < 4; reg++) {
            asp[reg] += __shfl_xor(asp[reg], msk);
            adp[reg] += __shfl_xor(adp[reg], msk);
        }
    }
    if (r < 4) {
        int row = row0 + quad * 4 + r;
        as_out[row] = asp[r];
        ad_out[row] = adp[r];
    }
}

// ---------------- per-node softmax, H=4: store unnormalized p + 1/sum ------------
__global__ __launch_bounds__(256) void node_softmax4(const int* __restrict__ rowptr,
                                                     const int* __restrict__ esrc,
                                                     const float* __restrict__ as4,
                                                     const float* __restrict__ ad4,
                                                     float* __restrict__ w,
                                                     float* __restrict__ winv) {
    int lane = threadIdx.x & 63;
    int n = blockIdx.x * 4 + (threadIdx.x >> 6);
    if (n >= NN) return;
    int beg = rowptr[n], end = rowptr[n + 1];
    float4 adn = *(const float4*)(ad4 + (size_t)n * 4);
    float m0 = -INFINITY, m1 = -INFINITY, m2 = -INFINITY, m3 = -INFINITY;
    for (int j = beg + lane; j < end; j += 64) {
        int s = esrc[j];
        float4 av = *(const float4*)(as4 + (size_t)s * 4);
        m0 = fmaxf(m0, leaky(av.x + adn.x));
        m1 = fmaxf(m1, leaky(av.y + adn.y));
        m2 = fmaxf(m2, leaky(av.z + adn.z));
        m3 = fmaxf(m3, leaky(av.w + adn.w));
    }
#pragma unroll
    for (int o = 32; o > 0; o >>= 1) {
        m0 = fmaxf(m0, __shfl_xor(m0, o));
        m1 = fmaxf(m1, __shfl_xor(m1, o));
        m2 = fmaxf(m2, __shfl_xor(m2, o));
        m3 = fmaxf(m3, __shfl_xor(m3, o));
    }
    float s0 = 0.f, s1 = 0.f, s2 = 0.f, s3 = 0.f;
    for (int j = beg + lane; j < end; j += 64) {
        int s = esrc[j];
        float4 av = *(const float4*)(as4 + (size_t)s * 4);
        float p0 = __expf(leaky(av.x + adn.x) - m0);
        float p1 = __expf(leaky(av.y + adn.y) - m1);
        float p2 = __expf(leaky(av.z + adn.z) - m2);
        float p3 = __expf(leaky(av.w + adn.w) - m3);
        *(float4*)(w + (size_t)j * 4) = make_float4(p0, p1, p2, p3);
        s0 += p0; s1 += p1; s2 += p2; s3 += p3;
    }
#pragma unroll
    for (int o = 32; o > 0; o >>= 1) {
        s0 += __shfl_xor(s0, o);
        s1 += __shfl_xor(s1, o);
        s2 += __shfl_xor(s2, o);
        s3 += __shfl_xor(s3, o);
    }
    if (lane == 0) {
        *(float4*)(winv + (size_t)n * 4) = make_float4(
            1.f / (s0 + 1e-16f), 1.f / (s1 + 1e-16f),
            1.f / (s2 + 1e-16f), 1.f / (s3 + 1e-16f));
    }
}

// ---------------- per-node softmax, H=1 ----------------
__global__ __launch_bounds__(256) void node_softmax1(const int* __restrict__ rowptr,
                                                     const int* __restrict__ esrc,
                                                     const float* __restrict__ as,
                                                     const float* __restrict__ ad,
                                                     float* __restrict__ w,
                                                     float* __restrict__ winv) {
    int lane = threadIdx.x & 63;
    int n = blockIdx.x * 4 + (threadIdx.x >> 6);
    if (n >= NN) return;
    int beg = rowptr[n], end = rowptr[n + 1];
    float adn = ad[n];
    float m = -INFINITY;
    for (int j = beg + lane; j < end; j += 64)
        m = fmaxf(m, leaky(as[esrc[j]] + adn));
#pragma unroll
    for (int o = 32; o > 0; o >>= 1) m = fmaxf(m, __shfl_xor(m, o));
    float sum = 0.f;
    for (int j = beg + lane; j < end; j += 64) {
        float p = __expf(leaky(as[esrc[j]] + adn) - m);
        w[j] = p;
        sum += p;
    }
#pragma unroll
    for (int o = 32; o > 0; o >>= 1) sum += __shfl_xor(sum, o);
    if (lane == 0) winv[n] = 1.f / (sum + 1e-16f);
}

// ---------------- aggregation H=4: one wave per node; lane owns 8 of 512 ch ------
__global__ __launch_bounds__(256) void node_aggr4(const int* __restrict__ rowptr,
                                                  const int* __restrict__ esrc,
                                                  const float* __restrict__ w,
                                                  const float* __restrict__ winv,
                                                  const unsigned short* __restrict__ h,
                                                  unsigned short* __restrict__ outb) {
    int lane = threadIdx.x & 63;
    int n = blockIdx.x * 4 + (threadIdx.x >> 6);
    if (n >= NN) return;
    int beg = rowptr[n], end = rowptr[n + 1];
    int hh = lane >> 4;
    float inv = winv[(size_t)n * 4 + hh];
    float acc[8] = {};
    const unsigned short* hbase = h + lane * 8;
    int j = beg;
    for (; j + 3 < end; j += 4) {
        int s0 = esrc[j], s1 = esrc[j + 1], s2 = esrc[j + 2], s3 = esrc[j + 3];
        float p0 = w[(size_t)j * 4 + hh];
        float p1 = w[(size_t)(j + 1) * 4 + hh];
        float p2 = w[(size_t)(j + 2) * 4 + hh];
        float p3 = w[(size_t)(j + 3) * 4 + hh];
        short8 h0 = *(const short8*)(hbase + (size_t)s0 * 512);
        short8 h1 = *(const short8*)(hbase + (size_t)s1 * 512);
        short8 h2 = *(const short8*)(hbase + (size_t)s2 * 512);
        short8 h3 = *(const short8*)(hbase + (size_t)s3 * 512);
#pragma unroll
        for (int i = 0; i < 8; i++) {
            acc[i] = fmaf(p0, bf2f((unsigned short)h0[i]), acc[i]);
            acc[i] = fmaf(p1, bf2f((unsigned short)h1[i]), acc[i]);
            acc[i] = fmaf(p2, bf2f((unsigned short)h2[i]), acc[i]);
            acc[i] = fmaf(p3, bf2f((unsigned short)h3[i]), acc[i]);
        }
    }
    for (; j < end; j++) {
        int s0 = esrc[j];
        float p0 = w[(size_t)j * 4 + hh];
        short8 h0 = *(const short8*)(hbase + (size_t)s0 * 512);
#pragma unroll
        for (int i = 0; i < 8; i++) acc[i] = fmaf(p0, bf2f((unsigned short)h0[i]), acc[i]);
    }
    short8 o;
#pragma unroll
    for (int i = 0; i < 8; i++) o[i] = (short)f2bf(acc[i] * inv);
    *(short8*)(outb + (size_t)n * 512 + lane * 8) = o;
}

// ---------------- aggregation H=1: one wave per node; lane owns 2 of 128 ch ------
__global__ __launch_bounds__(256) void node_aggr1(const int* __restrict__ rowptr,
                                                  const int* __restrict__ esrc,
                                                  const float* __restrict__ w,
                                                  const float* __restrict__ winv,
                                                  const unsigned short* __restrict__ h,
                                                  float* __restrict__ out) {
    int lane = threadIdx.x & 63;
    int n = blockIdx.x * 4 + (threadIdx.x >> 6);
    if (n >= NN) return;
    int beg = rowptr[n], end = rowptr[n + 1];
    float inv = winv[n];
    float2 acc = make_float2(0.f, 0.f);
    const unsigned short* hbase = h + lane * 2;
    int j = beg;
    for (; j + 3 < end; j += 4) {
        int s0 = esrc[j], s1 = esrc[j + 1], s2 = esrc[j + 2], s3 = esrc[j + 3];
        float p0 = w[j], p1 = w[j + 1], p2 = w[j + 2], p3 = w[j + 3];
        unsigned v0 = *(const unsigned*)(hbase + (size_t)s0 * CONVD);
        unsigned v1 = *(const unsigned*)(hbase + (size_t)s1 * CONVD);
        unsigned v2 = *(const unsigned*)(hbase + (size_t)s2 * CONVD);
        unsigned v3 = *(const unsigned*)(hbase + (size_t)s3 * CONVD);
        acc.x = fmaf(p0, bf2f((unsigned short)(v0 & 0xffffu)), acc.x);
        acc.y = fmaf(p0, bf2f((unsigned short)(v0 >> 16)), acc.y);
        acc.x = fmaf(p1, bf2f((unsigned short)(v1 & 0xffffu)), acc.x);
        acc.y = fmaf(p1, bf2f((unsigned short)(v1 >> 16)), acc.y);
        acc.x = fmaf(p2, bf2f((unsigned short)(v2 & 0xffffu)), acc.x);
        acc.y = fmaf(p2, bf2f((unsigned short)(v2 >> 16)), acc.y);
        acc.x = fmaf(p3, bf2f((unsigned short)(v3 & 0xffffu)), acc.x);
        acc.y = fmaf(p3, bf2f((unsigned short)(v3 >> 16)), acc.y);
    }
    for (; j < end; j++) {
        int s0 = esrc[j];
        float p0 = w[j];
        unsigned v0 = *(const unsigned*)(hbase + (size_t)s0 * CONVD);
        acc.x = fmaf(p0, bf2f((unsigned short)(v0 & 0xffffu)), acc.x);
        acc.y = fmaf(p0, bf2f((unsigned short)(v0 >> 16)), acc.y);
    }
    *(float2*)(out + (size_t)n * CONVD + lane * 2) = make_float2(acc.x * inv, acc.y * inv);
}

// ---------------- BN stats (bf16 input): per-column sum / sumsq of (x + bias) ----
__global__ void bn_stats_bf(const unsigned short* __restrict__ x, const float* __restrict__ bias,
                            float* __restrict__ stats, int Nn, int C) {
    const int ROWS = 64;
    int r0 = blockIdx.x * ROWS;
    int rend = min(r0 + ROWS, Nn);
    for (int c = threadIdx.x; c < C; c += blockDim.x) {
        float b = bias[c];
        float s1 = 0.f, s2 = 0.f;
        for (int r = r0; r < rend; r++) {
            float v = bf2f(x[(size_t)r * C + c]) + b;
            s1 += v;
            s2 = fmaf(v, v, s2);
        }
        atomicAdd(&stats[c], s1);
        atomicAdd(&stats[C + c], s2);
    }
}

// ---------------- BN finalize: stats -> per-channel scale/shift (bias folded) ----
__global__ void bn_finalize(const float* __restrict__ stats, const float* __restrict__ bias,
                            const float* __restrict__ gamma, const float* __restrict__ beta,
                            float* __restrict__ S, float* __restrict__ T, int Nn, int C) {
    int c = blockIdx.x * blockDim.x + threadIdx.x;
    if (c >= C) return;
    float inv_n = 1.f / (float)Nn;
    float mu = stats[c] * inv_n;
    float var = stats[C + c] * inv_n - mu * mu;
    float s = gamma[c] * rsqrtf(var + EPS_BN);
    S[c] = s;
    T[c] = fmaf(bias[c] - mu, s, beta[c]);
}

// ---------------- BN stats (f32 input) ----------------
__global__ void bn_stats_f32(const float* __restrict__ x, const float* __restrict__ bias,
                             float* __restrict__ stats, int Nn, int C) {
    const int ROWS = 64;
    int r0 = blockIdx.x * ROWS;
    int rend = min(r0 + ROWS, Nn);
    for (int c = threadIdx.x; c < C; c += blockDim.x) {
        float b = bias[c];
        float s1 = 0.f, s2 = 0.f;
        for (int r = r0; r < rend; r++) {
            float v = x[(size_t)r * C + c] + b;
            s1 += v;
            s2 = fmaf(v, v, s2);
        }
        atomicAdd(&stats[c], s1);
        atomicAdd(&stats[C + c], s2);
    }
}

// ---------------- BN apply + ReLU + pool (layer 2, fused) ------------------------
__global__ void bn_apply_pool(const float* __restrict__ x, const float* __restrict__ bias,
                              const float* __restrict__ stats,
                              const float* __restrict__ gamma, const float* __restrict__ beta,
                              const int* __restrict__ batch, float* __restrict__ z,
                              int Nn, int C) {
    int idx = blockIdx.x * blockDim.x + threadIdx.x;
    if (idx >= Nn * C) return;
    int c = idx % C;
    int n = idx / C;
    float inv_n = 1.f / (float)Nn;
    float mu = stats[c] * inv_n;
    float var = stats[C + c] * inv_n - mu * mu;
    float v = (x[idx] + bias[c] - mu) * rsqrtf(var + EPS_BN);
    v = fmaf(gamma[c], v, beta[c]);
    v = v > 0.f ? v : 0.f;
    atomicAdd(&z[batch[n] * C + c], v);
}

// ---------------- fused MLP head: one block per graph ----------------
__global__ __launch_bounds__(320) void mlp_kernel(const float* __restrict__ g,
                           const float* __restrict__ extras,
                           const float* __restrict__ Wm1, const float* __restrict__ bm1,
                           const float* __restrict__ Wm2, const float* __restrict__ bm2,
                           const float* __restrict__ Wm3, const float* __restrict__ bm3,
                           float* __restrict__ out) {
    const int Z0 = CONVD + NXD;   // 137
    const int Z1 = NETD + NXD;    // 265
    const int Z2 = NETD;          // 256
    __shared__ float z[Z0];
    __shared__ float z1[Z1];
    __shared__ float z2[Z2];
    __shared__ float wred[5];
    int gi = blockIdx.x, t = threadIdx.x;
    if (t < CONVD) z[t] = g[gi * CONVD + t];
    else if (t < Z0) z[t] = extras[gi * NXD + (t - CONVD)];
    __syncthreads();
    if (t < Z1) {
        float acc = bm1[t];
        for (int k = 0; k < Z0; k++) acc = fmaf(z[k], Wm1[k * Z1 + t], acc);
        z1[t] = acc > 0.f ? acc : 0.f;
    }
    __syncthreads();
    if (t < Z2) {
        float acc = bm2[t];
        for (int k = 0; k < Z1; k++) acc = fmaf(z1[k], Wm2[k * Z2 + t], acc);
        z2[t] = acc > 0.f ? acc : 0.f;
    }
    __syncthreads();
    float partial = (t < Z2) ? z2[t] * Wm3[t] : 0.f;
    for (int o = 32; o > 0; o >>= 1) partial += __shfl_down(partial, o);
    int wv = t >> 6, ln = t & 63;
    if (ln == 0) wred[wv] = partial;
    __syncthreads();
    if (t == 0) {
        float s = bm3[0];
        for (int i = 0; i < 5; i++) s += wred[i];
        out[gi] = s;
    }
}

// ---------------- launch ----------------
extern "C" void kernel_launch(void* const* d_in, const int* in_sizes, int n_in,
                              void* d_out, int out_size, void* d_ws, size_t ws_size,
                              hipStream_t stream) {
    const float* x      = (const float*)d_in[0];
    const int*   ei     = (const int*)d_in[1];
    const int*   batch  = (const int*)d_in[2];
    const float* extras = (const float*)d_in[3];
    const float* W1     = (const float*)d_in[4];
    const float* a_s1   = (const float*)d_in[5];
    const float* a_d1   = (const float*)d_in[6];
    const float* b1     = (const float*)d_in[7];
    const float* W2     = (const float*)d_in[8];
    const float* a_s2   = (const float*)d_in[9];
    const float* a_d2   = (const float*)d_in[10];
    const float* b2     = (const float*)d_in[11];
    const float* gamma1 = (const float*)d_in[12];
    const float* beta1  = (const float*)d_in[13];
    const float* gamma2 = (const float*)d_in[14];
    const float* beta2  = (const float*)d_in[15];
    const float* Wm1    = (const float*)d_in[16];
    const float* bm1    = (const float*)d_in[17];
    const float* Wm2    = (const float*)d_in[18];
    const float* bm2    = (const float*)d_in[19];
    const float* Wm3    = (const float*)d_in[20];
    const float* bm3    = (const float*)d_in[21];
    float* out = (float*)d_out;

    const int N = NN, E = EE, EP = EE + NN;

    char* ws = (char*)d_ws;
    size_t off = 0;
    auto alloc = [&](size_t bytes) -> void* {
        void* pp = (void*)(ws + off);
        off += (bytes + 255) & ~(size_t)255;
        return pp;
    };
    // --- zero region (contiguous; one small memset) ---
    int*   deg    = (int*)alloc((size_t)N * 4);
    int*   cursor = (int*)alloc((size_t)N * 4);
    float* stats1 = (float*)alloc(512 * 2 * 4);
    float* stats2 = (float*)alloc(128 * 2 * 4);
    float* zbuf   = (float*)alloc((size_t)GG * CONVD * 4);
    size_t zero_bytes = off;
    // --- scratch (fully overwritten each launch) ---
    int*   rowptr = (int*)alloc((size_t)(N + 1) * 4);
    int*   esrc   = (int*)alloc((size_t)EP * 4);
    unsigned short* xb    = (unsigned short*)alloc((size_t)N * VIN * 2);
    unsigned short* W1p   = (unsigned short*)alloc((size_t)VIN * 512 * 2);
    unsigned short* W2p   = (unsigned short*)alloc((size_t)512 * 128 * 2);
    unsigned short* h1b   = (unsigned short*)alloc((size_t)N * 512 * 2);
    unsigned short* h2b   = (unsigned short*)alloc((size_t)N * 128 * 2);
    unsigned short* out1b = (unsigned short*)alloc((size_t)N * 512 * 2);
    float* out2   = (float*)alloc((size_t)N * 128 * 4);
    float* as1    = (float*)alloc((size_t)N * 4 * 4);
    float* ad1    = (float*)alloc((size_t)N * 4 * 4);
    float* as2    = (float*)alloc((size_t)N * 4);
    float* ad2    = (float*)alloc((size_t)N * 4);
    float* w4     = (float*)alloc((size_t)EP * 4 * 4);
    float* winv4  = (float*)alloc((size_t)N * 4 * 4);
    float* w1e    = (float*)alloc((size_t)EP * 4);
    float* winv1  = (float*)alloc((size_t)N * 4);
    float* S1     = (float*)alloc(512 * 4);
    float* T1     = (float*)alloc(512 * 4);

    hipMemsetAsync(d_ws, 0, zero_bytes, stream);

    int eb = (EP + 255) / 256;
    int nrow = (N + 63) / 64;
    int mblk = (N + 63) / 64;
    int nblk4 = (N + 3) / 4;
    int prep_blocks = (N * VIN + 255) / 256 + 256 + 256 + eb;

    // ---- prep (cast + packs + histogram) ----
    prep_kernel<<<prep_blocks, 256, 0, stream>>>(x, xb, W1, W1p, W2, W2p, ei, deg);

    // ---- CSR build ----
    scan_kernel<<<1, 1024, 0, stream>>>(deg, rowptr, N, EP);
    scatter_kernel<<<eb, 256, 0, stream>>>(ei, rowptr, cursor, esrc, E, N);

    // ---- GAT layer 1 (H=4, concat) ----
    gemm1_alpha<<<dim3(mblk, 4), 256, 0, stream>>>(xb, W1p, a_s1, a_d1, h1b, as1, ad1, N);
    node_softmax4<<<nblk4, 256, 0, stream>>>(rowptr, esrc, as1, ad1, w4, winv4);
    node_aggr4<<<nblk4, 256, 0, stream>>>(rowptr, esrc, w4, winv4, h1b, out1b);
    bn_stats_bf<<<nrow, 256, 0, stream>>>(out1b, b1, stats1, N, 512);
    bn_finalize<<<2, 256, 0, stream>>>(stats1, b1, gamma1, beta1, S1, T1, N, 512);

    // ---- GAT layer 2 (H=1) ----
    gemm2_bn_alpha<<<mblk, 256, 0, stream>>>(out1b, W2p, S1, T1, a_s2, a_d2, h2b, as2, ad2, N);
    node_softmax1<<<nblk4, 256, 0, stream>>>(rowptr, esrc, as2, ad2, w1e, winv1);
    node_aggr1<<<nblk4, 256, 0, stream>>>(rowptr, esrc, w1e, winv1, h2b, out2);
    bn_stats_f32<<<nrow, 256, 0, stream>>>(out2, b2, stats2, N, 128);
    bn_apply_pool<<<(N * 128 + 255) / 256, 256, 0, stream>>>(out2, b2, stats2, gamma2, beta2, batch, zbuf, N, 128);

    // ---- MLP head ----
    mlp_kernel<<<GG, 320, 0, stream>>>(zbuf, extras, Wm1, bm1, Wm2, bm2, Wm3, bm3, out);
}

// Round 6
// 392.192 us; speedup vs baseline: 3.7685x; 1.0903x over previous
//
#include <hip/hip_runtime.h>
#include <hip/hip_bf16.h>
#include <math.h>

// ---------------- constants (match reference) ----------------
#define NN 20000
#define EE 400000
#define GG 64
#define VIN 128
#define CONVD 128
#define NETD 256
#define NXD 9
#define EPS_BN 1e-5f
#define NEG_SLOPE 0.2f

typedef short short8 __attribute__((ext_vector_type(8)));
typedef float floatx4 __attribute__((ext_vector_type(4)));

__device__ __forceinline__ float leaky(float v) {
    return v >= 0.f ? v : NEG_SLOPE * v;
}
__device__ __forceinline__ unsigned short f2bf(float f) {
    union { float f; unsigned u; } v; v.f = f;
    unsigned r = v.u + 0x7FFFu + ((v.u >> 16) & 1u);   // RNE
    return (unsigned short)(r >> 16);
}
__device__ __forceinline__ float bf2f(unsigned short u) {
    union { unsigned u; float f; } v; v.u = ((unsigned)u) << 16;
    return v.f;
}
__device__ __forceinline__ unsigned packbf2(float a, float b) {
    return (unsigned)f2bf(a) | ((unsigned)f2bf(b) << 16);
}

// ---------------- pack helper: B (f32 [K,Nn]) -> MFMA B-frag layout (bf16) -------
__device__ __forceinline__ void pack_one(const float* __restrict__ B,
                                         unsigned short* __restrict__ Bp,
                                         int K, int Nn, int idx) {
    int j = idx & 7, lane = (idx >> 3) & 63, t = idx >> 9;
    int KT = K >> 5;
    int kt = t % KT, nt = t / KT;
    int k = kt * 32 + (lane >> 4) * 8 + j;
    int n = nt * 16 + (lane & 15);
    Bp[idx] = f2bf(B[(size_t)k * Nn + n]);
}

// ------ prep: cast x->bf16, pack W1, pack W2, dst histogram, va = W1 . a ---------
__global__ void prep_kernel(const float* __restrict__ x, unsigned short* __restrict__ xb,
                            const float* __restrict__ W1, unsigned short* __restrict__ W1p,
                            const float* __restrict__ W2, unsigned short* __restrict__ W2p,
                            const int* __restrict__ ei, int* __restrict__ deg,
                            const float* __restrict__ a_s1, const float* __restrict__ a_d1,
                            float* __restrict__ va_s, float* __restrict__ va_d) {
    const int CB = (NN * VIN + 255) / 256;     // 10000
    const int PB = (VIN * 512) / 256;          // 256
    const int QB = (512 * 128) / 256;          // 256
    const int HB = (EE + NN + 255) / 256;      // 1642
    int b = blockIdx.x;
    if (b < CB) {
        int i = b * 256 + threadIdx.x;
        if (i < NN * VIN) xb[i] = f2bf(x[i]);
    } else if (b < CB + PB) {
        int i = (b - CB) * 256 + threadIdx.x;
        pack_one(W1, W1p, VIN, 512, i);
    } else if (b < CB + PB + QB) {
        int i = (b - CB - PB) * 256 + threadIdx.x;
        pack_one(W2, W2p, 512, 128, i);
    } else if (b < CB + PB + QB + HB) {
        int e = (b - CB - PB - QB) * 256 + threadIdx.x;
        if (e < EE + NN) {
            int d = (e < EE) ? ei[EE + e] : e - EE;
            atomicAdd(&deg[d], 1);
        }
    } else {
        // va: 1024 outputs; i<512 -> va_s[k*4+h], else va_d
        int i = (b - CB - PB - QB - HB) * 256 + threadIdx.x;
        int sd = i >> 9;
        int k = (i & 511) >> 2, h = i & 3;
        const float* a = (sd ? a_d1 : a_s1) + h * CONVD;
        const float* wrow = W1 + (size_t)k * 512 + h * CONVD;
        float acc = 0.f;
        for (int c = 0; c < CONVD; c++) acc = fmaf(wrow[c], a[c], acc);
        (sd ? va_d : va_s)[(k << 2) + h] = acc;
    }
}

// ---------------- single-block exclusive scan (LDS-staged, u16 degrees) ----------
__global__ __launch_bounds__(1024) void scan_kernel(const int* __restrict__ deg,
                                                    int* __restrict__ rowptr,
                                                    int n, int total) {
    __shared__ unsigned short sdeg[NN];
    __shared__ int ssum[1024];
    int t = threadIdx.x;
    for (int i = t; i < n; i += 1024) sdeg[i] = (unsigned short)deg[i];
    __syncthreads();
    const int CH = (NN + 1023) / 1024;   // 20
    int base = t * CH;
    int s = 0;
    for (int i = 0; i < CH; i++) {
        int idx = base + i;
        if (idx < n) s += sdeg[idx];
    }
    ssum[t] = s;
    __syncthreads();
    for (int off = 1; off < 1024; off <<= 1) {
        int v = (t >= off) ? ssum[t - off] : 0;
        __syncthreads();
        ssum[t] += v;
        __syncthreads();
    }
    int pre = ssum[t] - s;
    for (int i = 0; i < CH; i++) {
        int idx = base + i;
        if (idx < n) { rowptr[idx] = pre; pre += sdeg[idx]; }
    }
    if (t == 0) rowptr[n] = total;
}

// -------- scatter edges to CSR slots + alpha1 (as1/ad1 = xb @ va) combo ----------
__global__ __launch_bounds__(256) void scatter_alpha(const int* __restrict__ ei,
                                                     const int* __restrict__ rowptr,
                                                     int* __restrict__ cursor,
                                                     int* __restrict__ esrc,
                                                     const unsigned short* __restrict__ xb,
                                                     const float* __restrict__ va_s,
                                                     const float* __restrict__ va_d,
                                                     float* __restrict__ as1,
                                                     float* __restrict__ ad1) {
    const int E = EE, Np = NN;
    const int SB = (E + Np + 255) / 256;
    int b = blockIdx.x;
    if (b < SB) {
        int e = b * 256 + threadIdx.x;
        if (e >= E + Np) return;
        int s = (e < E) ? ei[e] : e - E;
        int d = (e < E) ? ei[E + e] : e - E;
        int slot = rowptr[d] + atomicAdd(&cursor[d], 1);
        esrc[slot] = s;
        return;
    }
    int lane = threadIdx.x & 63;
    int n = (b - SB) * 4 + (threadIdx.x >> 6);
    if (n >= NN) return;
    unsigned xv = *(const unsigned*)(xb + (size_t)n * VIN + lane * 2);
    float x0 = bf2f((unsigned short)(xv & 0xffffu));
    float x1 = bf2f((unsigned short)(xv >> 16));
    float4 vs0 = *(const float4*)(va_s + (lane * 2) * 4);
    float4 vs1 = *(const float4*)(va_s + (lane * 2 + 1) * 4);
    float4 vd0 = *(const float4*)(va_d + (lane * 2) * 4);
    float4 vd1 = *(const float4*)(va_d + (lane * 2 + 1) * 4);
    float s0 = fmaf(x0, vs0.x, x1 * vs1.x);
    float s1 = fmaf(x0, vs0.y, x1 * vs1.y);
    float s2 = fmaf(x0, vs0.z, x1 * vs1.z);
    float s3 = fmaf(x0, vs0.w, x1 * vs1.w);
    float d0 = fmaf(x0, vd0.x, x1 * vd1.x);
    float d1 = fmaf(x0, vd0.y, x1 * vd1.y);
    float d2 = fmaf(x0, vd0.z, x1 * vd1.z);
    float d3 = fmaf(x0, vd0.w, x1 * vd1.w);
#pragma unroll
    for (int o = 32; o > 0; o >>= 1) {
        s0 += __shfl_xor(s0, o); s1 += __shfl_xor(s1, o);
        s2 += __shfl_xor(s2, o); s3 += __shfl_xor(s3, o);
        d0 += __shfl_xor(d0, o); d1 += __shfl_xor(d1, o);
        d2 += __shfl_xor(d2, o); d3 += __shfl_xor(d3, o);
    }
    if (lane == 0) {
        *(float4*)(as1 + (size_t)n * 4) = make_float4(s0, s1, s2, s3);
        *(float4*)(ad1 + (size_t)n * 4) = make_float4(d0, d1, d2, d3);
    }
}

// -------- fused softmax + x-space aggregation, H=4 (one wave per node) -----------
// xagg[n, h*128+c] = (1/sum_h) * sum_e p_e^h * x[src_e, c]
__global__ __launch_bounds__(256) void attn_aggr_x4(const int* __restrict__ rowptr,
                                                    const int* __restrict__ esrc,
                                                    const float* __restrict__ as4,
                                                    const float* __restrict__ ad4,
                                                    const unsigned short* __restrict__ xb,
                                                    unsigned short* __restrict__ xagg) {
    int lane = threadIdx.x & 63;
    int n = blockIdx.x * 4 + (threadIdx.x >> 6);
    if (n >= NN) return;
    int beg = rowptr[n], end = rowptr[n + 1];
    int deg = end - beg;
    float4 adn = *(const float4*)(ad4 + (size_t)n * 4);
    // phase A: per-head segment max (lane-strided)
    float m0 = -INFINITY, m1 = -INFINITY, m2 = -INFINITY, m3 = -INFINITY;
    for (int j = beg + lane; j < end; j += 64) {
        float4 av = *(const float4*)(as4 + (size_t)esrc[j] * 4);
        m0 = fmaxf(m0, leaky(av.x + adn.x));
        m1 = fmaxf(m1, leaky(av.y + adn.y));
        m2 = fmaxf(m2, leaky(av.z + adn.z));
        m3 = fmaxf(m3, leaky(av.w + adn.w));
    }
#pragma unroll
    for (int o = 32; o > 0; o >>= 1) {
        m0 = fmaxf(m0, __shfl_xor(m0, o));
        m1 = fmaxf(m1, __shfl_xor(m1, o));
        m2 = fmaxf(m2, __shfl_xor(m2, o));
        m3 = fmaxf(m3, __shfl_xor(m3, o));
    }
    // phase B: denom; keep first-64 p and src in registers
    float pk0 = 0.f, pk1 = 0.f, pk2 = 0.f, pk3 = 0.f;
    int sk = 0;
    float s0 = 0.f, s1 = 0.f, s2 = 0.f, s3 = 0.f;
    for (int j = beg + lane; j < end; j += 64) {
        int s = esrc[j];
        float4 av = *(const float4*)(as4 + (size_t)s * 4);
        float e0 = __expf(leaky(av.x + adn.x) - m0);
        float e1 = __expf(leaky(av.y + adn.y) - m1);
        float e2 = __expf(leaky(av.z + adn.z) - m2);
        float e3 = __expf(leaky(av.w + adn.w) - m3);
        if (j - beg < 64) { pk0 = e0; pk1 = e1; pk2 = e2; pk3 = e3; sk = s; }
        s0 += e0; s1 += e1; s2 += e2; s3 += e3;
    }
#pragma unroll
    for (int o = 32; o > 0; o >>= 1) {
        s0 += __shfl_xor(s0, o); s1 += __shfl_xor(s1, o);
        s2 += __shfl_xor(s2, o); s3 += __shfl_xor(s3, o);
    }
    float i0 = 1.f / (s0 + 1e-16f), i1 = 1.f / (s1 + 1e-16f);
    float i2 = 1.f / (s2 + 1e-16f), i3 = 1.f / (s3 + 1e-16f);
    // phase C: serial edge walk; p/src broadcast via shfl; lane owns 2 x-channels
    float a00 = 0.f, a01 = 0.f, a10 = 0.f, a11 = 0.f;
    float a20 = 0.f, a21 = 0.f, a30 = 0.f, a31 = 0.f;
    const unsigned short* xrow = xb + lane * 2;
    int cap = deg < 64 ? deg : 64;
    for (int jj = 0; jj < cap; jj++) {
        int s = __shfl(sk, jj);
        float p0 = __shfl(pk0, jj), p1 = __shfl(pk1, jj);
        float p2 = __shfl(pk2, jj), p3 = __shfl(pk3, jj);
        unsigned xv = *(const unsigned*)(xrow + (size_t)s * VIN);
        float x0 = bf2f((unsigned short)(xv & 0xffffu));
        float x1 = bf2f((unsigned short)(xv >> 16));
        a00 = fmaf(p0, x0, a00); a01 = fmaf(p0, x1, a01);
        a10 = fmaf(p1, x0, a10); a11 = fmaf(p1, x1, a11);
        a20 = fmaf(p2, x0, a20); a21 = fmaf(p2, x1, a21);
        a30 = fmaf(p3, x0, a30); a31 = fmaf(p3, x1, a31);
    }
    for (int jj = 64; jj < deg; jj++) {      // rare overflow path
        int s = esrc[beg + jj];
        float4 av = *(const float4*)(as4 + (size_t)s * 4);
        float p0 = __expf(leaky(av.x + adn.x) - m0);
        float p1 = __expf(leaky(av.y + adn.y) - m1);
        float p2 = __expf(leaky(av.z + adn.z) - m2);
        float p3 = __expf(leaky(av.w + adn.w) - m3);
        unsigned xv = *(const unsigned*)(xrow + (size_t)s * VIN);
        float x0 = bf2f((unsigned short)(xv & 0xffffu));
        float x1 = bf2f((unsigned short)(xv >> 16));
        a00 = fmaf(p0, x0, a00); a01 = fmaf(p0, x1, a01);
        a10 = fmaf(p1, x0, a10); a11 = fmaf(p1, x1, a11);
        a20 = fmaf(p2, x0, a20); a21 = fmaf(p2, x1, a21);
        a30 = fmaf(p3, x0, a30); a31 = fmaf(p3, x1, a31);
    }
    unsigned* obase = (unsigned*)(xagg + (size_t)n * 512 + lane * 2);
    obase[0]  = packbf2(a00 * i0, a01 * i0);
    obase[64] = packbf2(a10 * i1, a11 * i1);    // +128 ushorts = +64 unsigned
    obase[128] = packbf2(a20 * i2, a21 * i2);
    obase[192] = packbf2(a30 * i3, a31 * i3);
}

// -------- gemm_agg: out1[n, h*128+c'] = xagg[n,h,:] @ W1[:, h*128+c'] ------------
// grid (mblk, 4 heads); fused BN1 stats (col sum/sumsq of f32 acc) via LDS+atomics
__global__ __launch_bounds__(256) void gemm_agg(const unsigned short* __restrict__ A,
                                                const unsigned short* __restrict__ Bp,
                                                unsigned short* __restrict__ C,
                                                float* __restrict__ stats, int M) {
    constexpr int KT = 4;            // K = 128
    __shared__ float sred[128];
    __shared__ float qred[128];
    if (threadIdx.x < 128) { sred[threadIdx.x] = 0.f; qred[threadIdx.x] = 0.f; }
    __syncthreads();
    int wave = threadIdx.x >> 6, lane = threadIdx.x & 63;
    int hh = blockIdx.y;
    int row0 = (blockIdx.x * 4 + wave) * 16;
    bool act = row0 < M;
    int rowc = act ? row0 : 0;
    int r = lane & 15, quad = lane >> 4;
    short8 af[KT];
    const unsigned short* arow = A + (size_t)(rowc + r) * 512 + hh * CONVD + quad * 8;
#pragma unroll
    for (int kt = 0; kt < KT; kt++) af[kt] = *(const short8*)(arow + kt * 32);
#pragma unroll
    for (int nt = 0; nt < 8; nt++) {
        floatx4 acc = {0.f, 0.f, 0.f, 0.f};
        const unsigned short* bbase = Bp + (((size_t)(hh * 8 + nt) * KT) << 9) + lane * 8;
#pragma unroll
        for (int kt = 0; kt < KT; kt++) {
            short8 bf = *(const short8*)(bbase + ((size_t)kt << 9));
            acc = __builtin_amdgcn_mfma_f32_16x16x32_bf16(af[kt], bf, acc, 0, 0, 0);
        }
        int col = (hh * 8 + nt) * 16 + r;
        unsigned short* cbase = C + (size_t)(rowc + quad * 4) * 512 + col;
        float ls = 0.f, lq = 0.f;
#pragma unroll
        for (int reg = 0; reg < 4; reg++) {
            float v = acc[reg];
            if (act) cbase[(size_t)reg * 512] = f2bf(v);
            ls += v;
            lq = fmaf(v, v, lq);
        }
        if (!act) { ls = 0.f; lq = 0.f; }
        ls += __shfl_xor(ls, 16); ls += __shfl_xor(ls, 32);
        lq += __shfl_xor(lq, 16); lq += __shfl_xor(lq, 32);
        if (quad == 0) {
            atomicAdd(&sred[nt * 16 + r], ls);
            atomicAdd(&qred[nt * 16 + r], lq);
        }
    }
    __syncthreads();
    if (threadIdx.x < 128) {
        int col = hh * CONVD + threadIdx.x;
        atomicAdd(&stats[col], sred[threadIdx.x]);
        atomicAdd(&stats[512 + col], qred[threadIdx.x]);
    }
}

// ---------------- BN finalize: stats -> per-channel scale/shift ------------------
// stats are over pre-bias v; bias cancels exactly in BN: S = g/sigma, T = beta - mu*S
__global__ void bn_finalize(const float* __restrict__ stats,
                            const float* __restrict__ gamma, const float* __restrict__ beta,
                            float* __restrict__ S, float* __restrict__ T, int Nn, int C) {
    int c = blockIdx.x * blockDim.x + threadIdx.x;
    if (c >= C) return;
    float inv_n = 1.f / (float)Nn;
    float mu = stats[c] * inv_n;
    float var = stats[C + c] * inv_n - mu * mu;
    float s = gamma[c] * rsqrtf(var + EPS_BN);
    S[c] = s;
    T[c] = fmaf(-mu, s, beta[c]);
}

// ---- GEMM2 + fused layer-1 BN on A-load + fused alpha: h2 = bn(out1)@W2 ---------
__global__ __launch_bounds__(256) void gemm2_bn_alpha(const unsigned short* __restrict__ A,
                                                      const unsigned short* __restrict__ Bp,
                                                      const float* __restrict__ S,
                                                      const float* __restrict__ T,
                                                      const float* __restrict__ a_s,
                                                      const float* __restrict__ a_d,
                                                      unsigned short* __restrict__ C,
                                                      float* __restrict__ as_out,
                                                      float* __restrict__ ad_out, int M) {
    constexpr int K = 512;
    constexpr int Nn = CONVD;         // 128
    constexpr int KT = K / 32;        // 16
    int wave = threadIdx.x >> 6, lane = threadIdx.x & 63;
    int row0 = (blockIdx.x * 4 + wave) * 16;
    if (row0 >= M) return;
    int r = lane & 15, quad = lane >> 4;
    short8 af[KT];
    const unsigned short* arow = A + (size_t)(row0 + r) * K + quad * 8;
#pragma unroll
    for (int kt = 0; kt < KT; kt++) {
        short8 raw = *(const short8*)(arow + kt * 32);
        int k = kt * 32 + quad * 8;
        float4 s0 = *(const float4*)(S + k);
        float4 s1 = *(const float4*)(S + k + 4);
        float4 t0 = *(const float4*)(T + k);
        float4 t1 = *(const float4*)(T + k + 4);
        float sv[8] = {s0.x, s0.y, s0.z, s0.w, s1.x, s1.y, s1.z, s1.w};
        float tv[8] = {t0.x, t0.y, t0.z, t0.w, t1.x, t1.y, t1.z, t1.w};
        short8 o;
#pragma unroll
        for (int i = 0; i < 8; i++) {
            float v = fmaf(bf2f((unsigned short)raw[i]), sv[i], tv[i]);
            o[i] = (short)f2bf(v > 0.f ? v : 0.f);
        }
        af[kt] = o;
    }
    float asp[4] = {}, adp[4] = {};
#pragma unroll
    for (int nt = 0; nt < 8; nt++) {
        floatx4 acc = {0.f, 0.f, 0.f, 0.f};
        const unsigned short* bbase = Bp + (((size_t)nt * KT) << 9) + lane * 8;
#pragma unroll
        for (int kt = 0; kt < KT; kt++) {
            short8 bf = *(const short8*)(bbase + ((size_t)kt << 9));
            acc = __builtin_amdgcn_mfma_f32_16x16x32_bf16(af[kt], bf, acc, 0, 0, 0);
        }
        int col = nt * 16 + r;
        unsigned short* cbase = C + (size_t)(row0 + quad * 4) * Nn + col;
        float sv = a_s[col];
        float dv = a_d[col];
#pragma unroll
        for (int reg = 0; reg < 4; reg++) {
            cbase[(size_t)reg * Nn] = f2bf(acc[reg]);
            asp[reg] = fmaf(acc[reg], sv, asp[reg]);
            adp[reg] = fmaf(acc[reg], dv, adp[reg]);
        }
    }
#pragma unroll
    for (int msk = 1; msk < 16; msk <<= 1) {
#pragma unroll
        for (int reg = 0; reg < 4; reg++) {
            asp[reg] += __shfl_xor(asp[reg], msk);
            adp[reg] += __shfl_xor(adp[reg], msk);
        }
    }
    if (r < 4) {
        int row = row0 + quad * 4 + r;
        as_out[row] = asp[r];
        ad_out[row] = adp[r];
    }
}

// -------- fused softmax + aggregation, H=1 (one wave per node) -------------------
__global__ __launch_bounds__(256) void attn_aggr1(const int* __restrict__ rowptr,
                                                  const int* __restrict__ esrc,
                                                  const float* __restrict__ as,
                                                  const float* __restrict__ ad,
                                                  const unsigned short* __restrict__ h,
                                                  float* __restrict__ out) {
    int lane = threadIdx.x & 63;
    int n = blockIdx.x * 4 + (threadIdx.x >> 6);
    if (n >= NN) return;
    int beg = rowptr[n], end = rowptr[n + 1];
    int deg = end - beg;
    float adn = ad[n];
    float m = -INFINITY;
    for (int j = beg + lane; j < end; j += 64)
        m = fmaxf(m, leaky(as[esrc[j]] + adn));
#pragma unroll
    for (int o = 32; o > 0; o >>= 1) m = fmaxf(m, __shfl_xor(m, o));
    float pk = 0.f;
    int sk = 0;
    float sum = 0.f;
    for (int j = beg + lane; j < end; j += 64) {
        int s = esrc[j];
        float e = __expf(leaky(as[s] + adn) - m);
        if (j - beg < 64) { pk = e; sk = s; }
        sum += e;
    }
#pragma unroll
    for (int o = 32; o > 0; o >>= 1) sum += __shfl_xor(sum, o);
    float inv = 1.f / (sum + 1e-16f);
    float a0 = 0.f, a1 = 0.f;
    const unsigned short* hrow = h + lane * 2;
    int cap = deg < 64 ? deg : 64;
    for (int jj = 0; jj < cap; jj++) {
        int s = __shfl(sk, jj);
        float p = __shfl(pk, jj);
        unsigned xv = *(const unsigned*)(hrow + (size_t)s * CONVD);
        a0 = fmaf(p, bf2f((unsigned short)(xv & 0xffffu)), a0);
        a1 = fmaf(p, bf2f((unsigned short)(xv >> 16)), a1);
    }
    for (int jj = 64; jj < deg; jj++) {
        int s = esrc[beg + jj];
        float p = __expf(leaky(as[s] + adn) - m);
        unsigned xv = *(const unsigned*)(hrow + (size_t)s * CONVD);
        a0 = fmaf(p, bf2f((unsigned short)(xv & 0xffffu)), a0);
        a1 = fmaf(p, bf2f((unsigned short)(xv >> 16)), a1);
    }
    *(float2*)(out + (size_t)n * CONVD + lane * 2) = make_float2(a0 * inv, a1 * inv);
}

// ---------------- BN stats (f32 input) ----------------
__global__ void bn_stats_f32(const float* __restrict__ x, const float* __restrict__ bias,
                             float* __restrict__ stats, int Nn, int C) {
    const int ROWS = 64;
    int r0 = blockIdx.x * ROWS;
    int rend = min(r0 + ROWS, Nn);
    for (int c = threadIdx.x; c < C; c += blockDim.x) {
        float b = bias[c];
        float s1 = 0.f, s2 = 0.f;
        for (int r = r0; r < rend; r++) {
            float v = x[(size_t)r * C + c] + b;
            s1 += v;
            s2 = fmaf(v, v, s2);
        }
        atomicAdd(&stats[c], s1);
        atomicAdd(&stats[C + c], s2);
    }
}

// ---------------- BN apply + ReLU + pool (layer 2, fused) ------------------------
__global__ void bn_apply_pool(const float* __restrict__ x, const float* __restrict__ bias,
                              const float* __restrict__ stats,
                              const float* __restrict__ gamma, const float* __restrict__ beta,
                              const int* __restrict__ batch, float* __restrict__ z,
                              int Nn, int C) {
    int idx = blockIdx.x * blockDim.x + threadIdx.x;
    if (idx >= Nn * C) return;
    int c = idx % C;
    int n = idx / C;
    float inv_n = 1.f / (float)Nn;
    float mu = stats[c] * inv_n;
    float var = stats[C + c] * inv_n - mu * mu;
    float v = (x[idx] + bias[c] - mu) * rsqrtf(var + EPS_BN);
    v = fmaf(gamma[c], v, beta[c]);
    v = v > 0.f ? v : 0.f;
    atomicAdd(&z[batch[n] * C + c], v);
}

// ---------------- fused MLP head: one block per graph ----------------
__global__ __launch_bounds__(320) void mlp_kernel(const float* __restrict__ g,
                           const float* __restrict__ extras,
                           const float* __restrict__ Wm1, const float* __restrict__ bm1,
                           const float* __restrict__ Wm2, const float* __restrict__ bm2,
                           const float* __restrict__ Wm3, const float* __restrict__ bm3,
                           float* __restrict__ out) {
    const int Z0 = CONVD + NXD;   // 137
    const int Z1 = NETD + NXD;    // 265
    const int Z2 = NETD;          // 256
    __shared__ float z[Z0];
    __shared__ float z1[Z1];
    __shared__ float z2[Z2];
    __shared__ float wred[5];
    int gi = blockIdx.x, t = threadIdx.x;
    if (t < CONVD) z[t] = g[gi * CONVD + t];
    else if (t < Z0) z[t] = extras[gi * NXD + (t - CONVD)];
    __syncthreads();
    if (t < Z1) {
        float acc = bm1[t];
        for (int k = 0; k < Z0; k++) acc = fmaf(z[k], Wm1[k * Z1 + t], acc);
        z1[t] = acc > 0.f ? acc : 0.f;
    }
    __syncthreads();
    if (t < Z2) {
        float acc = bm2[t];
        for (int k = 0; k < Z1; k++) acc = fmaf(z1[k], Wm2[k * Z2 + t], acc);
        z2[t] = acc > 0.f ? acc : 0.f;
    }
    __syncthreads();
    float partial = (t < Z2) ? z2[t] * Wm3[t] : 0.f;
    for (int o = 32; o > 0; o >>= 1) partial += __shfl_down(partial, o);
    int wv = t >> 6, ln = t & 63;
    if (ln == 0) wred[wv] = partial;
    __syncthreads();
    if (t == 0) {
        float s = bm3[0];
        for (int i = 0; i < 5; i++) s += wred[i];
        out[gi] = s;
    }
}

// ---------------- launch ----------------
extern "C" void kernel_launch(void* const* d_in, const int* in_sizes, int n_in,
                              void* d_out, int out_size, void* d_ws, size_t ws_size,
                              hipStream_t stream) {
    const float* x      = (const float*)d_in[0];
    const int*   ei     = (const int*)d_in[1];
    const int*   batch  = (const int*)d_in[2];
    const float* extras = (const float*)d_in[3];
    const float* W1     = (const float*)d_in[4];
    const float* a_s1   = (const float*)d_in[5];
    const float* a_d1   = (const float*)d_in[6];
    const float* b1     = (const float*)d_in[7];
    const float* W2     = (const float*)d_in[8];
    const float* a_s2   = (const float*)d_in[9];
    const float* a_d2   = (const float*)d_in[10];
    const float* b2     = (const float*)d_in[11];
    const float* gamma1 = (const float*)d_in[12];
    const float* beta1  = (const float*)d_in[13];
    const float* gamma2 = (const float*)d_in[14];
    const float* beta2  = (const float*)d_in[15];
    const float* Wm1    = (const float*)d_in[16];
    const float* bm1    = (const float*)d_in[17];
    const float* Wm2    = (const float*)d_in[18];
    const float* bm2    = (const float*)d_in[19];
    const float* Wm3    = (const float*)d_in[20];
    const float* bm3    = (const float*)d_in[21];
    float* out = (float*)d_out;

    const int N = NN, E = EE, EP = EE + NN;

    char* ws = (char*)d_ws;
    size_t off = 0;
    auto alloc = [&](size_t bytes) -> void* {
        void* pp = (void*)(ws + off);
        off += (bytes + 255) & ~(size_t)255;
        return pp;
    };
    // --- zero region (contiguous; one small memset) ---
    int*   deg    = (int*)alloc((size_t)N * 4);
    int*   cursor = (int*)alloc((size_t)N * 4);
    float* stats1 = (float*)alloc(512 * 2 * 4);
    float* stats2 = (float*)alloc(128 * 2 * 4);
    float* zbuf   = (float*)alloc((size_t)GG * CONVD * 4);
    size_t zero_bytes = off;
    // --- scratch (fully overwritten each launch) ---
    int*   rowptr = (int*)alloc((size_t)(N + 1) * 4);
    int*   esrc   = (int*)alloc((size_t)EP * 4);
    unsigned short* xb    = (unsigned short*)alloc((size_t)N * VIN * 2);
    unsigned short* W1p   = (unsigned short*)alloc((size_t)VIN * 512 * 2);
    unsigned short* W2p   = (unsigned short*)alloc((size_t)512 * 128 * 2);
    unsigned short* xagg  = (unsigned short*)alloc((size_t)N * 512 * 2);
    unsigned short* out1b = (unsigned short*)alloc((size_t)N * 512 * 2);
    unsigned short* h2b   = (unsigned short*)alloc((size_t)N * 128 * 2);
    float* out2   = (float*)alloc((size_t)N * 128 * 4);
    float* as1    = (float*)alloc((size_t)N * 4 * 4);
    float* ad1    = (float*)alloc((size_t)N * 4 * 4);
    float* as2    = (float*)alloc((size_t)N * 4);
    float* ad2    = (float*)alloc((size_t)N * 4);
    float* va_s   = (float*)alloc(VIN * 4 * 4);
    float* va_d   = (float*)alloc(VIN * 4 * 4);
    float* S1     = (float*)alloc(512 * 4);
    float* T1     = (float*)alloc(512 * 4);

    hipMemsetAsync(d_ws, 0, zero_bytes, stream);

    int eb = (EP + 255) / 256;                 // 1642
    int nrow = (N + 63) / 64;                  // 313
    int mblk = (N + 63) / 64;                  // 313
    int nblk4 = (N + 3) / 4;                   // 5000
    int prep_blocks = (N * VIN + 255) / 256 + 256 + 256 + eb + 4;
    int sa_blocks = eb + nblk4;

    // ---- prep (cast + packs + histogram + va) ----
    prep_kernel<<<prep_blocks, 256, 0, stream>>>(x, xb, W1, W1p, W2, W2p, ei, deg,
                                                 a_s1, a_d1, va_s, va_d);

    // ---- CSR build + alpha1 ----
    scan_kernel<<<1, 1024, 0, stream>>>(deg, rowptr, N, EP);
    scatter_alpha<<<sa_blocks, 256, 0, stream>>>(ei, rowptr, cursor, esrc, xb, va_s, va_d, as1, ad1);

    // ---- GAT layer 1 (H=4, concat): x-space aggregation then per-head GEMM ----
    attn_aggr_x4<<<nblk4, 256, 0, stream>>>(rowptr, esrc, as1, ad1, xb, xagg);
    gemm_agg<<<dim3(mblk, 4), 256, 0, stream>>>(xagg, W1p, out1b, stats1, N);
    bn_finalize<<<2, 256, 0, stream>>>(stats1, gamma1, beta1, S1, T1, N, 512);

    // ---- GAT layer 2 (H=1) ----
    gemm2_bn_alpha<<<mblk, 256, 0, stream>>>(out1b, W2p, S1, T1, a_s2, a_d2, h2b, as2, ad2, N);
    attn_aggr1<<<nblk4, 256, 0, stream>>>(rowptr, esrc, as2, ad2, h2b, out2);
    bn_stats_f32<<<nrow, 256, 0, stream>>>(out2, b2, stats2, N, 128);
    bn_apply_pool<<<(N * 128 + 255) / 256, 256, 0, stream>>>(out2, b2, stats2, gamma2, beta2, batch, zbuf, N, 128);

    // ---- MLP head ----
    mlp_kernel<<<GG, 320, 0, stream>>>(zbuf, extras, Wm1, bm1, Wm2, bm2, Wm3, bm3, out);
}

// Round 7
// 369.858 us; speedup vs baseline: 3.9961x; 1.0604x over previous
//
#include <hip/hip_runtime.h>
#include <hip/hip_bf16.h>
#include <math.h>

// ---------------- constants (match reference) ----------------
#define NN 20000
#define EE 400000
#define GG 64
#define VIN 128
#define CONVD 128
#define NETD 256
#define NXD 9
#define EPS_BN 1e-5f
#define NEG_SLOPE 0.2f

typedef short short8 __attribute__((ext_vector_type(8)));
typedef float floatx4 __attribute__((ext_vector_type(4)));

__device__ __forceinline__ float leaky(float v) {
    return v >= 0.f ? v : NEG_SLOPE * v;
}
__device__ __forceinline__ unsigned short f2bf(float f) {
    union { float f; unsigned u; } v; v.f = f;
    unsigned r = v.u + 0x7FFFu + ((v.u >> 16) & 1u);   // RNE
    return (unsigned short)(r >> 16);
}
__device__ __forceinline__ float bf2f(unsigned short u) {
    union { unsigned u; float f; } v; v.u = ((unsigned)u) << 16;
    return v.f;
}
__device__ __forceinline__ unsigned packbf2(float a, float b) {
    return (unsigned)f2bf(a) | ((unsigned)f2bf(b) << 16);
}

// ---------------- pack helper: B (f32 [K,Nn]) -> MFMA B-frag layout (bf16) -------
__device__ __forceinline__ void pack_one(const float* __restrict__ B,
                                         unsigned short* __restrict__ Bp,
                                         int K, int Nn, int idx) {
    int j = idx & 7, lane = (idx >> 3) & 63, t = idx >> 9;
    int KT = K >> 5;
    int kt = t % KT, nt = t / KT;
    int k = kt * 32 + (lane >> 4) * 8 + j;
    int n = nt * 16 + (lane & 15);
    Bp[idx] = f2bf(B[(size_t)k * Nn + n]);
}

// ------ prep: cast x->bf16, pack W1, pack W2, dst histogram, va = W1 . a ---------
__global__ void prep_kernel(const float* __restrict__ x, unsigned short* __restrict__ xb,
                            const float* __restrict__ W1, unsigned short* __restrict__ W1p,
                            const float* __restrict__ W2, unsigned short* __restrict__ W2p,
                            const int* __restrict__ ei, int* __restrict__ deg,
                            const float* __restrict__ a_s1, const float* __restrict__ a_d1,
                            float* __restrict__ va_s, float* __restrict__ va_d) {
    const int CB = (NN * VIN + 255) / 256;     // 10000
    const int PB = (VIN * 512) / 256;          // 256
    const int QB = (512 * 128) / 256;          // 256
    const int HB = (EE + NN + 255) / 256;      // 1642
    int b = blockIdx.x;
    if (b < CB) {
        int i = b * 256 + threadIdx.x;
        if (i < NN * VIN) xb[i] = f2bf(x[i]);
    } else if (b < CB + PB) {
        int i = (b - CB) * 256 + threadIdx.x;
        pack_one(W1, W1p, VIN, 512, i);
    } else if (b < CB + PB + QB) {
        int i = (b - CB - PB) * 256 + threadIdx.x;
        pack_one(W2, W2p, 512, 128, i);
    } else if (b < CB + PB + QB + HB) {
        int e = (b - CB - PB - QB) * 256 + threadIdx.x;
        if (e < EE + NN) {
            int d = (e < EE) ? ei[EE + e] : e - EE;
            atomicAdd(&deg[d], 1);
        }
    } else {
        // va: 1024 outputs; i<512 -> va_s[k*4+h], else va_d
        int i = (b - CB - PB - QB - HB) * 256 + threadIdx.x;
        int sd = i >> 9;
        int k = (i & 511) >> 2, h = i & 3;
        const float* a = (sd ? a_d1 : a_s1) + h * CONVD;
        const float* wrow = W1 + (size_t)k * 512 + h * CONVD;
        float acc = 0.f;
        for (int c = 0; c < CONVD; c++) acc = fmaf(wrow[c], a[c], acc);
        (sd ? va_d : va_s)[(k << 2) + h] = acc;
    }
}

// ---------------- single-block exclusive scan (LDS-staged, u16 degrees) ----------
__global__ __launch_bounds__(1024) void scan_kernel(const int* __restrict__ deg,
                                                    int* __restrict__ rowptr,
                                                    int n, int total) {
    __shared__ unsigned short sdeg[NN];
    __shared__ int ssum[1024];
    int t = threadIdx.x;
    for (int i = t; i < n; i += 1024) sdeg[i] = (unsigned short)deg[i];
    __syncthreads();
    const int CH = (NN + 1023) / 1024;   // 20
    int base = t * CH;
    int s = 0;
    for (int i = 0; i < CH; i++) {
        int idx = base + i;
        if (idx < n) s += sdeg[idx];
    }
    ssum[t] = s;
    __syncthreads();
    for (int off = 1; off < 1024; off <<= 1) {
        int v = (t >= off) ? ssum[t - off] : 0;
        __syncthreads();
        ssum[t] += v;
        __syncthreads();
    }
    int pre = ssum[t] - s;
    for (int i = 0; i < CH; i++) {
        int idx = base + i;
        if (idx < n) { rowptr[idx] = pre; pre += sdeg[idx]; }
    }
    if (t == 0) rowptr[n] = total;
}

// -------- scatter edges to CSR slots + alpha1 (as1/ad1 = xb @ va) combo ----------
__global__ __launch_bounds__(256) void scatter_alpha(const int* __restrict__ ei,
                                                     const int* __restrict__ rowptr,
                                                     int* __restrict__ cursor,
                                                     int* __restrict__ esrc,
                                                     const unsigned short* __restrict__ xb,
                                                     const float* __restrict__ va_s,
                                                     const float* __restrict__ va_d,
                                                     float* __restrict__ as1,
                                                     float* __restrict__ ad1) {
    const int E = EE, Np = NN;
    const int SB = (E + Np + 255) / 256;
    int b = blockIdx.x;
    if (b < SB) {
        int e = b * 256 + threadIdx.x;
        if (e >= E + Np) return;
        int s = (e < E) ? ei[e] : e - E;
        int d = (e < E) ? ei[E + e] : e - E;
        int slot = rowptr[d] + atomicAdd(&cursor[d], 1);
        esrc[slot] = s;
        return;
    }
    int lane = threadIdx.x & 63;
    int n = (b - SB) * 4 + (threadIdx.x >> 6);
    if (n >= NN) return;
    unsigned xv = *(const unsigned*)(xb + (size_t)n * VIN + lane * 2);
    float x0 = bf2f((unsigned short)(xv & 0xffffu));
    float x1 = bf2f((unsigned short)(xv >> 16));
    float4 vs0 = *(const float4*)(va_s + (lane * 2) * 4);
    float4 vs1 = *(const float4*)(va_s + (lane * 2 + 1) * 4);
    float4 vd0 = *(const float4*)(va_d + (lane * 2) * 4);
    float4 vd1 = *(const float4*)(va_d + (lane * 2 + 1) * 4);
    float s0 = fmaf(x0, vs0.x, x1 * vs1.x);
    float s1 = fmaf(x0, vs0.y, x1 * vs1.y);
    float s2 = fmaf(x0, vs0.z, x1 * vs1.z);
    float s3 = fmaf(x0, vs0.w, x1 * vs1.w);
    float d0 = fmaf(x0, vd0.x, x1 * vd1.x);
    float d1 = fmaf(x0, vd0.y, x1 * vd1.y);
    float d2 = fmaf(x0, vd0.z, x1 * vd1.z);
    float d3 = fmaf(x0, vd0.w, x1 * vd1.w);
#pragma unroll
    for (int o = 32; o > 0; o >>= 1) {
        s0 += __shfl_xor(s0, o); s1 += __shfl_xor(s1, o);
        s2 += __shfl_xor(s2, o); s3 += __shfl_xor(s3, o);
        d0 += __shfl_xor(d0, o); d1 += __shfl_xor(d1, o);
        d2 += __shfl_xor(d2, o); d3 += __shfl_xor(d3, o);
    }
    if (lane == 0) {
        *(float4*)(as1 + (size_t)n * 4) = make_float4(s0, s1, s2, s3);
        *(float4*)(ad1 + (size_t)n * 4) = make_float4(d0, d1, d2, d3);
    }
}

// -------- fused softmax + x-space aggregation, H=4 (one wave per node) -----------
// phase C pipelined 4-wide: 4 independent gathers in flight per wave
__global__ __launch_bounds__(256) void attn_aggr_x4(const int* __restrict__ rowptr,
                                                    const int* __restrict__ esrc,
                                                    const float* __restrict__ as4,
                                                    const float* __restrict__ ad4,
                                                    const unsigned short* __restrict__ xb,
                                                    unsigned short* __restrict__ xagg) {
    int lane = threadIdx.x & 63;
    int n = blockIdx.x * 4 + (threadIdx.x >> 6);
    if (n >= NN) return;
    int beg = rowptr[n], end = rowptr[n + 1];
    int deg = end - beg;
    float4 adn = *(const float4*)(ad4 + (size_t)n * 4);
    // phase A: per-head segment max (lane-strided)
    float m0 = -INFINITY, m1 = -INFINITY, m2 = -INFINITY, m3 = -INFINITY;
    for (int j = beg + lane; j < end; j += 64) {
        float4 av = *(const float4*)(as4 + (size_t)esrc[j] * 4);
        m0 = fmaxf(m0, leaky(av.x + adn.x));
        m1 = fmaxf(m1, leaky(av.y + adn.y));
        m2 = fmaxf(m2, leaky(av.z + adn.z));
        m3 = fmaxf(m3, leaky(av.w + adn.w));
    }
#pragma unroll
    for (int o = 32; o > 0; o >>= 1) {
        m0 = fmaxf(m0, __shfl_xor(m0, o));
        m1 = fmaxf(m1, __shfl_xor(m1, o));
        m2 = fmaxf(m2, __shfl_xor(m2, o));
        m3 = fmaxf(m3, __shfl_xor(m3, o));
    }
    // phase B: denom; keep first-64 p and src in registers
    float pk0 = 0.f, pk1 = 0.f, pk2 = 0.f, pk3 = 0.f;
    int sk = 0;
    float s0 = 0.f, s1 = 0.f, s2 = 0.f, s3 = 0.f;
    for (int j = beg + lane; j < end; j += 64) {
        int s = esrc[j];
        float4 av = *(const float4*)(as4 + (size_t)s * 4);
        float e0 = __expf(leaky(av.x + adn.x) - m0);
        float e1 = __expf(leaky(av.y + adn.y) - m1);
        float e2 = __expf(leaky(av.z + adn.z) - m2);
        float e3 = __expf(leaky(av.w + adn.w) - m3);
        if (j - beg < 64) { pk0 = e0; pk1 = e1; pk2 = e2; pk3 = e3; sk = s; }
        s0 += e0; s1 += e1; s2 += e2; s3 += e3;
    }
#pragma unroll
    for (int o = 32; o > 0; o >>= 1) {
        s0 += __shfl_xor(s0, o); s1 += __shfl_xor(s1, o);
        s2 += __shfl_xor(s2, o); s3 += __shfl_xor(s3, o);
    }
    float i0 = 1.f / (s0 + 1e-16f), i1 = 1.f / (s1 + 1e-16f);
    float i2 = 1.f / (s2 + 1e-16f), i3 = 1.f / (s3 + 1e-16f);
    // phase C: 4-wide pipelined edge walk
    float a00 = 0.f, a01 = 0.f, a10 = 0.f, a11 = 0.f;
    float a20 = 0.f, a21 = 0.f, a30 = 0.f, a31 = 0.f;
    const unsigned short* xrow = xb + lane * 2;
    int cap = deg < 64 ? deg : 64;
    int jj = 0;
    for (; jj + 3 < cap; jj += 4) {
        int sA = __shfl(sk, jj);
        int sB = __shfl(sk, jj + 1);
        int sC = __shfl(sk, jj + 2);
        int sD = __shfl(sk, jj + 3);
        unsigned xvA = *(const unsigned*)(xrow + (size_t)sA * VIN);
        unsigned xvB = *(const unsigned*)(xrow + (size_t)sB * VIN);
        unsigned xvC = *(const unsigned*)(xrow + (size_t)sC * VIN);
        unsigned xvD = *(const unsigned*)(xrow + (size_t)sD * VIN);
        float pA0 = __shfl(pk0, jj),     pA1 = __shfl(pk1, jj);
        float pA2 = __shfl(pk2, jj),     pA3 = __shfl(pk3, jj);
        float pB0 = __shfl(pk0, jj + 1), pB1 = __shfl(pk1, jj + 1);
        float pB2 = __shfl(pk2, jj + 1), pB3 = __shfl(pk3, jj + 1);
        float pC0 = __shfl(pk0, jj + 2), pC1 = __shfl(pk1, jj + 2);
        float pC2 = __shfl(pk2, jj + 2), pC3 = __shfl(pk3, jj + 2);
        float pD0 = __shfl(pk0, jj + 3), pD1 = __shfl(pk1, jj + 3);
        float pD2 = __shfl(pk2, jj + 3), pD3 = __shfl(pk3, jj + 3);
        float xA0 = bf2f((unsigned short)(xvA & 0xffffu)), xA1 = bf2f((unsigned short)(xvA >> 16));
        float xB0 = bf2f((unsigned short)(xvB & 0xffffu)), xB1 = bf2f((unsigned short)(xvB >> 16));
        float xC0 = bf2f((unsigned short)(xvC & 0xffffu)), xC1 = bf2f((unsigned short)(xvC >> 16));
        float xD0 = bf2f((unsigned short)(xvD & 0xffffu)), xD1 = bf2f((unsigned short)(xvD >> 16));
        a00 = fmaf(pA0, xA0, a00); a01 = fmaf(pA0, xA1, a01);
        a10 = fmaf(pA1, xA0, a10); a11 = fmaf(pA1, xA1, a11);
        a20 = fmaf(pA2, xA0, a20); a21 = fmaf(pA2, xA1, a21);
        a30 = fmaf(pA3, xA0, a30); a31 = fmaf(pA3, xA1, a31);
        a00 = fmaf(pB0, xB0, a00); a01 = fmaf(pB0, xB1, a01);
        a10 = fmaf(pB1, xB0, a10); a11 = fmaf(pB1, xB1, a11);
        a20 = fmaf(pB2, xB0, a20); a21 = fmaf(pB2, xB1, a21);
        a30 = fmaf(pB3, xB0, a30); a31 = fmaf(pB3, xB1, a31);
        a00 = fmaf(pC0, xC0, a00); a01 = fmaf(pC0, xC1, a01);
        a10 = fmaf(pC1, xC0, a10); a11 = fmaf(pC1, xC1, a11);
        a20 = fmaf(pC2, xC0, a20); a21 = fmaf(pC2, xC1, a21);
        a30 = fmaf(pC3, xC0, a30); a31 = fmaf(pC3, xC1, a31);
        a00 = fmaf(pD0, xD0, a00); a01 = fmaf(pD0, xD1, a01);
        a10 = fmaf(pD1, xD0, a10); a11 = fmaf(pD1, xD1, a11);
        a20 = fmaf(pD2, xD0, a20); a21 = fmaf(pD2, xD1, a21);
        a30 = fmaf(pD3, xD0, a30); a31 = fmaf(pD3, xD1, a31);
    }
    for (; jj < cap; jj++) {
        int s = __shfl(sk, jj);
        float p0 = __shfl(pk0, jj), p1 = __shfl(pk1, jj);
        float p2 = __shfl(pk2, jj), p3 = __shfl(pk3, jj);
        unsigned xv = *(const unsigned*)(xrow + (size_t)s * VIN);
        float x0 = bf2f((unsigned short)(xv & 0xffffu));
        float x1 = bf2f((unsigned short)(xv >> 16));
        a00 = fmaf(p0, x0, a00); a01 = fmaf(p0, x1, a01);
        a10 = fmaf(p1, x0, a10); a11 = fmaf(p1, x1, a11);
        a20 = fmaf(p2, x0, a20); a21 = fmaf(p2, x1, a21);
        a30 = fmaf(p3, x0, a30); a31 = fmaf(p3, x1, a31);
    }
    for (int j2 = 64; j2 < deg; j2++) {      // rare overflow path
        int s = esrc[beg + j2];
        float4 av = *(const float4*)(as4 + (size_t)s * 4);
        float p0 = __expf(leaky(av.x + adn.x) - m0);
        float p1 = __expf(leaky(av.y + adn.y) - m1);
        float p2 = __expf(leaky(av.z + adn.z) - m2);
        float p3 = __expf(leaky(av.w + adn.w) - m3);
        unsigned xv = *(const unsigned*)(xrow + (size_t)s * VIN);
        float x0 = bf2f((unsigned short)(xv & 0xffffu));
        float x1 = bf2f((unsigned short)(xv >> 16));
        a00 = fmaf(p0, x0, a00); a01 = fmaf(p0, x1, a01);
        a10 = fmaf(p1, x0, a10); a11 = fmaf(p1, x1, a11);
        a20 = fmaf(p2, x0, a20); a21 = fmaf(p2, x1, a21);
        a30 = fmaf(p3, x0, a31 == a31 ? a30 : a30); a31 = fmaf(p3, x1, a31);
    }
    unsigned* obase = (unsigned*)(xagg + (size_t)n * 512 + lane * 2);
    obase[0]   = packbf2(a00 * i0, a01 * i0);
    obase[64]  = packbf2(a10 * i1, a11 * i1);
    obase[128] = packbf2(a20 * i2, a21 * i2);
    obase[192] = packbf2(a30 * i3, a31 * i3);
}

// -------- gemm_agg: out1[n, h*128+c'] = xagg[n,h,:] @ W1[:, h*128+c'] ------------
__global__ __launch_bounds__(256) void gemm_agg(const unsigned short* __restrict__ A,
                                                const unsigned short* __restrict__ Bp,
                                                unsigned short* __restrict__ C,
                                                float* __restrict__ stats, int M) {
    constexpr int KT = 4;            // K = 128
    __shared__ float sred[128];
    __shared__ float qred[128];
    if (threadIdx.x < 128) { sred[threadIdx.x] = 0.f; qred[threadIdx.x] = 0.f; }
    __syncthreads();
    int wave = threadIdx.x >> 6, lane = threadIdx.x & 63;
    int hh = blockIdx.y;
    int row0 = (blockIdx.x * 4 + wave) * 16;
    bool act = row0 < M;
    int rowc = act ? row0 : 0;
    int r = lane & 15, quad = lane >> 4;
    short8 af[KT];
    const unsigned short* arow = A + (size_t)(rowc + r) * 512 + hh * CONVD + quad * 8;
#pragma unroll
    for (int kt = 0; kt < KT; kt++) af[kt] = *(const short8*)(arow + kt * 32);
#pragma unroll
    for (int nt = 0; nt < 8; nt++) {
        floatx4 acc = {0.f, 0.f, 0.f, 0.f};
        const unsigned short* bbase = Bp + (((size_t)(hh * 8 + nt) * KT) << 9) + lane * 8;
#pragma unroll
        for (int kt = 0; kt < KT; kt++) {
            short8 bf = *(const short8*)(bbase + ((size_t)kt << 9));
            acc = __builtin_amdgcn_mfma_f32_16x16x32_bf16(af[kt], bf, acc, 0, 0, 0);
        }
        int col = (hh * 8 + nt) * 16 + r;
        unsigned short* cbase = C + (size_t)(rowc + quad * 4) * 512 + col;
        float ls = 0.f, lq = 0.f;
#pragma unroll
        for (int reg = 0; reg < 4; reg++) {
            float v = acc[reg];
            if (act) cbase[(size_t)reg * 512] = f2bf(v);
            ls += v;
            lq = fmaf(v, v, lq);
        }
        if (!act) { ls = 0.f; lq = 0.f; }
        ls += __shfl_xor(ls, 16); ls += __shfl_xor(ls, 32);
        lq += __shfl_xor(lq, 16); lq += __shfl_xor(lq, 32);
        if (quad == 0) {
            atomicAdd(&sred[nt * 16 + r], ls);
            atomicAdd(&qred[nt * 16 + r], lq);
        }
    }
    __syncthreads();
    if (threadIdx.x < 128) {
        int col = hh * CONVD + threadIdx.x;
        atomicAdd(&stats[col], sred[threadIdx.x]);
        atomicAdd(&stats[512 + col], qred[threadIdx.x]);
    }
}

// ---- GEMM2: BN-finalize (from stats, in LDS) + BN on A-load + fused alpha -------
__global__ __launch_bounds__(256) void gemm2_bn_alpha(const unsigned short* __restrict__ A,
                                                      const unsigned short* __restrict__ Bp,
                                                      const float* __restrict__ stats,
                                                      const float* __restrict__ gamma,
                                                      const float* __restrict__ beta,
                                                      const float* __restrict__ a_s,
                                                      const float* __restrict__ a_d,
                                                      unsigned short* __restrict__ C,
                                                      float* __restrict__ as_out,
                                                      float* __restrict__ ad_out, int M) {
    constexpr int K = 512;
    constexpr int Nn = CONVD;         // 128
    constexpr int KT = K / 32;        // 16
    __shared__ float Ssm[512];
    __shared__ float Tsm[512];
    for (int c = threadIdx.x; c < 512; c += 256) {
        float inv_n = 1.f / (float)NN;
        float mu = stats[c] * inv_n;
        float var = stats[512 + c] * inv_n - mu * mu;
        float s = gamma[c] * rsqrtf(var + EPS_BN);
        Ssm[c] = s;
        Tsm[c] = fmaf(-mu, s, beta[c]);
    }
    __syncthreads();
    int wave = threadIdx.x >> 6, lane = threadIdx.x & 63;
    int row0 = (blockIdx.x * 4 + wave) * 16;
    if (row0 >= M) return;
    int r = lane & 15, quad = lane >> 4;
    short8 af[KT];
    const unsigned short* arow = A + (size_t)(row0 + r) * K + quad * 8;
#pragma unroll
    for (int kt = 0; kt < KT; kt++) {
        short8 raw = *(const short8*)(arow + kt * 32);
        int k = kt * 32 + quad * 8;
        short8 o;
#pragma unroll
        for (int i = 0; i < 8; i++) {
            float v = fmaf(bf2f((unsigned short)raw[i]), Ssm[k + i], Tsm[k + i]);
            o[i] = (short)f2bf(v > 0.f ? v : 0.f);
        }
        af[kt] = o;
    }
    float asp[4] = {}, adp[4] = {};
#pragma unroll
    for (int nt = 0; nt < 8; nt++) {
        floatx4 acc = {0.f, 0.f, 0.f, 0.f};
        const unsigned short* bbase = Bp + (((size_t)nt * KT) << 9) + lane * 8;
#pragma unroll
        for (int kt = 0; kt < KT; kt++) {
            short8 bf = *(const short8*)(bbase + ((size_t)kt << 9));
            acc = __builtin_amdgcn_mfma_f32_16x16x32_bf16(af[kt], bf, acc, 0, 0, 0);
        }
        int col = nt * 16 + r;
        unsigned short* cbase = C + (size_t)(row0 + quad * 4) * Nn + col;
        float sv = a_s[col];
        float dv = a_d[col];
#pragma unroll
        for (int reg = 0; reg < 4; reg++) {
            cbase[(size_t)reg * Nn] = f2bf(acc[reg]);
            asp[reg] = fmaf(acc[reg], sv, asp[reg]);
            adp[reg] = fmaf(acc[reg], dv, adp[reg]);
        }
    }
#pragma unroll
    for (int msk = 1; msk < 16; msk <<= 1) {
#pragma unroll
        for (int reg = 0; reg < 4; reg++) {
            asp[reg] += __shfl_xor(asp[reg], msk);
            adp[reg] += __shfl_xor(adp[reg], msk);
        }
    }
    if (r < 4) {
        int row = row0 + quad * 4 + r;
        as_out[row] = asp[r];
        ad_out[row] = adp[r];
    }
}

// -------- fused softmax + aggregation, H=1 (one wave per node), pipelined --------
__global__ __launch_bounds__(256) void attn_aggr1(const int* __restrict__ rowptr,
                                                  const int* __restrict__ esrc,
                                                  const float* __restrict__ as,
                                                  const float* __restrict__ ad,
                                                  const unsigned short* __restrict__ h,
                                                  float* __restrict__ out) {
    int lane = threadIdx.x & 63;
    int n = blockIdx.x * 4 + (threadIdx.x >> 6);
    if (n >= NN) return;
    int beg = rowptr[n], end = rowptr[n + 1];
    int deg = end - beg;
    float adn = ad[n];
    float m = -INFINITY;
    for (int j = beg + lane; j < end; j += 64)
        m = fmaxf(m, leaky(as[esrc[j]] + adn));
#pragma unroll
    for (int o = 32; o > 0; o >>= 1) m = fmaxf(m, __shfl_xor(m, o));
    float pk = 0.f;
    int sk = 0;
    float sum = 0.f;
    for (int j = beg + lane; j < end; j += 64) {
        int s = esrc[j];
        float e = __expf(leaky(as[s] + adn) - m);
        if (j - beg < 64) { pk = e; sk = s; }
        sum += e;
    }
#pragma unroll
    for (int o = 32; o > 0; o >>= 1) sum += __shfl_xor(sum, o);
    float inv = 1.f / (sum + 1e-16f);
    float a0 = 0.f, a1 = 0.f, b0 = 0.f, b1 = 0.f;
    const unsigned short* hrow = h + lane * 2;
    int cap = deg < 64 ? deg : 64;
    int jj = 0;
    for (; jj + 3 < cap; jj += 4) {
        int sA = __shfl(sk, jj);
        int sB = __shfl(sk, jj + 1);
        int sC = __shfl(sk, jj + 2);
        int sD = __shfl(sk, jj + 3);
        unsigned xvA = *(const unsigned*)(hrow + (size_t)sA * CONVD);
        unsigned xvB = *(const unsigned*)(hrow + (size_t)sB * CONVD);
        unsigned xvC = *(const unsigned*)(hrow + (size_t)sC * CONVD);
        unsigned xvD = *(const unsigned*)(hrow + (size_t)sD * CONVD);
        float pA = __shfl(pk, jj),     pB = __shfl(pk, jj + 1);
        float pC = __shfl(pk, jj + 2), pD = __shfl(pk, jj + 3);
        a0 = fmaf(pA, bf2f((unsigned short)(xvA & 0xffffu)), a0);
        a1 = fmaf(pA, bf2f((unsigned short)(xvA >> 16)), a1);
        b0 = fmaf(pB, bf2f((unsigned short)(xvB & 0xffffu)), b0);
        b1 = fmaf(pB, bf2f((unsigned short)(xvB >> 16)), b1);
        a0 = fmaf(pC, bf2f((unsigned short)(xvC & 0xffffu)), a0);
        a1 = fmaf(pC, bf2f((unsigned short)(xvC >> 16)), a1);
        b0 = fmaf(pD, bf2f((unsigned short)(xvD & 0xffffu)), b0);
        b1 = fmaf(pD, bf2f((unsigned short)(xvD >> 16)), b1);
    }
    for (; jj < cap; jj++) {
        int s = __shfl(sk, jj);
        float p = __shfl(pk, jj);
        unsigned xv = *(const unsigned*)(hrow + (size_t)s * CONVD);
        a0 = fmaf(p, bf2f((unsigned short)(xv & 0xffffu)), a0);
        a1 = fmaf(p, bf2f((unsigned short)(xv >> 16)), a1);
    }
    for (int j2 = 64; j2 < deg; j2++) {
        int s = esrc[beg + j2];
        float p = __expf(leaky(as[s] + adn) - m);
        unsigned xv = *(const unsigned*)(hrow + (size_t)s * CONVD);
        a0 = fmaf(p, bf2f((unsigned short)(xv & 0xffffu)), a0);
        a1 = fmaf(p, bf2f((unsigned short)(xv >> 16)), a1);
    }
    a0 += b0; a1 += b1;
    *(float2*)(out + (size_t)n * CONVD + lane * 2) = make_float2(a0 * inv, a1 * inv);
}

// ---------------- BN stats (f32 input) ----------------
__global__ void bn_stats_f32(const float* __restrict__ x, const float* __restrict__ bias,
                             float* __restrict__ stats, int Nn, int C) {
    const int ROWS = 64;
    int r0 = blockIdx.x * ROWS;
    int rend = min(r0 + ROWS, Nn);
    for (int c = threadIdx.x; c < C; c += blockDim.x) {
        float b = bias[c];
        float s1 = 0.f, s2 = 0.f;
        for (int r = r0; r < rend; r++) {
            float v = x[(size_t)r * C + c] + b;
            s1 += v;
            s2 = fmaf(v, v, s2);
        }
        atomicAdd(&stats[c], s1);
        atomicAdd(&stats[C + c], s2);
    }
}

// ---------------- BN apply + ReLU + pool (layer 2, fused) ------------------------
__global__ void bn_apply_pool(const float* __restrict__ x, const float* __restrict__ bias,
                              const float* __restrict__ stats,
                              const float* __restrict__ gamma, const float* __restrict__ beta,
                              const int* __restrict__ batch, float* __restrict__ z,
                              int Nn, int C) {
    int idx = blockIdx.x * blockDim.x + threadIdx.x;
    if (idx >= Nn * C) return;
    int c = idx % C;
    int n = idx / C;
    float inv_n = 1.f / (float)Nn;
    float mu = stats[c] * inv_n;
    float var = stats[C + c] * inv_n - mu * mu;
    float v = (x[idx] + bias[c] - mu) * rsqrtf(var + EPS_BN);
    v = fmaf(gamma[c], v, beta[c]);
    v = v > 0.f ? v : 0.f;
    atomicAdd(&z[batch[n] * C + c], v);
}

// ---------------- fused MLP head: one block per graph ----------------
__global__ __launch_bounds__(320) void mlp_kernel(const float* __restrict__ g,
                           const float* __restrict__ extras,
                           const float* __restrict__ Wm1, const float* __restrict__ bm1,
                           const float* __restrict__ Wm2, const float* __restrict__ bm2,
                           const float* __restrict__ Wm3, const float* __restrict__ bm3,
                           float* __restrict__ out) {
    const int Z0 = CONVD + NXD;   // 137
    const int Z1 = NETD + NXD;    // 265
    const int Z2 = NETD;          // 256
    __shared__ float z[Z0];
    __shared__ float z1[Z1];
    __shared__ float z2[Z2];
    __shared__ float wred[5];
    int gi = blockIdx.x, t = threadIdx.x;
    if (t < CONVD) z[t] = g[gi * CONVD + t];
    else if (t < Z0) z[t] = extras[gi * NXD + (t - CONVD)];
    __syncthreads();
    if (t < Z1) {
        float acc = bm1[t];
        for (int k = 0; k < Z0; k++) acc = fmaf(z[k], Wm1[k * Z1 + t], acc);
        z1[t] = acc > 0.f ? acc : 0.f;
    }
    __syncthreads();
    if (t < Z2) {
        float acc = bm2[t];
        for (int k = 0; k < Z1; k++) acc = fmaf(z1[k], Wm2[k * Z2 + t], acc);
        z2[t] = acc > 0.f ? acc : 0.f;
    }
    __syncthreads();
    float partial = (t < Z2) ? z2[t] * Wm3[t] : 0.f;
    for (int o = 32; o > 0; o >>= 1) partial += __shfl_down(partial, o);
    int wv = t >> 6, ln = t & 63;
    if (ln == 0) wred[wv] = partial;
    __syncthreads();
    if (t == 0) {
        float s = bm3[0];
        for (int i = 0; i < 5; i++) s += wred[i];
        out[gi] = s;
    }
}

// ---------------- launch ----------------
extern "C" void kernel_launch(void* const* d_in, const int* in_sizes, int n_in,
                              void* d_out, int out_size, void* d_ws, size_t ws_size,
                              hipStream_t stream) {
    const float* x      = (const float*)d_in[0];
    const int*   ei     = (const int*)d_in[1];
    const int*   batch  = (const int*)d_in[2];
    const float* extras = (const float*)d_in[3];
    const float* W1     = (const float*)d_in[4];
    const float* a_s1   = (const float*)d_in[5];
    const float* a_d1   = (const float*)d_in[6];
    const float* b1     = (const float*)d_in[7];
    const float* W2     = (const float*)d_in[8];
    const float* a_s2   = (const float*)d_in[9];
    const float* a_d2   = (const float*)d_in[10];
    const float* b2     = (const float*)d_in[11];
    const float* gamma1 = (const float*)d_in[12];
    const float* beta1  = (const float*)d_in[13];
    const float* gamma2 = (const float*)d_in[14];
    const float* beta2  = (const float*)d_in[15];
    const float* Wm1    = (const float*)d_in[16];
    const float* bm1    = (const float*)d_in[17];
    const float* Wm2    = (const float*)d_in[18];
    const float* bm2    = (const float*)d_in[19];
    const float* Wm3    = (const float*)d_in[20];
    const float* bm3    = (const float*)d_in[21];
    float* out = (float*)d_out;

    const int N = NN, E = EE, EP = EE + NN;

    char* ws = (char*)d_ws;
    size_t off = 0;
    auto alloc = [&](size_t bytes) -> void* {
        void* pp = (void*)(ws + off);
        off += (bytes + 255) & ~(size_t)255;
        return pp;
    };
    // --- zero region (contiguous; one small memset) ---
    int*   deg    = (int*)alloc((size_t)N * 4);
    int*   cursor = (int*)alloc((size_t)N * 4);
    float* stats1 = (float*)alloc(512 * 2 * 4);
    float* stats2 = (float*)alloc(128 * 2 * 4);
    float* zbuf   = (float*)alloc((size_t)GG * CONVD * 4);
    size_t zero_bytes = off;
    // --- scratch (fully overwritten each launch) ---
    int*   rowptr = (int*)alloc((size_t)(N + 1) * 4);
    int*   esrc   = (int*)alloc((size_t)EP * 4);
    unsigned short* xb    = (unsigned short*)alloc((size_t)N * VIN * 2);
    unsigned short* W1p   = (unsigned short*)alloc((size_t)VIN * 512 * 2);
    unsigned short* W2p   = (unsigned short*)alloc((size_t)512 * 128 * 2);
    unsigned short* xagg  = (unsigned short*)alloc((size_t)N * 512 * 2);
    unsigned short* out1b = (unsigned short*)alloc((size_t)N * 512 * 2);
    unsigned short* h2b   = (unsigned short*)alloc((size_t)N * 128 * 2);
    float* out2   = (float*)alloc((size_t)N * 128 * 4);
    float* as1    = (float*)alloc((size_t)N * 4 * 4);
    float* ad1    = (float*)alloc((size_t)N * 4 * 4);
    float* as2    = (float*)alloc((size_t)N * 4);
    float* ad2    = (float*)alloc((size_t)N * 4);
    float* va_s   = (float*)alloc(VIN * 4 * 4);
    float* va_d   = (float*)alloc(VIN * 4 * 4);

    hipMemsetAsync(d_ws, 0, zero_bytes, stream);

    int eb = (EP + 255) / 256;                 // 1642
    int nrow = (N + 63) / 64;                  // 313
    int mblk = (N + 63) / 64;                  // 313
    int nblk4 = (N + 3) / 4;                   // 5000
    int prep_blocks = (N * VIN + 255) / 256 + 256 + 256 + eb + 4;
    int sa_blocks = eb + nblk4;

    // ---- prep (cast + packs + histogram + va) ----
    prep_kernel<<<prep_blocks, 256, 0, stream>>>(x, xb, W1, W1p, W2, W2p, ei, deg,
                                                 a_s1, a_d1, va_s, va_d);

    // ---- CSR build + alpha1 ----
    scan_kernel<<<1, 1024, 0, stream>>>(deg, rowptr, N, EP);
    scatter_alpha<<<sa_blocks, 256, 0, stream>>>(ei, rowptr, cursor, esrc, xb, va_s, va_d, as1, ad1);

    // ---- GAT layer 1 (H=4, concat): x-space aggregation then per-head GEMM ----
    attn_aggr_x4<<<nblk4, 256, 0, stream>>>(rowptr, esrc, as1, ad1, xb, xagg);
    gemm_agg<<<dim3(mblk, 4), 256, 0, stream>>>(xagg, W1p, out1b, stats1, N);

    // ---- GAT layer 2 (H=1): BN finalize folded into GEMM2 ----
    gemm2_bn_alpha<<<mblk, 256, 0, stream>>>(out1b, W2p, stats1, gamma1, beta1,
                                             a_s2, a_d2, h2b, as2, ad2, N);
    attn_aggr1<<<nblk4, 256, 0, stream>>>(rowptr, esrc, as2, ad2, h2b, out2);
    bn_stats_f32<<<nrow, 256, 0, stream>>>(out2, b2, stats2, N, 128);
    bn_apply_pool<<<(N * 128 + 255) / 256, 256, 0, stream>>>(out2, b2, stats2, gamma2, beta2, batch, zbuf, N, 128);

    // ---- MLP head ----
    mlp_kernel<<<GG, 320, 0, stream>>>(zbuf, extras, Wm1, bm1, Wm2, bm2, Wm3, bm3, out);
}

// Round 8
// 353.903 us; speedup vs baseline: 4.1763x; 1.0451x over previous
//
#include <hip/hip_runtime.h>
#include <hip/hip_bf16.h>
#include <math.h>

// ---------------- constants (match reference) ----------------
#define NN 20000
#define EE 400000
#define GG 64
#define VIN 128
#define CONVD 128
#define NETD 256
#define NXD 9
#define EPS_BN 1e-5f
#define NEG_SLOPE 0.2f

typedef short short8 __attribute__((ext_vector_type(8)));
typedef float floatx4 __attribute__((ext_vector_type(4)));

__device__ __forceinline__ float leaky(float v) {
    return v >= 0.f ? v : NEG_SLOPE * v;
}
__device__ __forceinline__ unsigned short f2bf(float f) {
    union { float f; unsigned u; } v; v.f = f;
    unsigned r = v.u + 0x7FFFu + ((v.u >> 16) & 1u);   // RNE
    return (unsigned short)(r >> 16);
}
__device__ __forceinline__ float bf2f(unsigned short u) {
    union { unsigned u; float f; } v; v.u = ((unsigned)u) << 16;
    return v.f;
}
__device__ __forceinline__ unsigned packbf2(float a, float b) {
    return (unsigned)f2bf(a) | ((unsigned)f2bf(b) << 16);
}

// ---------------- pack helper: B (f32 [K,Nn]) -> MFMA B-frag layout (bf16) -------
__device__ __forceinline__ void pack_one(const float* __restrict__ B,
                                         unsigned short* __restrict__ Bp,
                                         int K, int Nn, int idx) {
    int j = idx & 7, lane = (idx >> 3) & 63, t = idx >> 9;
    int KT = K >> 5;
    int kt = t % KT, nt = t / KT;
    int k = kt * 32 + (lane >> 4) * 8 + j;
    int n = nt * 16 + (lane & 15);
    Bp[idx] = f2bf(B[(size_t)k * Nn + n]);
}

// ------ prep: cast x->bf16, pack W1, pack W2, dst histogram, va = W1 . a ---------
__global__ void prep_kernel(const float* __restrict__ x, unsigned short* __restrict__ xb,
                            const float* __restrict__ W1, unsigned short* __restrict__ W1p,
                            const float* __restrict__ W2, unsigned short* __restrict__ W2p,
                            const int* __restrict__ ei, int* __restrict__ deg,
                            const float* __restrict__ a_s1, const float* __restrict__ a_d1,
                            float* __restrict__ va_s, float* __restrict__ va_d) {
    const int CB = (NN * VIN + 255) / 256;     // 10000
    const int PB = (VIN * 512) / 256;          // 256
    const int QB = (512 * 128) / 256;          // 256
    const int HB = (EE + NN + 255) / 256;      // 1642
    int b = blockIdx.x;
    if (b < CB) {
        int i = b * 256 + threadIdx.x;
        if (i < NN * VIN) xb[i] = f2bf(x[i]);
    } else if (b < CB + PB) {
        int i = (b - CB) * 256 + threadIdx.x;
        pack_one(W1, W1p, VIN, 512, i);
    } else if (b < CB + PB + QB) {
        int i = (b - CB - PB) * 256 + threadIdx.x;
        pack_one(W2, W2p, 512, 128, i);
    } else if (b < CB + PB + QB + HB) {
        int e = (b - CB - PB - QB) * 256 + threadIdx.x;
        if (e < EE + NN) {
            int d = (e < EE) ? ei[EE + e] : e - EE;
            atomicAdd(&deg[d], 1);
        }
    } else {
        // va: 1024 outputs; i<512 -> va_s[k*4+h], else va_d
        int i = (b - CB - PB - QB - HB) * 256 + threadIdx.x;
        int sd = i >> 9;
        int k = (i & 511) >> 2, h = i & 3;
        const float* a = (sd ? a_d1 : a_s1) + h * CONVD;
        const float* wrow = W1 + (size_t)k * 512 + h * CONVD;
        float acc = 0.f;
        for (int c = 0; c < CONVD; c++) acc = fmaf(wrow[c], a[c], acc);
        (sd ? va_d : va_s)[(k << 2) + h] = acc;
    }
}

// ---------------- single-block exclusive scan (LDS-staged, u16 degrees) ----------
__global__ __launch_bounds__(1024) void scan_kernel(const int* __restrict__ deg,
                                                    int* __restrict__ rowptr,
                                                    int n, int total) {
    __shared__ unsigned short sdeg[NN];
    __shared__ int ssum[1024];
    int t = threadIdx.x;
    for (int i = t; i < n; i += 1024) sdeg[i] = (unsigned short)deg[i];
    __syncthreads();
    const int CH = (NN + 1023) / 1024;   // 20
    int base = t * CH;
    int s = 0;
    for (int i = 0; i < CH; i++) {
        int idx = base + i;
        if (idx < n) s += sdeg[idx];
    }
    ssum[t] = s;
    __syncthreads();
    for (int off = 1; off < 1024; off <<= 1) {
        int v = (t >= off) ? ssum[t - off] : 0;
        __syncthreads();
        ssum[t] += v;
        __syncthreads();
    }
    int pre = ssum[t] - s;
    for (int i = 0; i < CH; i++) {
        int idx = base + i;
        if (idx < n) { rowptr[idx] = pre; pre += sdeg[idx]; }
    }
    if (t == 0) rowptr[n] = total;
}

// -------- scatter edges to CSR slots + alpha1 (as1/ad1 = xb @ va) combo ----------
__global__ __launch_bounds__(256) void scatter_alpha(const int* __restrict__ ei,
                                                     const int* __restrict__ rowptr,
                                                     int* __restrict__ cursor,
                                                     int* __restrict__ esrc,
                                                     const unsigned short* __restrict__ xb,
                                                     const float* __restrict__ va_s,
                                                     const float* __restrict__ va_d,
                                                     float* __restrict__ as1,
                                                     float* __restrict__ ad1) {
    const int E = EE, Np = NN;
    const int SB = (E + Np + 255) / 256;
    int b = blockIdx.x;
    if (b < SB) {
        int e = b * 256 + threadIdx.x;
        if (e >= E + Np) return;
        int s = (e < E) ? ei[e] : e - E;
        int d = (e < E) ? ei[E + e] : e - E;
        int slot = rowptr[d] + atomicAdd(&cursor[d], 1);
        esrc[slot] = s;
        return;
    }
    int lane = threadIdx.x & 63;
    int n = (b - SB) * 4 + (threadIdx.x >> 6);
    if (n >= NN) return;
    unsigned xv = *(const unsigned*)(xb + (size_t)n * VIN + lane * 2);
    float x0 = bf2f((unsigned short)(xv & 0xffffu));
    float x1 = bf2f((unsigned short)(xv >> 16));
    float4 vs0 = *(const float4*)(va_s + (lane * 2) * 4);
    float4 vs1 = *(const float4*)(va_s + (lane * 2 + 1) * 4);
    float4 vd0 = *(const float4*)(va_d + (lane * 2) * 4);
    float4 vd1 = *(const float4*)(va_d + (lane * 2 + 1) * 4);
    float s0 = fmaf(x0, vs0.x, x1 * vs1.x);
    float s1 = fmaf(x0, vs0.y, x1 * vs1.y);
    float s2 = fmaf(x0, vs0.z, x1 * vs1.z);
    float s3 = fmaf(x0, vs0.w, x1 * vs1.w);
    float d0 = fmaf(x0, vd0.x, x1 * vd1.x);
    float d1 = fmaf(x0, vd0.y, x1 * vd1.y);
    float d2 = fmaf(x0, vd0.z, x1 * vd1.z);
    float d3 = fmaf(x0, vd0.w, x1 * vd1.w);
#pragma unroll
    for (int o = 32; o > 0; o >>= 1) {
        s0 += __shfl_xor(s0, o); s1 += __shfl_xor(s1, o);
        s2 += __shfl_xor(s2, o); s3 += __shfl_xor(s3, o);
        d0 += __shfl_xor(d0, o); d1 += __shfl_xor(d1, o);
        d2 += __shfl_xor(d2, o); d3 += __shfl_xor(d3, o);
    }
    if (lane == 0) {
        *(float4*)(as1 + (size_t)n * 4) = make_float4(s0, s1, s2, s3);
        *(float4*)(ad1 + (size_t)n * 4) = make_float4(d0, d1, d2, d3);
    }
}

// -------- fused softmax + x-space aggregation, H=4 (one wave per node) -----------
__global__ __launch_bounds__(256) void attn_aggr_x4(const int* __restrict__ rowptr,
                                                    const int* __restrict__ esrc,
                                                    const float* __restrict__ as4,
                                                    const float* __restrict__ ad4,
                                                    const unsigned short* __restrict__ xb,
                                                    unsigned short* __restrict__ xagg) {
    int lane = threadIdx.x & 63;
    int n = blockIdx.x * 4 + (threadIdx.x >> 6);
    if (n >= NN) return;
    int beg = rowptr[n], end = rowptr[n + 1];
    int deg = end - beg;
    float4 adn = *(const float4*)(ad4 + (size_t)n * 4);
    float m0 = -INFINITY, m1 = -INFINITY, m2 = -INFINITY, m3 = -INFINITY;
    for (int j = beg + lane; j < end; j += 64) {
        float4 av = *(const float4*)(as4 + (size_t)esrc[j] * 4);
        m0 = fmaxf(m0, leaky(av.x + adn.x));
        m1 = fmaxf(m1, leaky(av.y + adn.y));
        m2 = fmaxf(m2, leaky(av.z + adn.z));
        m3 = fmaxf(m3, leaky(av.w + adn.w));
    }
#pragma unroll
    for (int o = 32; o > 0; o >>= 1) {
        m0 = fmaxf(m0, __shfl_xor(m0, o));
        m1 = fmaxf(m1, __shfl_xor(m1, o));
        m2 = fmaxf(m2, __shfl_xor(m2, o));
        m3 = fmaxf(m3, __shfl_xor(m3, o));
    }
    float pk0 = 0.f, pk1 = 0.f, pk2 = 0.f, pk3 = 0.f;
    int sk = 0;
    float s0 = 0.f, s1 = 0.f, s2 = 0.f, s3 = 0.f;
    for (int j = beg + lane; j < end; j += 64) {
        int s = esrc[j];
        float4 av = *(const float4*)(as4 + (size_t)s * 4);
        float e0 = __expf(leaky(av.x + adn.x) - m0);
        float e1 = __expf(leaky(av.y + adn.y) - m1);
        float e2 = __expf(leaky(av.z + adn.z) - m2);
        float e3 = __expf(leaky(av.w + adn.w) - m3);
        if (j - beg < 64) { pk0 = e0; pk1 = e1; pk2 = e2; pk3 = e3; sk = s; }
        s0 += e0; s1 += e1; s2 += e2; s3 += e3;
    }
#pragma unroll
    for (int o = 32; o > 0; o >>= 1) {
        s0 += __shfl_xor(s0, o); s1 += __shfl_xor(s1, o);
        s2 += __shfl_xor(s2, o); s3 += __shfl_xor(s3, o);
    }
    float i0 = 1.f / (s0 + 1e-16f), i1 = 1.f / (s1 + 1e-16f);
    float i2 = 1.f / (s2 + 1e-16f), i3 = 1.f / (s3 + 1e-16f);
    float a00 = 0.f, a01 = 0.f, a10 = 0.f, a11 = 0.f;
    float a20 = 0.f, a21 = 0.f, a30 = 0.f, a31 = 0.f;
    const unsigned short* xrow = xb + lane * 2;
    int cap = deg < 64 ? deg : 64;
    int jj = 0;
    for (; jj + 3 < cap; jj += 4) {
        int sA = __shfl(sk, jj);
        int sB = __shfl(sk, jj + 1);
        int sC = __shfl(sk, jj + 2);
        int sD = __shfl(sk, jj + 3);
        unsigned xvA = *(const unsigned*)(xrow + (size_t)sA * VIN);
        unsigned xvB = *(const unsigned*)(xrow + (size_t)sB * VIN);
        unsigned xvC = *(const unsigned*)(xrow + (size_t)sC * VIN);
        unsigned xvD = *(const unsigned*)(xrow + (size_t)sD * VIN);
        float pA0 = __shfl(pk0, jj),     pA1 = __shfl(pk1, jj);
        float pA2 = __shfl(pk2, jj),     pA3 = __shfl(pk3, jj);
        float pB0 = __shfl(pk0, jj + 1), pB1 = __shfl(pk1, jj + 1);
        float pB2 = __shfl(pk2, jj + 1), pB3 = __shfl(pk3, jj + 1);
        float pC0 = __shfl(pk0, jj + 2), pC1 = __shfl(pk1, jj + 2);
        float pC2 = __shfl(pk2, jj + 2), pC3 = __shfl(pk3, jj + 2);
        float pD0 = __shfl(pk0, jj + 3), pD1 = __shfl(pk1, jj + 3);
        float pD2 = __shfl(pk2, jj + 3), pD3 = __shfl(pk3, jj + 3);
        float xA0 = bf2f((unsigned short)(xvA & 0xffffu)), xA1 = bf2f((unsigned short)(xvA >> 16));
        float xB0 = bf2f((unsigned short)(xvB & 0xffffu)), xB1 = bf2f((unsigned short)(xvB >> 16));
        float xC0 = bf2f((unsigned short)(xvC & 0xffffu)), xC1 = bf2f((unsigned short)(xvC >> 16));
        float xD0 = bf2f((unsigned short)(xvD & 0xffffu)), xD1 = bf2f((unsigned short)(xvD >> 16));
        a00 = fmaf(pA0, xA0, a00); a01 = fmaf(pA0, xA1, a01);
        a10 = fmaf(pA1, xA0, a10); a11 = fmaf(pA1, xA1, a11);
        a20 = fmaf(pA2, xA0, a20); a21 = fmaf(pA2, xA1, a21);
        a30 = fmaf(pA3, xA0, a30); a31 = fmaf(pA3, xA1, a31);
        a00 = fmaf(pB0, xB0, a00); a01 = fmaf(pB0, xB1, a01);
        a10 = fmaf(pB1, xB0, a10); a11 = fmaf(pB1, xB1, a11);
        a20 = fmaf(pB2, xB0, a20); a21 = fmaf(pB2, xB1, a21);
        a30 = fmaf(pB3, xB0, a30); a31 = fmaf(pB3, xB1, a31);
        a00 = fmaf(pC0, xC0, a00); a01 = fmaf(pC0, xC1, a01);
        a10 = fmaf(pC1, xC0, a10); a11 = fmaf(pC1, xC1, a11);
        a20 = fmaf(pC2, xC0, a20); a21 = fmaf(pC2, xC1, a21);
        a30 = fmaf(pC3, xC0, a30); a31 = fmaf(pC3, xC1, a31);
        a00 = fmaf(pD0, xD0, a00); a01 = fmaf(pD0, xD1, a01);
        a10 = fmaf(pD1, xD0, a10); a11 = fmaf(pD1, xD1, a11);
        a20 = fmaf(pD2, xD0, a20); a21 = fmaf(pD2, xD1, a21);
        a30 = fmaf(pD3, xD0, a30); a31 = fmaf(pD3, xD1, a31);
    }
    for (; jj < cap; jj++) {
        int s = __shfl(sk, jj);
        float p0 = __shfl(pk0, jj), p1 = __shfl(pk1, jj);
        float p2 = __shfl(pk2, jj), p3 = __shfl(pk3, jj);
        unsigned xv = *(const unsigned*)(xrow + (size_t)s * VIN);
        float x0 = bf2f((unsigned short)(xv & 0xffffu));
        float x1 = bf2f((unsigned short)(xv >> 16));
        a00 = fmaf(p0, x0, a00); a01 = fmaf(p0, x1, a01);
        a10 = fmaf(p1, x0, a10); a11 = fmaf(p1, x1, a11);
        a20 = fmaf(p2, x0, a20); a21 = fmaf(p2, x1, a21);
        a30 = fmaf(p3, x0, a30); a31 = fmaf(p3, x1, a31);
    }
    for (int j2 = 64; j2 < deg; j2++) {      // rare overflow path
        int s = esrc[beg + j2];
        float4 av = *(const float4*)(as4 + (size_t)s * 4);
        float p0 = __expf(leaky(av.x + adn.x) - m0);
        float p1 = __expf(leaky(av.y + adn.y) - m1);
        float p2 = __expf(leaky(av.z + adn.z) - m2);
        float p3 = __expf(leaky(av.w + adn.w) - m3);
        unsigned xv = *(const unsigned*)(xrow + (size_t)s * VIN);
        float x0 = bf2f((unsigned short)(xv & 0xffffu));
        float x1 = bf2f((unsigned short)(xv >> 16));
        a00 = fmaf(p0, x0, a00); a01 = fmaf(p0, x1, a01);
        a10 = fmaf(p1, x0, a10); a11 = fmaf(p1, x1, a11);
        a20 = fmaf(p2, x0, a20); a21 = fmaf(p2, x1, a21);
        a30 = fmaf(p3, x0, a30); a31 = fmaf(p3, x1, a31);
    }
    unsigned* obase = (unsigned*)(xagg + (size_t)n * 512 + lane * 2);
    obase[0]   = packbf2(a00 * i0, a01 * i0);
    obase[64]  = packbf2(a10 * i1, a11 * i1);
    obase[128] = packbf2(a20 * i2, a21 * i2);
    obase[192] = packbf2(a30 * i3, a31 * i3);
}

// -------- gemm_agg: out1[n, h*128+c'] = xagg[n,h,:] @ W1[:, h*128+c'] ------------
__global__ __launch_bounds__(256) void gemm_agg(const unsigned short* __restrict__ A,
                                                const unsigned short* __restrict__ Bp,
                                                unsigned short* __restrict__ C,
                                                float* __restrict__ stats, int M) {
    constexpr int KT = 4;            // K = 128
    __shared__ float sred[128];
    __shared__ float qred[128];
    if (threadIdx.x < 128) { sred[threadIdx.x] = 0.f; qred[threadIdx.x] = 0.f; }
    __syncthreads();
    int wave = threadIdx.x >> 6, lane = threadIdx.x & 63;
    int hh = blockIdx.y;
    int row0 = (blockIdx.x * 4 + wave) * 16;
    bool act = row0 < M;
    int rowc = act ? row0 : 0;
    int r = lane & 15, quad = lane >> 4;
    short8 af[KT];
    const unsigned short* arow = A + (size_t)(rowc + r) * 512 + hh * CONVD + quad * 8;
#pragma unroll
    for (int kt = 0; kt < KT; kt++) af[kt] = *(const short8*)(arow + kt * 32);
#pragma unroll
    for (int nt = 0; nt < 8; nt++) {
        floatx4 acc = {0.f, 0.f, 0.f, 0.f};
        const unsigned short* bbase = Bp + (((size_t)(hh * 8 + nt) * KT) << 9) + lane * 8;
#pragma unroll
        for (int kt = 0; kt < KT; kt++) {
            short8 bf = *(const short8*)(bbase + ((size_t)kt << 9));
            acc = __builtin_amdgcn_mfma_f32_16x16x32_bf16(af[kt], bf, acc, 0, 0, 0);
        }
        int col = (hh * 8 + nt) * 16 + r;
        unsigned short* cbase = C + (size_t)(rowc + quad * 4) * 512 + col;
        float ls = 0.f, lq = 0.f;
#pragma unroll
        for (int reg = 0; reg < 4; reg++) {
            float v = acc[reg];
            if (act) cbase[(size_t)reg * 512] = f2bf(v);
            ls += v;
            lq = fmaf(v, v, lq);
        }
        if (!act) { ls = 0.f; lq = 0.f; }
        ls += __shfl_xor(ls, 16); ls += __shfl_xor(ls, 32);
        lq += __shfl_xor(lq, 16); lq += __shfl_xor(lq, 32);
        if (quad == 0) {
            atomicAdd(&sred[nt * 16 + r], ls);
            atomicAdd(&qred[nt * 16 + r], lq);
        }
    }
    __syncthreads();
    if (threadIdx.x < 128) {
        int col = hh * CONVD + threadIdx.x;
        atomicAdd(&stats[col], sred[threadIdx.x]);
        atomicAdd(&stats[512 + col], qred[threadIdx.x]);
    }
}

// ---- GEMM2: BN-finalize in LDS + BN on A-load + fused alpha; N split 4-way ------
// grid (mblk, 4): blockIdx.y owns 32 cols (nt = y*2 + {0,1}); alpha partials atomic
__global__ __launch_bounds__(256) void gemm2_bn_alpha(const unsigned short* __restrict__ A,
                                                      const unsigned short* __restrict__ Bp,
                                                      const float* __restrict__ stats,
                                                      const float* __restrict__ gamma,
                                                      const float* __restrict__ beta,
                                                      const float* __restrict__ a_s,
                                                      const float* __restrict__ a_d,
                                                      unsigned short* __restrict__ C,
                                                      float* __restrict__ as_out,
                                                      float* __restrict__ ad_out, int M) {
    constexpr int K = 512;
    constexpr int Nn = CONVD;         // 128
    constexpr int KT = K / 32;        // 16
    __shared__ float Ssm[512];
    __shared__ float Tsm[512];
    for (int c = threadIdx.x; c < 512; c += 256) {
        float inv_n = 1.f / (float)NN;
        float mu = stats[c] * inv_n;
        float var = stats[512 + c] * inv_n - mu * mu;
        float s = gamma[c] * rsqrtf(var + EPS_BN);
        Ssm[c] = s;
        Tsm[c] = fmaf(-mu, s, beta[c]);
    }
    __syncthreads();
    int wave = threadIdx.x >> 6, lane = threadIdx.x & 63;
    int row0 = (blockIdx.x * 4 + wave) * 16;
    if (row0 >= M) return;
    int r = lane & 15, quad = lane >> 4;
    int nt0 = blockIdx.y * 2;
    short8 af[KT];
    const unsigned short* arow = A + (size_t)(row0 + r) * K + quad * 8;
#pragma unroll
    for (int kt = 0; kt < KT; kt++) {
        short8 raw = *(const short8*)(arow + kt * 32);
        int k = kt * 32 + quad * 8;
        short8 o;
#pragma unroll
        for (int i = 0; i < 8; i++) {
            float v = fmaf(bf2f((unsigned short)raw[i]), Ssm[k + i], Tsm[k + i]);
            o[i] = (short)f2bf(v > 0.f ? v : 0.f);
        }
        af[kt] = o;
    }
    float asp[4] = {}, adp[4] = {};
#pragma unroll
    for (int nt2 = 0; nt2 < 2; nt2++) {
        int nt = nt0 + nt2;
        floatx4 acc = {0.f, 0.f, 0.f, 0.f};
        const unsigned short* bbase = Bp + (((size_t)nt * KT) << 9) + lane * 8;
#pragma unroll
        for (int kt = 0; kt < KT; kt++) {
            short8 bf = *(const short8*)(bbase + ((size_t)kt << 9));
            acc = __builtin_amdgcn_mfma_f32_16x16x32_bf16(af[kt], bf, acc, 0, 0, 0);
        }
        int col = nt * 16 + r;
        unsigned short* cbase = C + (size_t)(row0 + quad * 4) * Nn + col;
        float sv = a_s[col];
        float dv = a_d[col];
#pragma unroll
        for (int reg = 0; reg < 4; reg++) {
            cbase[(size_t)reg * Nn] = f2bf(acc[reg]);
            asp[reg] = fmaf(acc[reg], sv, asp[reg]);
            adp[reg] = fmaf(acc[reg], dv, adp[reg]);
        }
    }
#pragma unroll
    for (int msk = 1; msk < 16; msk <<= 1) {
#pragma unroll
        for (int reg = 0; reg < 4; reg++) {
            asp[reg] += __shfl_xor(asp[reg], msk);
            adp[reg] += __shfl_xor(adp[reg], msk);
        }
    }
    if (r < 4) {
        int row = row0 + quad * 4 + r;
        atomicAdd(&as_out[row], asp[r]);
        atomicAdd(&ad_out[row], adp[r]);
    }
}

// -------- fused softmax + aggregation, H=1 (one wave per node), pipelined --------
__global__ __launch_bounds__(256) void attn_aggr1(const int* __restrict__ rowptr,
                                                  const int* __restrict__ esrc,
                                                  const float* __restrict__ as,
                                                  const float* __restrict__ ad,
                                                  const unsigned short* __restrict__ h,
                                                  float* __restrict__ out) {
    int lane = threadIdx.x & 63;
    int n = blockIdx.x * 4 + (threadIdx.x >> 6);
    if (n >= NN) return;
    int beg = rowptr[n], end = rowptr[n + 1];
    int deg = end - beg;
    float adn = ad[n];
    float m = -INFINITY;
    for (int j = beg + lane; j < end; j += 64)
        m = fmaxf(m, leaky(as[esrc[j]] + adn));
#pragma unroll
    for (int o = 32; o > 0; o >>= 1) m = fmaxf(m, __shfl_xor(m, o));
    float pk = 0.f;
    int sk = 0;
    float sum = 0.f;
    for (int j = beg + lane; j < end; j += 64) {
        int s = esrc[j];
        float e = __expf(leaky(as[s] + adn) - m);
        if (j - beg < 64) { pk = e; sk = s; }
        sum += e;
    }
#pragma unroll
    for (int o = 32; o > 0; o >>= 1) sum += __shfl_xor(sum, o);
    float inv = 1.f / (sum + 1e-16f);
    float a0 = 0.f, a1 = 0.f, b0 = 0.f, b1 = 0.f;
    const unsigned short* hrow = h + lane * 2;
    int cap = deg < 64 ? deg : 64;
    int jj = 0;
    for (; jj + 3 < cap; jj += 4) {
        int sA = __shfl(sk, jj);
        int sB = __shfl(sk, jj + 1);
        int sC = __shfl(sk, jj + 2);
        int sD = __shfl(sk, jj + 3);
        unsigned xvA = *(const unsigned*)(hrow + (size_t)sA * CONVD);
        unsigned xvB = *(const unsigned*)(hrow + (size_t)sB * CONVD);
        unsigned xvC = *(const unsigned*)(hrow + (size_t)sC * CONVD);
        unsigned xvD = *(const unsigned*)(hrow + (size_t)sD * CONVD);
        float pA = __shfl(pk, jj),     pB = __shfl(pk, jj + 1);
        float pC = __shfl(pk, jj + 2), pD = __shfl(pk, jj + 3);
        a0 = fmaf(pA, bf2f((unsigned short)(xvA & 0xffffu)), a0);
        a1 = fmaf(pA, bf2f((unsigned short)(xvA >> 16)), a1);
        b0 = fmaf(pB, bf2f((unsigned short)(xvB & 0xffffu)), b0);
        b1 = fmaf(pB, bf2f((unsigned short)(xvB >> 16)), b1);
        a0 = fmaf(pC, bf2f((unsigned short)(xvC & 0xffffu)), a0);
        a1 = fmaf(pC, bf2f((unsigned short)(xvC >> 16)), a1);
        b0 = fmaf(pD, bf2f((unsigned short)(xvD & 0xffffu)), b0);
        b1 = fmaf(pD, bf2f((unsigned short)(xvD >> 16)), b1);
    }
    for (; jj < cap; jj++) {
        int s = __shfl(sk, jj);
        float p = __shfl(pk, jj);
        unsigned xv = *(const unsigned*)(hrow + (size_t)s * CONVD);
        a0 = fmaf(p, bf2f((unsigned short)(xv & 0xffffu)), a0);
        a1 = fmaf(p, bf2f((unsigned short)(xv >> 16)), a1);
    }
    for (int j2 = 64; j2 < deg; j2++) {
        int s = esrc[beg + j2];
        float p = __expf(leaky(as[s] + adn) - m);
        unsigned xv = *(const unsigned*)(hrow + (size_t)s * CONVD);
        a0 = fmaf(p, bf2f((unsigned short)(xv & 0xffffu)), a0);
        a1 = fmaf(p, bf2f((unsigned short)(xv >> 16)), a1);
    }
    a0 += b0; a1 += b1;
    *(float2*)(out + (size_t)n * CONVD + lane * 2) = make_float2(a0 * inv, a1 * inv);
}

// ---------------- BN stats (f32 input) ----------------
__global__ void bn_stats_f32(const float* __restrict__ x, const float* __restrict__ bias,
                             float* __restrict__ stats, int Nn, int C) {
    const int ROWS = 64;
    int r0 = blockIdx.x * ROWS;
    int rend = min(r0 + ROWS, Nn);
    for (int c = threadIdx.x; c < C; c += blockDim.x) {
        float b = bias[c];
        float s1 = 0.f, s2 = 0.f;
        for (int r = r0; r < rend; r++) {
            float v = x[(size_t)r * C + c] + b;
            s1 += v;
            s2 = fmaf(v, v, s2);
        }
        atomicAdd(&stats[c], s1);
        atomicAdd(&stats[C + c], s2);
    }
}

// ---------------- BN apply + ReLU + pool (layer 2, fused) ------------------------
__global__ void bn_apply_pool(const float* __restrict__ x, const float* __restrict__ bias,
                              const float* __restrict__ stats,
                              const float* __restrict__ gamma, const float* __restrict__ beta,
                              const int* __restrict__ batch, float* __restrict__ z,
                              int Nn, int C) {
    int idx = blockIdx.x * blockDim.x + threadIdx.x;
    if (idx >= Nn * C) return;
    int c = idx % C;
    int n = idx / C;
    float inv_n = 1.f / (float)Nn;
    float mu = stats[c] * inv_n;
    float var = stats[C + c] * inv_n - mu * mu;
    float v = (x[idx] + bias[c] - mu) * rsqrtf(var + EPS_BN);
    v = fmaf(gamma[c], v, beta[c]);
    v = v > 0.f ? v : 0.f;
    atomicAdd(&z[batch[n] * C + c], v);
}

// ---------------- fused MLP head: one block per graph ----------------
__global__ __launch_bounds__(320) void mlp_kernel(const float* __restrict__ g,
                           const float* __restrict__ extras,
                           const float* __restrict__ Wm1, const float* __restrict__ bm1,
                           const float* __restrict__ Wm2, const float* __restrict__ bm2,
                           const float* __restrict__ Wm3, const float* __restrict__ bm3,
                           float* __restrict__ out) {
    const int Z0 = CONVD + NXD;   // 137
    const int Z1 = NETD + NXD;    // 265
    const int Z2 = NETD;          // 256
    __shared__ float z[Z0];
    __shared__ float z1[Z1];
    __shared__ float z2[Z2];
    __shared__ float wred[5];
    int gi = blockIdx.x, t = threadIdx.x;
    if (t < CONVD) z[t] = g[gi * CONVD + t];
    else if (t < Z0) z[t] = extras[gi * NXD + (t - CONVD)];
    __syncthreads();
    if (t < Z1) {
        float acc = bm1[t];
        for (int k = 0; k < Z0; k++) acc = fmaf(z[k], Wm1[k * Z1 + t], acc);
        z1[t] = acc > 0.f ? acc : 0.f;
    }
    __syncthreads();
    if (t < Z2) {
        float acc = bm2[t];
        for (int k = 0; k < Z1; k++) acc = fmaf(z1[k], Wm2[k * Z2 + t], acc);
        z2[t] = acc > 0.f ? acc : 0.f;
    }
    __syncthreads();
    float partial = (t < Z2) ? z2[t] * Wm3[t] : 0.f;
    for (int o = 32; o > 0; o >>= 1) partial += __shfl_down(partial, o);
    int wv = t >> 6, ln = t & 63;
    if (ln == 0) wred[wv] = partial;
    __syncthreads();
    if (t == 0) {
        float s = bm3[0];
        for (int i = 0; i < 5; i++) s += wred[i];
        out[gi] = s;
    }
}

// ---------------- launch ----------------
extern "C" void kernel_launch(void* const* d_in, const int* in_sizes, int n_in,
                              void* d_out, int out_size, void* d_ws, size_t ws_size,
                              hipStream_t stream) {
    const float* x      = (const float*)d_in[0];
    const int*   ei     = (const int*)d_in[1];
    const int*   batch  = (const int*)d_in[2];
    const float* extras = (const float*)d_in[3];
    const float* W1     = (const float*)d_in[4];
    const float* a_s1   = (const float*)d_in[5];
    const float* a_d1   = (const float*)d_in[6];
    const float* b1     = (const float*)d_in[7];
    const float* W2     = (const float*)d_in[8];
    const float* a_s2   = (const float*)d_in[9];
    const float* a_d2   = (const float*)d_in[10];
    const float* b2     = (const float*)d_in[11];
    const float* gamma1 = (const float*)d_in[12];
    const float* beta1  = (const float*)d_in[13];
    const float* gamma2 = (const float*)d_in[14];
    const float* beta2  = (const float*)d_in[15];
    const float* Wm1    = (const float*)d_in[16];
    const float* bm1    = (const float*)d_in[17];
    const float* Wm2    = (const float*)d_in[18];
    const float* bm2    = (const float*)d_in[19];
    const float* Wm3    = (const float*)d_in[20];
    const float* bm3    = (const float*)d_in[21];
    float* out = (float*)d_out;

    const int N = NN, E = EE, EP = EE + NN;

    char* ws = (char*)d_ws;
    size_t off = 0;
    auto alloc = [&](size_t bytes) -> void* {
        void* pp = (void*)(ws + off);
        off += (bytes + 255) & ~(size_t)255;
        return pp;
    };
    // --- zero region (contiguous; one small memset) ---
    int*   deg    = (int*)alloc((size_t)N * 4);
    int*   cursor = (int*)alloc((size_t)N * 4);
    float* stats1 = (float*)alloc(512 * 2 * 4);
    float* stats2 = (float*)alloc(128 * 2 * 4);
    float* zbuf   = (float*)alloc((size_t)GG * CONVD * 4);
    float* as2    = (float*)alloc((size_t)N * 4);      // atomic-accumulated in gemm2
    float* ad2    = (float*)alloc((size_t)N * 4);
    size_t zero_bytes = off;
    // --- scratch (fully overwritten each launch) ---
    int*   rowptr = (int*)alloc((size_t)(N + 1) * 4);
    int*   esrc   = (int*)alloc((size_t)EP * 4);
    unsigned short* xb    = (unsigned short*)alloc((size_t)N * VIN * 2);
    unsigned short* W1p   = (unsigned short*)alloc((size_t)VIN * 512 * 2);
    unsigned short* W2p   = (unsigned short*)alloc((size_t)512 * 128 * 2);
    unsigned short* xagg  = (unsigned short*)alloc((size_t)N * 512 * 2);
    unsigned short* out1b = (unsigned short*)alloc((size_t)N * 512 * 2);
    unsigned short* h2b   = (unsigned short*)alloc((size_t)N * 128 * 2);
    float* out2   = (float*)alloc((size_t)N * 128 * 4);
    float* as1    = (float*)alloc((size_t)N * 4 * 4);
    float* ad1    = (float*)alloc((size_t)N * 4 * 4);
    float* va_s   = (float*)alloc(VIN * 4 * 4);
    float* va_d   = (float*)alloc(VIN * 4 * 4);

    hipMemsetAsync(d_ws, 0, zero_bytes, stream);

    int eb = (EP + 255) / 256;                 // 1642
    int nrow = (N + 63) / 64;                  // 313
    int mblk = (N + 63) / 64;                  // 313
    int nblk4 = (N + 3) / 4;                   // 5000
    int prep_blocks = (N * VIN + 255) / 256 + 256 + 256 + eb + 4;
    int sa_blocks = eb + nblk4;

    // ---- prep (cast + packs + histogram + va) ----
    prep_kernel<<<prep_blocks, 256, 0, stream>>>(x, xb, W1, W1p, W2, W2p, ei, deg,
                                                 a_s1, a_d1, va_s, va_d);

    // ---- CSR build + alpha1 ----
    scan_kernel<<<1, 1024, 0, stream>>>(deg, rowptr, N, EP);
    scatter_alpha<<<sa_blocks, 256, 0, stream>>>(ei, rowptr, cursor, esrc, xb, va_s, va_d, as1, ad1);

    // ---- GAT layer 1 (H=4, concat): x-space aggregation then per-head GEMM ----
    attn_aggr_x4<<<nblk4, 256, 0, stream>>>(rowptr, esrc, as1, ad1, xb, xagg);
    gemm_agg<<<dim3(mblk, 4), 256, 0, stream>>>(xagg, W1p, out1b, stats1, N);

    // ---- GAT layer 2 (H=1): BN finalize folded into GEMM2; N split 4-way ----
    gemm2_bn_alpha<<<dim3(mblk, 4), 256, 0, stream>>>(out1b, W2p, stats1, gamma1, beta1,
                                                      a_s2, a_d2, h2b, as2, ad2, N);
    attn_aggr1<<<nblk4, 256, 0, stream>>>(rowptr, esrc, as2, ad2, h2b, out2);
    bn_stats_f32<<<nrow, 256, 0, stream>>>(out2, b2, stats2, N, 128);
    bn_apply_pool<<<(N * 128 + 255) / 256, 256, 0, stream>>>(out2, b2, stats2, gamma2, beta2, batch, zbuf, N, 128);

    // ---- MLP head ----
    mlp_kernel<<<GG, 320, 0, stream>>>(zbuf, extras, Wm1, bm1, Wm2, bm2, Wm3, bm3, out);
}

// Round 9
// 344.337 us; speedup vs baseline: 4.2923x; 1.0278x over previous
//
#include <hip/hip_runtime.h>
#include <hip/hip_bf16.h>
#include <math.h>

// ---------------- constants (match reference) ----------------
#define NN 20000
#define EE 400000
#define GG 64
#define VIN 128
#define CONVD 128
#define NETD 256
#define NXD 9
#define EPS_BN 1e-5f
#define NEG_SLOPE 0.2f

typedef short short8 __attribute__((ext_vector_type(8)));
typedef float floatx4 __attribute__((ext_vector_type(4)));

__device__ __forceinline__ float leaky(float v) {
    return v >= 0.f ? v : NEG_SLOPE * v;
}
__device__ __forceinline__ unsigned short f2bf(float f) {
    union { float f; unsigned u; } v; v.f = f;
    unsigned r = v.u + 0x7FFFu + ((v.u >> 16) & 1u);   // RNE
    return (unsigned short)(r >> 16);
}
__device__ __forceinline__ float bf2f(unsigned short u) {
    union { unsigned u; float f; } v; v.u = ((unsigned)u) << 16;
    return v.f;
}
__device__ __forceinline__ unsigned packbf2(float a, float b) {
    return (unsigned)f2bf(a) | ((unsigned)f2bf(b) << 16);
}

// ---------------- pack helper: B (f32 [K,Nn]) -> MFMA B-frag layout (bf16) -------
__device__ __forceinline__ void pack_one(const float* __restrict__ B,
                                         unsigned short* __restrict__ Bp,
                                         int K, int Nn, int idx) {
    int j = idx & 7, lane = (idx >> 3) & 63, t = idx >> 9;
    int KT = K >> 5;
    int kt = t % KT, nt = t / KT;
    int k = kt * 32 + (lane >> 4) * 8 + j;
    int n = nt * 16 + (lane & 15);
    Bp[idx] = f2bf(B[(size_t)k * Nn + n]);
}

// ------ prep: cast x->bf16, pack W1, pack W2, dst histogram, va = W1 . a ---------
__global__ void prep_kernel(const float* __restrict__ x, unsigned short* __restrict__ xb,
                            const float* __restrict__ W1, unsigned short* __restrict__ W1p,
                            const float* __restrict__ W2, unsigned short* __restrict__ W2p,
                            const int* __restrict__ ei, int* __restrict__ deg,
                            const float* __restrict__ a_s1, const float* __restrict__ a_d1,
                            float* __restrict__ va_s, float* __restrict__ va_d) {
    const int CB = (NN * VIN + 255) / 256;     // 10000
    const int PB = (VIN * 512) / 256;          // 256
    const int QB = (512 * 128) / 256;          // 256
    const int HB = (EE + NN + 255) / 256;      // 1642
    int b = blockIdx.x;
    if (b < CB) {
        int i = b * 256 + threadIdx.x;
        if (i < NN * VIN) xb[i] = f2bf(x[i]);
    } else if (b < CB + PB) {
        int i = (b - CB) * 256 + threadIdx.x;
        pack_one(W1, W1p, VIN, 512, i);
    } else if (b < CB + PB + QB) {
        int i = (b - CB - PB) * 256 + threadIdx.x;
        pack_one(W2, W2p, 512, 128, i);
    } else if (b < CB + PB + QB + HB) {
        int e = (b - CB - PB - QB) * 256 + threadIdx.x;
        if (e < EE + NN) {
            int d = (e < EE) ? ei[EE + e] : e - EE;
            atomicAdd(&deg[d], 1);
        }
    } else {
        // va: 1024 outputs; i<512 -> va_s[k*4+h], else va_d
        int i = (b - CB - PB - QB - HB) * 256 + threadIdx.x;
        int sd = i >> 9;
        int k = (i & 511) >> 2, h = i & 3;
        const float* a = (sd ? a_d1 : a_s1) + h * CONVD;
        const float* wrow = W1 + (size_t)k * 512 + h * CONVD;
        float acc = 0.f;
        for (int c = 0; c < CONVD; c++) acc = fmaf(wrow[c], a[c], acc);
        (sd ? va_d : va_s)[(k << 2) + h] = acc;
    }
}

// ---------------- single-block exclusive scan (LDS-staged, u16 degrees) ----------
__global__ __launch_bounds__(1024) void scan_kernel(const int* __restrict__ deg,
                                                    int* __restrict__ rowptr,
                                                    int n, int total) {
    __shared__ unsigned short sdeg[NN];
    __shared__ int ssum[1024];
    int t = threadIdx.x;
    for (int i = t; i < n; i += 1024) sdeg[i] = (unsigned short)deg[i];
    __syncthreads();
    const int CH = (NN + 1023) / 1024;   // 20
    int base = t * CH;
    int s = 0;
    for (int i = 0; i < CH; i++) {
        int idx = base + i;
        if (idx < n) s += sdeg[idx];
    }
    ssum[t] = s;
    __syncthreads();
    for (int off = 1; off < 1024; off <<= 1) {
        int v = (t >= off) ? ssum[t - off] : 0;
        __syncthreads();
        ssum[t] += v;
        __syncthreads();
    }
    int pre = ssum[t] - s;
    for (int i = 0; i < CH; i++) {
        int idx = base + i;
        if (idx < n) { rowptr[idx] = pre; pre += sdeg[idx]; }
    }
    if (t == 0) rowptr[n] = total;
}

// -------- scatter edges to CSR slots + alpha1 (as1/ad1 = xb @ va) combo ----------
__global__ __launch_bounds__(256) void scatter_alpha(const int* __restrict__ ei,
                                                     const int* __restrict__ rowptr,
                                                     int* __restrict__ cursor,
                                                     int* __restrict__ esrc,
                                                     const unsigned short* __restrict__ xb,
                                                     const float* __restrict__ va_s,
                                                     const float* __restrict__ va_d,
                                                     float* __restrict__ as1,
                                                     float* __restrict__ ad1) {
    const int E = EE, Np = NN;
    const int SB = (E + Np + 255) / 256;
    int b = blockIdx.x;
    if (b < SB) {
        int e = b * 256 + threadIdx.x;
        if (e >= E + Np) return;
        int s = (e < E) ? ei[e] : e - E;
        int d = (e < E) ? ei[E + e] : e - E;
        int slot = rowptr[d] + atomicAdd(&cursor[d], 1);
        esrc[slot] = s;
        return;
    }
    int lane = threadIdx.x & 63;
    int n = (b - SB) * 4 + (threadIdx.x >> 6);
    if (n >= NN) return;
    unsigned xv = *(const unsigned*)(xb + (size_t)n * VIN + lane * 2);
    float x0 = bf2f((unsigned short)(xv & 0xffffu));
    float x1 = bf2f((unsigned short)(xv >> 16));
    float4 vs0 = *(const float4*)(va_s + (lane * 2) * 4);
    float4 vs1 = *(const float4*)(va_s + (lane * 2 + 1) * 4);
    float4 vd0 = *(const float4*)(va_d + (lane * 2) * 4);
    float4 vd1 = *(const float4*)(va_d + (lane * 2 + 1) * 4);
    float s0 = fmaf(x0, vs0.x, x1 * vs1.x);
    float s1 = fmaf(x0, vs0.y, x1 * vs1.y);
    float s2 = fmaf(x0, vs0.z, x1 * vs1.z);
    float s3 = fmaf(x0, vs0.w, x1 * vs1.w);
    float d0 = fmaf(x0, vd0.x, x1 * vd1.x);
    float d1 = fmaf(x0, vd0.y, x1 * vd1.y);
    float d2 = fmaf(x0, vd0.z, x1 * vd1.z);
    float d3 = fmaf(x0, vd0.w, x1 * vd1.w);
#pragma unroll
    for (int o = 32; o > 0; o >>= 1) {
        s0 += __shfl_xor(s0, o); s1 += __shfl_xor(s1, o);
        s2 += __shfl_xor(s2, o); s3 += __shfl_xor(s3, o);
        d0 += __shfl_xor(d0, o); d1 += __shfl_xor(d1, o);
        d2 += __shfl_xor(d2, o); d3 += __shfl_xor(d3, o);
    }
    if (lane == 0) {
        *(float4*)(as1 + (size_t)n * 4) = make_float4(s0, s1, s2, s3);
        *(float4*)(ad1 + (size_t)n * 4) = make_float4(d0, d1, d2, d3);
    }
}

// -------- fused softmax + x-space aggregation, H=4 (one wave per node) -----------
// deg<=64 fast path: single-pass softmax (lane j owns edge j), p/src stashed in
// LDS; phase C 8-wide pipelined (8 gathers in flight)
__global__ __launch_bounds__(256) void attn_aggr_x4(const int* __restrict__ rowptr,
                                                    const int* __restrict__ esrc,
                                                    const float* __restrict__ as4,
                                                    const float* __restrict__ ad4,
                                                    const unsigned short* __restrict__ xb,
                                                    unsigned short* __restrict__ xagg) {
    __shared__ float4 sp[4][64];
    __shared__ int ssrc[4][64];
    int lane = threadIdx.x & 63;
    int wv = threadIdx.x >> 6;
    int n = blockIdx.x * 4 + wv;          // grid exactly NN/4 blocks
    int beg = rowptr[n], end = rowptr[n + 1];
    int deg = end - beg;
    float4 adn = *(const float4*)(ad4 + (size_t)n * 4);
    float m0, m1, m2, m3, s0, s1, s2, s3;
    if (deg <= 64) {
        bool valid = lane < deg;
        int s = esrc[beg + (valid ? lane : 0)];
        float4 av = *(const float4*)(as4 + (size_t)s * 4);
        float l0 = valid ? leaky(av.x + adn.x) : -INFINITY;
        float l1 = valid ? leaky(av.y + adn.y) : -INFINITY;
        float l2 = valid ? leaky(av.z + adn.z) : -INFINITY;
        float l3 = valid ? leaky(av.w + adn.w) : -INFINITY;
        m0 = l0; m1 = l1; m2 = l2; m3 = l3;
#pragma unroll
        for (int o = 32; o > 0; o >>= 1) {
            m0 = fmaxf(m0, __shfl_xor(m0, o));
            m1 = fmaxf(m1, __shfl_xor(m1, o));
            m2 = fmaxf(m2, __shfl_xor(m2, o));
            m3 = fmaxf(m3, __shfl_xor(m3, o));
        }
        float e0 = valid ? __expf(l0 - m0) : 0.f;
        float e1 = valid ? __expf(l1 - m1) : 0.f;
        float e2 = valid ? __expf(l2 - m2) : 0.f;
        float e3 = valid ? __expf(l3 - m3) : 0.f;
        s0 = e0; s1 = e1; s2 = e2; s3 = e3;
#pragma unroll
        for (int o = 32; o > 0; o >>= 1) {
            s0 += __shfl_xor(s0, o); s1 += __shfl_xor(s1, o);
            s2 += __shfl_xor(s2, o); s3 += __shfl_xor(s3, o);
        }
        sp[wv][lane] = make_float4(e0, e1, e2, e3);
        ssrc[wv][lane] = s;
    } else {
        // rare overflow path: classic two-pass; stash first-64 p in LDS
        m0 = -INFINITY; m1 = -INFINITY; m2 = -INFINITY; m3 = -INFINITY;
        for (int j = beg + lane; j < end; j += 64) {
            float4 av = *(const float4*)(as4 + (size_t)esrc[j] * 4);
            m0 = fmaxf(m0, leaky(av.x + adn.x));
            m1 = fmaxf(m1, leaky(av.y + adn.y));
            m2 = fmaxf(m2, leaky(av.z + adn.z));
            m3 = fmaxf(m3, leaky(av.w + adn.w));
        }
#pragma unroll
        for (int o = 32; o > 0; o >>= 1) {
            m0 = fmaxf(m0, __shfl_xor(m0, o));
            m1 = fmaxf(m1, __shfl_xor(m1, o));
            m2 = fmaxf(m2, __shfl_xor(m2, o));
            m3 = fmaxf(m3, __shfl_xor(m3, o));
        }
        s0 = 0.f; s1 = 0.f; s2 = 0.f; s3 = 0.f;
        for (int j = beg + lane; j < end; j += 64) {
            int s = esrc[j];
            float4 av = *(const float4*)(as4 + (size_t)s * 4);
            float e0 = __expf(leaky(av.x + adn.x) - m0);
            float e1 = __expf(leaky(av.y + adn.y) - m1);
            float e2 = __expf(leaky(av.z + adn.z) - m2);
            float e3 = __expf(leaky(av.w + adn.w) - m3);
            if (j - beg < 64) {
                sp[wv][lane] = make_float4(e0, e1, e2, e3);
                ssrc[wv][lane] = s;
            }
            s0 += e0; s1 += e1; s2 += e2; s3 += e3;
        }
#pragma unroll
        for (int o = 32; o > 0; o >>= 1) {
            s0 += __shfl_xor(s0, o); s1 += __shfl_xor(s1, o);
            s2 += __shfl_xor(s2, o); s3 += __shfl_xor(s3, o);
        }
    }
    __syncthreads();
    float i0 = 1.f / (s0 + 1e-16f), i1 = 1.f / (s1 + 1e-16f);
    float i2 = 1.f / (s2 + 1e-16f), i3 = 1.f / (s3 + 1e-16f);
    // phase C: 8-wide pipelined edge walk (p/src broadcast-read from LDS)
    float a00 = 0.f, a01 = 0.f, a10 = 0.f, a11 = 0.f;
    float a20 = 0.f, a21 = 0.f, a30 = 0.f, a31 = 0.f;
    const unsigned short* xrow = xb + lane * 2;
    int cap = deg < 64 ? deg : 64;
    int jj = 0;
    for (; jj + 7 < cap; jj += 8) {
        int sv[8];
#pragma unroll
        for (int u = 0; u < 8; u++) sv[u] = ssrc[wv][jj + u];
        unsigned xv[8];
#pragma unroll
        for (int u = 0; u < 8; u++) xv[u] = *(const unsigned*)(xrow + (size_t)sv[u] * VIN);
        float4 pv[8];
#pragma unroll
        for (int u = 0; u < 8; u++) pv[u] = sp[wv][jj + u];
#pragma unroll
        for (int u = 0; u < 8; u++) {
            float x0 = bf2f((unsigned short)(xv[u] & 0xffffu));
            float x1 = bf2f((unsigned short)(xv[u] >> 16));
            a00 = fmaf(pv[u].x, x0, a00); a01 = fmaf(pv[u].x, x1, a01);
            a10 = fmaf(pv[u].y, x0, a10); a11 = fmaf(pv[u].y, x1, a11);
            a20 = fmaf(pv[u].z, x0, a20); a21 = fmaf(pv[u].z, x1, a21);
            a30 = fmaf(pv[u].w, x0, a30); a31 = fmaf(pv[u].w, x1, a31);
        }
    }
    for (; jj < cap; jj++) {
        int s = ssrc[wv][jj];
        float4 p = sp[wv][jj];
        unsigned xv = *(const unsigned*)(xrow + (size_t)s * VIN);
        float x0 = bf2f((unsigned short)(xv & 0xffffu));
        float x1 = bf2f((unsigned short)(xv >> 16));
        a00 = fmaf(p.x, x0, a00); a01 = fmaf(p.x, x1, a01);
        a10 = fmaf(p.y, x0, a10); a11 = fmaf(p.y, x1, a11);
        a20 = fmaf(p.z, x0, a20); a21 = fmaf(p.z, x1, a21);
        a30 = fmaf(p.w, x0, a30); a31 = fmaf(p.w, x1, a31);
    }
    for (int j2 = 64; j2 < deg; j2++) {      // rare overflow tail
        int s = esrc[beg + j2];
        float4 av = *(const float4*)(as4 + (size_t)s * 4);
        float p0 = __expf(leaky(av.x + adn.x) - m0);
        float p1 = __expf(leaky(av.y + adn.y) - m1);
        float p2 = __expf(leaky(av.z + adn.z) - m2);
        float p3 = __expf(leaky(av.w + adn.w) - m3);
        unsigned xv = *(const unsigned*)(xrow + (size_t)s * VIN);
        float x0 = bf2f((unsigned short)(xv & 0xffffu));
        float x1 = bf2f((unsigned short)(xv >> 16));
        a00 = fmaf(p0, x0, a00); a01 = fmaf(p0, x1, a01);
        a10 = fmaf(p1, x0, a10); a11 = fmaf(p1, x1, a11);
        a20 = fmaf(p2, x0, a20); a21 = fmaf(p2, x1, a21);
        a30 = fmaf(p3, x0, a30); a31 = fmaf(p3, x1, a31);
    }
    unsigned* obase = (unsigned*)(xagg + (size_t)n * 512 + lane * 2);
    obase[0]   = packbf2(a00 * i0, a01 * i0);
    obase[64]  = packbf2(a10 * i1, a11 * i1);
    obase[128] = packbf2(a20 * i2, a21 * i2);
    obase[192] = packbf2(a30 * i3, a31 * i3);
}

// -------- gemm_agg: out1[n, h*128+c'] = xagg[n,h,:] @ W1[:, h*128+c'] ------------
__global__ __launch_bounds__(256) void gemm_agg(const unsigned short* __restrict__ A,
                                                const unsigned short* __restrict__ Bp,
                                                unsigned short* __restrict__ C,
                                                float* __restrict__ stats, int M) {
    constexpr int KT = 4;            // K = 128
    __shared__ float sred[128];
    __shared__ float qred[128];
    if (threadIdx.x < 128) { sred[threadIdx.x] = 0.f; qred[threadIdx.x] = 0.f; }
    __syncthreads();
    int wave = threadIdx.x >> 6, lane = threadIdx.x & 63;
    int hh = blockIdx.y;
    int row0 = (blockIdx.x * 4 + wave) * 16;
    bool act = row0 < M;
    int rowc = act ? row0 : 0;
    int r = lane & 15, quad = lane >> 4;
    short8 af[KT];
    const unsigned short* arow = A + (size_t)(rowc + r) * 512 + hh * CONVD + quad * 8;
#pragma unroll
    for (int kt = 0; kt < KT; kt++) af[kt] = *(const short8*)(arow + kt * 32);
#pragma unroll
    for (int nt = 0; nt < 8; nt++) {
        floatx4 acc = {0.f, 0.f, 0.f, 0.f};
        const unsigned short* bbase = Bp + (((size_t)(hh * 8 + nt) * KT) << 9) + lane * 8;
#pragma unroll
        for (int kt = 0; kt < KT; kt++) {
            short8 bf = *(const short8*)(bbase + ((size_t)kt << 9));
            acc = __builtin_amdgcn_mfma_f32_16x16x32_bf16(af[kt], bf, acc, 0, 0, 0);
        }
        int col = (hh * 8 + nt) * 16 + r;
        unsigned short* cbase = C + (size_t)(rowc + quad * 4) * 512 + col;
        float ls = 0.f, lq = 0.f;
#pragma unroll
        for (int reg = 0; reg < 4; reg++) {
            float v = acc[reg];
            if (act) cbase[(size_t)reg * 512] = f2bf(v);
            ls += v;
            lq = fmaf(v, v, lq);
        }
        if (!act) { ls = 0.f; lq = 0.f; }
        ls += __shfl_xor(ls, 16); ls += __shfl_xor(ls, 32);
        lq += __shfl_xor(lq, 16); lq += __shfl_xor(lq, 32);
        if (quad == 0) {
            atomicAdd(&sred[nt * 16 + r], ls);
            atomicAdd(&qred[nt * 16 + r], lq);
        }
    }
    __syncthreads();
    if (threadIdx.x < 128) {
        int col = hh * CONVD + threadIdx.x;
        atomicAdd(&stats[col], sred[threadIdx.x]);
        atomicAdd(&stats[512 + col], qred[threadIdx.x]);
    }
}

// ---- GEMM2: BN-finalize in LDS + BN on A-load + fused alpha; N split 4-way ------
__global__ __launch_bounds__(256) void gemm2_bn_alpha(const unsigned short* __restrict__ A,
                                                      const unsigned short* __restrict__ Bp,
                                                      const float* __restrict__ stats,
                                                      const float* __restrict__ gamma,
                                                      const float* __restrict__ beta,
                                                      const float* __restrict__ a_s,
                                                      const float* __restrict__ a_d,
                                                      unsigned short* __restrict__ C,
                                                      float* __restrict__ as_out,
                                                      float* __restrict__ ad_out, int M) {
    constexpr int K = 512;
    constexpr int Nn = CONVD;         // 128
    constexpr int KT = K / 32;        // 16
    __shared__ float Ssm[512];
    __shared__ float Tsm[512];
    for (int c = threadIdx.x; c < 512; c += 256) {
        float inv_n = 1.f / (float)NN;
        float mu = stats[c] * inv_n;
        float var = stats[512 + c] * inv_n - mu * mu;
        float s = gamma[c] * rsqrtf(var + EPS_BN);
        Ssm[c] = s;
        Tsm[c] = fmaf(-mu, s, beta[c]);
    }
    __syncthreads();
    int wave = threadIdx.x >> 6, lane = threadIdx.x & 63;
    int row0 = (blockIdx.x * 4 + wave) * 16;
    if (row0 >= M) return;
    int r = lane & 15, quad = lane >> 4;
    int nt0 = blockIdx.y * 2;
    short8 af[KT];
    const unsigned short* arow = A + (size_t)(row0 + r) * K + quad * 8;
#pragma unroll
    for (int kt = 0; kt < KT; kt++) {
        short8 raw = *(const short8*)(arow + kt * 32);
        int k = kt * 32 + quad * 8;
        short8 o;
#pragma unroll
        for (int i = 0; i < 8; i++) {
            float v = fmaf(bf2f((unsigned short)raw[i]), Ssm[k + i], Tsm[k + i]);
            o[i] = (short)f2bf(v > 0.f ? v : 0.f);
        }
        af[kt] = o;
    }
    float asp[4] = {}, adp[4] = {};
#pragma unroll
    for (int nt2 = 0; nt2 < 2; nt2++) {
        int nt = nt0 + nt2;
        floatx4 acc = {0.f, 0.f, 0.f, 0.f};
        const unsigned short* bbase = Bp + (((size_t)nt * KT) << 9) + lane * 8;
#pragma unroll
        for (int kt = 0; kt < KT; kt++) {
            short8 bf = *(const short8*)(bbase + ((size_t)kt << 9));
            acc = __builtin_amdgcn_mfma_f32_16x16x32_bf16(af[kt], bf, acc, 0, 0, 0);
        }
        int col = nt * 16 + r;
        unsigned short* cbase = C + (size_t)(row0 + quad * 4) * Nn + col;
        float sv = a_s[col];
        float dv = a_d[col];
#pragma unroll
        for (int reg = 0; reg < 4; reg++) {
            cbase[(size_t)reg * Nn] = f2bf(acc[reg]);
            asp[reg] = fmaf(acc[reg], sv, asp[reg]);
            adp[reg] = fmaf(acc[reg], dv, adp[reg]);
        }
    }
#pragma unroll
    for (int msk = 1; msk < 16; msk <<= 1) {
#pragma unroll
        for (int reg = 0; reg < 4; reg++) {
            asp[reg] += __shfl_xor(asp[reg], msk);
            adp[reg] += __shfl_xor(adp[reg], msk);
        }
    }
    if (r < 4) {
        int row = row0 + quad * 4 + r;
        atomicAdd(&as_out[row], asp[r]);
        atomicAdd(&ad_out[row], adp[r]);
    }
}

// -------- fused softmax + aggregation, H=1 (one wave per node), LDS + 8-wide -----
__global__ __launch_bounds__(256) void attn_aggr1(const int* __restrict__ rowptr,
                                                  const int* __restrict__ esrc,
                                                  const float* __restrict__ as,
                                                  const float* __restrict__ ad,
                                                  const unsigned short* __restrict__ h,
                                                  float* __restrict__ out) {
    __shared__ float sp[4][64];
    __shared__ int ssrc[4][64];
    int lane = threadIdx.x & 63;
    int wv = threadIdx.x >> 6;
    int n = blockIdx.x * 4 + wv;
    int beg = rowptr[n], end = rowptr[n + 1];
    int deg = end - beg;
    float adn = ad[n];
    float m, sum;
    if (deg <= 64) {
        bool valid = lane < deg;
        int s = esrc[beg + (valid ? lane : 0)];
        float l = valid ? leaky(as[s] + adn) : -INFINITY;
        m = l;
#pragma unroll
        for (int o = 32; o > 0; o >>= 1) m = fmaxf(m, __shfl_xor(m, o));
        float e = valid ? __expf(l - m) : 0.f;
        sum = e;
#pragma unroll
        for (int o = 32; o > 0; o >>= 1) sum += __shfl_xor(sum, o);
        sp[wv][lane] = e;
        ssrc[wv][lane] = s;
    } else {
        m = -INFINITY;
        for (int j = beg + lane; j < end; j += 64)
            m = fmaxf(m, leaky(as[esrc[j]] + adn));
#pragma unroll
        for (int o = 32; o > 0; o >>= 1) m = fmaxf(m, __shfl_xor(m, o));
        sum = 0.f;
        for (int j = beg + lane; j < end; j += 64) {
            int s = esrc[j];
            float e = __expf(leaky(as[s] + adn) - m);
            if (j - beg < 64) { sp[wv][lane] = e; ssrc[wv][lane] = s; }
            sum += e;
        }
#pragma unroll
        for (int o = 32; o > 0; o >>= 1) sum += __shfl_xor(sum, o);
    }
    __syncthreads();
    float inv = 1.f / (sum + 1e-16f);
    float a0 = 0.f, a1 = 0.f;
    const unsigned short* hrow = h + lane * 2;
    int cap = deg < 64 ? deg : 64;
    int jj = 0;
    for (; jj + 7 < cap; jj += 8) {
        int sv[8];
#pragma unroll
        for (int u = 0; u < 8; u++) sv[u] = ssrc[wv][jj + u];
        unsigned xv[8];
#pragma unroll
        for (int u = 0; u < 8; u++) xv[u] = *(const unsigned*)(hrow + (size_t)sv[u] * CONVD);
        float pv[8];
#pragma unroll
        for (int u = 0; u < 8; u++) pv[u] = sp[wv][jj + u];
#pragma unroll
        for (int u = 0; u < 8; u++) {
            a0 = fmaf(pv[u], bf2f((unsigned short)(xv[u] & 0xffffu)), a0);
            a1 = fmaf(pv[u], bf2f((unsigned short)(xv[u] >> 16)), a1);
        }
    }
    for (; jj < cap; jj++) {
        int s = ssrc[wv][jj];
        float p = sp[wv][jj];
        unsigned xv = *(const unsigned*)(hrow + (size_t)s * CONVD);
        a0 = fmaf(p, bf2f((unsigned short)(xv & 0xffffu)), a0);
        a1 = fmaf(p, bf2f((unsigned short)(xv >> 16)), a1);
    }
    for (int j2 = 64; j2 < deg; j2++) {
        int s = esrc[beg + j2];
        float p = __expf(leaky(as[s] + adn) - m);
        unsigned xv = *(const unsigned*)(hrow + (size_t)s * CONVD);
        a0 = fmaf(p, bf2f((unsigned short)(xv & 0xffffu)), a0);
        a1 = fmaf(p, bf2f((unsigned short)(xv >> 16)), a1);
    }
    *(float2*)(out + (size_t)n * CONVD + lane * 2) = make_float2(a0 * inv, a1 * inv);
}

// ---------------- BN stats (f32 input) ----------------
__global__ void bn_stats_f32(const float* __restrict__ x, const float* __restrict__ bias,
                             float* __restrict__ stats, int Nn, int C) {
    const int ROWS = 64;
    int r0 = blockIdx.x * ROWS;
    int rend = min(r0 + ROWS, Nn);
    for (int c = threadIdx.x; c < C; c += blockDim.x) {
        float b = bias[c];
        float s1 = 0.f, s2 = 0.f;
        for (int r = r0; r < rend; r++) {
            float v = x[(size_t)r * C + c] + b;
            s1 += v;
            s2 = fmaf(v, v, s2);
        }
        atomicAdd(&stats[c], s1);
        atomicAdd(&stats[C + c], s2);
    }
}

// ---------------- BN apply + ReLU + pool (layer 2, fused) ------------------------
__global__ void bn_apply_pool(const float* __restrict__ x, const float* __restrict__ bias,
                              const float* __restrict__ stats,
                              const float* __restrict__ gamma, const float* __restrict__ beta,
                              const int* __restrict__ batch, float* __restrict__ z,
                              int Nn, int C) {
    int idx = blockIdx.x * blockDim.x + threadIdx.x;
    if (idx >= Nn * C) return;
    int c = idx % C;
    int n = idx / C;
    float inv_n = 1.f / (float)Nn;
    float mu = stats[c] * inv_n;
    float var = stats[C + c] * inv_n - mu * mu;
    float v = (x[idx] + bias[c] - mu) * rsqrtf(var + EPS_BN);
    v = fmaf(gamma[c], v, beta[c]);
    v = v > 0.f ? v : 0.f;
    atomicAdd(&z[batch[n] * C + c], v);
}

// ---------------- fused MLP head: one block per graph ----------------
__global__ __launch_bounds__(320) void mlp_kernel(const float* __restrict__ g,
                           const float* __restrict__ extras,
                           const float* __restrict__ Wm1, const float* __restrict__ bm1,
                           const float* __restrict__ Wm2, const float* __restrict__ bm2,
                           const float* __restrict__ Wm3, const float* __restrict__ bm3,
                           float* __restrict__ out) {
    const int Z0 = CONVD + NXD;   // 137
    const int Z1 = NETD + NXD;    // 265
    const int Z2 = NETD;          // 256
    __shared__ float z[Z0];
    __shared__ float z1[Z1];
    __shared__ float z2[Z2];
    __shared__ float wred[5];
    int gi = blockIdx.x, t = threadIdx.x;
    if (t < CONVD) z[t] = g[gi * CONVD + t];
    else if (t < Z0) z[t] = extras[gi * NXD + (t - CONVD)];
    __syncthreads();
    if (t < Z1) {
        float acc = bm1[t];
        for (int k = 0; k < Z0; k++) acc = fmaf(z[k], Wm1[k * Z1 + t], acc);
        z1[t] = acc > 0.f ? acc : 0.f;
    }
    __syncthreads();
    if (t < Z2) {
        float acc = bm2[t];
        for (int k = 0; k < Z1; k++) acc = fmaf(z1[k], Wm2[k * Z2 + t], acc);
        z2[t] = acc > 0.f ? acc : 0.f;
    }
    __syncthreads();
    float partial = (t < Z2) ? z2[t] * Wm3[t] : 0.f;
    for (int o = 32; o > 0; o >>= 1) partial += __shfl_down(partial, o);
    int wv = t >> 6, ln = t & 63;
    if (ln == 0) wred[wv] = partial;
    __syncthreads();
    if (t == 0) {
        float s = bm3[0];
        for (int i = 0; i < 5; i++) s += wred[i];
        out[gi] = s;
    }
}

// ---------------- launch ----------------
extern "C" void kernel_launch(void* const* d_in, const int* in_sizes, int n_in,
                              void* d_out, int out_size, void* d_ws, size_t ws_size,
                              hipStream_t stream) {
    const float* x      = (const float*)d_in[0];
    const int*   ei     = (const int*)d_in[1];
    const int*   batch  = (const int*)d_in[2];
    const float* extras = (const float*)d_in[3];
    const float* W1     = (const float*)d_in[4];
    const float* a_s1   = (const float*)d_in[5];
    const float* a_d1   = (const float*)d_in[6];
    const float* b1     = (const float*)d_in[7];
    const float* W2     = (const float*)d_in[8];
    const float* a_s2   = (const float*)d_in[9];
    const float* a_d2   = (const float*)d_in[10];
    const float* b2     = (const float*)d_in[11];
    const float* gamma1 = (const float*)d_in[12];
    const float* beta1  = (const float*)d_in[13];
    const float* gamma2 = (const float*)d_in[14];
    const float* beta2  = (const float*)d_in[15];
    const float* Wm1    = (const float*)d_in[16];
    const float* bm1    = (const float*)d_in[17];
    const float* Wm2    = (const float*)d_in[18];
    const float* bm2    = (const float*)d_in[19];
    const float* Wm3    = (const float*)d_in[20];
    const float* bm3    = (const float*)d_in[21];
    float* out = (float*)d_out;

    const int N = NN, E = EE, EP = EE + NN;

    char* ws = (char*)d_ws;
    size_t off = 0;
    auto alloc = [&](size_t bytes) -> void* {
        void* pp = (void*)(ws + off);
        off += (bytes + 255) & ~(size_t)255;
        return pp;
    };
    // --- zero region (contiguous; one small memset) ---
    int*   deg    = (int*)alloc((size_t)N * 4);
    int*   cursor = (int*)alloc((size_t)N * 4);
    float* stats1 = (float*)alloc(512 * 2 * 4);
    float* stats2 = (float*)alloc(128 * 2 * 4);
    float* zbuf   = (float*)alloc((size_t)GG * CONVD * 4);
    float* as2    = (float*)alloc((size_t)N * 4);      // atomic-accumulated in gemm2
    float* ad2    = (float*)alloc((size_t)N * 4);
    size_t zero_bytes = off;
    // --- scratch (fully overwritten each launch) ---
    int*   rowptr = (int*)alloc((size_t)(N + 1) * 4);
    int*   esrc   = (int*)alloc((size_t)EP * 4);
    unsigned short* xb    = (unsigned short*)alloc((size_t)N * VIN * 2);
    unsigned short* W1p   = (unsigned short*)alloc((size_t)VIN * 512 * 2);
    unsigned short* W2p   = (unsigned short*)alloc((size_t)512 * 128 * 2);
    unsigned short* xagg  = (unsigned short*)alloc((size_t)N * 512 * 2);
    unsigned short* out1b = (unsigned short*)alloc((size_t)N * 512 * 2);
    unsigned short* h2b   = (unsigned short*)alloc((size_t)N * 128 * 2);
    float* out2   = (float*)alloc((size_t)N * 128 * 4);
    float* as1    = (float*)alloc((size_t)N * 4 * 4);
    float* ad1    = (float*)alloc((size_t)N * 4 * 4);
    float* va_s   = (float*)alloc(VIN * 4 * 4);
    float* va_d   = (float*)alloc(VIN * 4 * 4);

    hipMemsetAsync(d_ws, 0, zero_bytes, stream);

    int eb = (EP + 255) / 256;                 // 1642
    int nrow = (N + 63) / 64;                  // 313
    int mblk = (N + 63) / 64;                  // 313
    int nblk4 = N / 4;                         // 5000 (exact)
    int prep_blocks = (N * VIN + 255) / 256 + 256 + 256 + eb + 4;
    int sa_blocks = eb + nblk4;

    // ---- prep (cast + packs + histogram + va) ----
    prep_kernel<<<prep_blocks, 256, 0, stream>>>(x, xb, W1, W1p, W2, W2p, ei, deg,
                                                 a_s1, a_d1, va_s, va_d);

    // ---- CSR build + alpha1 ----
    scan_kernel<<<1, 1024, 0, stream>>>(deg, rowptr, N, EP);
    scatter_alpha<<<sa_blocks, 256, 0, stream>>>(ei, rowptr, cursor, esrc, xb, va_s, va_d, as1, ad1);

    // ---- GAT layer 1 (H=4, concat): x-space aggregation then per-head GEMM ----
    attn_aggr_x4<<<nblk4, 256, 0, stream>>>(rowptr, esrc, as1, ad1, xb, xagg);
    gemm_agg<<<dim3(mblk, 4), 256, 0, stream>>>(xagg, W1p, out1b, stats1, N);

    // ---- GAT layer 2 (H=1): BN finalize folded into GEMM2; N split 4-way ----
    gemm2_bn_alpha<<<dim3(mblk, 4), 256, 0, stream>>>(out1b, W2p, stats1, gamma1, beta1,
                                                      a_s2, a_d2, h2b, as2, ad2, N);
    attn_aggr1<<<nblk4, 256, 0, stream>>>(rowptr, esrc, as2, ad2, h2b, out2);
    bn_stats_f32<<<nrow, 256, 0, stream>>>(out2, b2, stats2, N, 128);
    bn_apply_pool<<<(N * 128 + 255) / 256, 256, 0, stream>>>(out2, b2, stats2, gamma2, beta2, batch, zbuf, N, 128);

    // ---- MLP head ----
    mlp_kernel<<<GG, 320, 0, stream>>>(zbuf, extras, Wm1, bm1, Wm2, bm2, Wm3, bm3, out);
}